// Round 2
// baseline (2205.105 us; speedup 1.0000x reference)
//
#include <hip/hip_runtime.h>
#include <hip/hip_bf16.h>
#include <math.h>

#define NTOK 36864   // tokens per batch (192*192)
#define NTOT 73728   // total tokens (B=2)
#define CDIM 192
#define C3   576
#define NH   6
#define HD   32
#define RD   20
#define NTD  128     // dictionary tokens
#define GSZ  128     // ac-msa group size
#define NGRP 288     // groups per batch
#define MLP  384
#define TDF  48
#define CH   432     // MLP+TDF

typedef __hip_bfloat16 bf16;

__device__ __forceinline__ float gelu_f(float x) {
    return 0.5f * x * (1.0f + erff(x * 0.7071067811865475f));
}

// ---------------- LayerNorm: one wave per token, 4 tokens per block ----------
__global__ void ln_kernel(const float* __restrict__ x, const float* __restrict__ g,
                          const float* __restrict__ be, float* __restrict__ out) {
    long tok = (long)blockIdx.x * 4 + (threadIdx.x >> 6);
    int lane = threadIdx.x & 63;
    const float* row = x + tok * CDIM;
    float v0 = row[lane], v1 = row[lane + 64], v2 = row[lane + 128];
    float s  = v0 + v1 + v2;
    float ss = v0 * v0 + v1 * v1 + v2 * v2;
    #pragma unroll
    for (int o = 32; o > 0; o >>= 1) {
        s  += __shfl_down(s, o);
        ss += __shfl_down(ss, o);
    }
    s = __shfl(s, 0); ss = __shfl(ss, 0);
    float mean = s * (1.0f / 192.0f);
    float var  = ss * (1.0f / 192.0f) - mean * mean;
    float rstd = rsqrtf(var + 1e-5f);
    float* orow = out + tok * CDIM;
    orow[lane]       = (v0 - mean) * rstd * g[lane]       + be[lane];
    orow[lane + 64]  = (v1 - mean) * rstd * g[lane + 64]  + be[lane + 64];
    orow[lane + 128] = (v2 - mean) * rstd * g[lane + 128] + be[lane + 128];
}

// ---------------- Generic tiled f32 GEMM: C(M,N) (+)= A(M,K) @ B(K,N) --------
// 64x64 tile, 256 threads, 4x4 micro-tile, BK=16. K must be a multiple of 16.
// LDS: 2*16*68*4 = 8.7 KB.
template<int ACC, int GELU, int BF16OUT>
__global__ void __launch_bounds__(256) gemm_kernel(
        const float* __restrict__ A, const float* __restrict__ B,
        void* __restrict__ Cv, int M, int N, int K, int lda, int ldb, int ldc) {
    __shared__ float As[16][68];
    __shared__ float Bs[16][68];
    int tid = threadIdx.x;
    int tr = tid >> 4, tc = tid & 15;
    int row0 = blockIdx.y * 64, col0 = blockIdx.x * 64;
    float acc[4][4] = {};
    int lm = tid >> 4;  // A row within group of 16
    int lk = tid & 15;  // A k
    int bk = tid >> 6;  // B k within group of 4
    int bn = tid & 63;  // B col
    for (int k0 = 0; k0 < K; k0 += 16) {
        #pragma unroll
        for (int i = 0; i < 4; ++i) {
            int m = lm + i * 16;
            int gr = row0 + m;
            As[lk][m] = (gr < M) ? A[(long)gr * lda + (k0 + lk)] : 0.0f;
        }
        #pragma unroll
        for (int i = 0; i < 4; ++i) {
            int kk = bk + i * 4;
            int gc = col0 + bn;
            Bs[kk][bn] = (gc < N) ? B[(long)(k0 + kk) * ldb + gc] : 0.0f;
        }
        __syncthreads();
        #pragma unroll
        for (int kk = 0; kk < 16; ++kk) {
            float4 av = *(const float4*)&As[kk][tr * 4];
            float4 bv = *(const float4*)&Bs[kk][tc * 4];
            float a[4] = {av.x, av.y, av.z, av.w};
            float b[4] = {bv.x, bv.y, bv.z, bv.w};
            #pragma unroll
            for (int i = 0; i < 4; ++i)
                #pragma unroll
                for (int j = 0; j < 4; ++j)
                    acc[i][j] = fmaf(a[i], b[j], acc[i][j]);
        }
        __syncthreads();
    }
    #pragma unroll
    for (int i = 0; i < 4; ++i) {
        int gr = row0 + tr * 4 + i;
        if (gr >= M) continue;
        #pragma unroll
        for (int j = 0; j < 4; ++j) {
            int gc = col0 + tc * 4 + j;
            if (gc >= N) continue;
            float v = acc[i][j];
            if (GELU) v = gelu_f(v);
            long o = (long)gr * ldc + gc;
            if (BF16OUT) {
                ((bf16*)Cv)[o] = __float2bfloat16(v);
            } else {
                float* Cc = (float*)Cv;
                if (ACC) Cc[o] += v; else Cc[o] = v;
            }
        }
    }
}

// ---------------- row-wise L2 normalize (RD=20), in place --------------------
__global__ void l2n_kernel(float* __restrict__ d, int nrows) {
    int i = blockIdx.x * blockDim.x + threadIdx.x;
    if (i >= nrows) return;
    float* r = d + (long)i * RD;
    float ss = 0.0f;
    #pragma unroll
    for (int k = 0; k < RD; ++k) ss += r[k] * r[k];
    float inv = 1.0f / fmaxf(sqrtf(ss), 1e-12f);
    #pragma unroll
    for (int k = 0; k < RD; ++k) r[k] *= inv;
}

// ---------------- ATD similarity softmax + argmax (block = token) ------------
__global__ void __launch_bounds__(128) sim_kernel(
        const float* __restrict__ qn, const float* __restrict__ kn,
        const float* __restrict__ scale_p, float* __restrict__ sim,
        int* __restrict__ tkid) {
    int tok = blockIdx.x;           // 0..NTOT-1
    int b = tok / NTOK;
    int j = threadIdx.x;            // 0..127
    __shared__ float qv[RD];
    __shared__ float wred[4];
    __shared__ int   wredi[2];
    if (j < RD) qv[j] = qn[(long)tok * RD + j];
    __syncthreads();
    const float* kr = kn + ((long)b * NTD + j) * RD;
    float s = 0.0f;
    #pragma unroll
    for (int r = 0; r < RD; ++r) s = fmaf(qv[r], kr[r], s);
    float scl = 1.0f + fminf(fmaxf(scale_p[0], 0.0f), 3.0f) * logf(128.0f);
    s *= scl;
    // max + argmax (first-index on ties, matching jnp.argmax)
    float m = s; int mi = j;
    #pragma unroll
    for (int o = 32; o > 0; o >>= 1) {
        float om = __shfl_down(m, o); int oi = __shfl_down(mi, o);
        if (om > m || (om == m && oi < mi)) { m = om; mi = oi; }
    }
    int wv = j >> 6;
    if ((j & 63) == 0) { wred[wv] = m; wredi[wv] = mi; }
    __syncthreads();
    float m0 = wred[0], m1 = wred[1];
    float gm; int gi;
    if (m1 > m0) { gm = m1; gi = wredi[1]; } else { gm = m0; gi = wredi[0]; }
    float p = expf(s - gm);
    float t = p;
    #pragma unroll
    for (int o = 32; o > 0; o >>= 1) t += __shfl_down(t, o);
    if ((j & 63) == 0) wred[2 + wv] = t;
    __syncthreads();
    float tot = wred[2] + wred[3];
    sim[(long)tok * NTD + j] = p / tot;
    if (j == 0) tkid[tok] = gi;
}

// ---------------- stable counting sort: hist / scan / scatter ----------------
__global__ void hist_kernel(const int* __restrict__ tkid, int* __restrict__ hist) {
    int tile = blockIdx.x;          // 0..575 (b*NGRP+g)
    int tid = threadIdx.x;          // 0..127
    __shared__ int h[NTD];
    h[tid] = 0;
    __syncthreads();
    atomicAdd(&h[tkid[tile * GSZ + tid]], 1);
    __syncthreads();
    hist[tile * NTD + tid] = h[tid];
}

__global__ void scan_kernel(int* __restrict__ hist) {
    int b = blockIdx.x;             // batch
    int c = threadIdx.x;            // category
    __shared__ int tot[NTD];
    __shared__ int base[NTD];
    int run = 0;
    for (int t = 0; t < NGRP; ++t) {
        int id = (b * NGRP + t) * NTD + c;
        int v = hist[id];
        hist[id] = run;
        run += v;
    }
    tot[c] = run;
    __syncthreads();
    if (c == 0) {
        int a = 0;
        for (int i = 0; i < NTD; ++i) { base[i] = a; a += tot[i]; }
    }
    __syncthreads();
    int bc = base[c];
    for (int t = 0; t < NGRP; ++t)
        hist[(b * NGRP + t) * NTD + c] += bc;
}

__global__ void scatter_kernel(const int* __restrict__ tkid, const int* __restrict__ hist,
                               int* __restrict__ idxs) {
    int tile = blockIdx.x;          // 0..575
    int b = tile / NGRP;
    int gl = tile % NGRP;
    int tid = threadIdx.x;
    __shared__ int cats[GSZ];
    int cat = tkid[tile * GSZ + tid];
    cats[tid] = cat;
    __syncthreads();
    int rank = 0;
    for (int j = 0; j < tid; ++j) rank += (cats[j] == cat) ? 1 : 0;
    int pos = hist[tile * NTD + cat] + rank;
    idxs[b * NTOK + pos] = gl * GSZ + tid;
}

// ---------------- window attention: block = (window, head), 256 threads ------
// K/V staged in 2 tiles of 128 tokens; LDS = 2*16KB + 3.8KB = 35.9 KB.
__global__ void __launch_bounds__(256) win_kernel(
        const bf16* __restrict__ qkv, const float* __restrict__ rpb,
        float* __restrict__ out) {
    int wid = blockIdx.x / NH;
    int h   = blockIdx.x % NH;
    int b = wid / 144;
    int wrem = wid % 144;
    int wy = wrem / 12, wx = wrem % 12;
    __shared__ float Ks[128][HD];
    __shared__ float Vs[128][HD];
    __shared__ float rb[961];
    int tid = threadIdx.x;
    int iy = tid >> 4, ix = tid & 15;
    long nq = (long)b * NTOK + (long)(wy * 16 + iy) * 192 + (wx * 16 + ix);
    const bf16* qb = qkv + nq * C3 + h * HD;
    float q[HD];
    #pragma unroll
    for (int d = 0; d < HD; ++d) q[d] = __bfloat162float(qb[d]) * 0.17677669529663687f;
    for (int i = tid; i < 961; i += 256) rb[i] = rpb[i * NH + h];
    float m = -INFINITY, l = 0.0f;
    float acc[HD];
    #pragma unroll
    for (int d = 0; d < HD; ++d) acc[d] = 0.0f;
    int st = tid >> 1, sd = (tid & 1) * 16;  // staging: token, dim-half
    for (int t0 = 0; t0 < 256; t0 += 128) {
        __syncthreads();   // previous tile consumed (also covers rb staging)
        {
            int p = t0 + st;
            int py = p >> 4, px = p & 15;
            long nk = (long)b * NTOK + (long)(wy * 16 + py) * 192 + (wx * 16 + px);
            const bf16* kb = qkv + nk * C3 + CDIM + h * HD;
            const bf16* vb = kb + CDIM;
            #pragma unroll
            for (int d = 0; d < 16; ++d) {
                Ks[st][sd + d] = __bfloat162float(kb[sd + d]);
                Vs[st][sd + d] = __bfloat162float(vb[sd + d]);
            }
        }
        __syncthreads();
        for (int j = 0; j < 128; ++j) {
            float s = 0.0f;
            const float4* kr = (const float4*)Ks[j];
            #pragma unroll
            for (int d4 = 0; d4 < 8; ++d4) {
                float4 kv = kr[d4];
                s = fmaf(q[d4*4+0], kv.x, s);
                s = fmaf(q[d4*4+1], kv.y, s);
                s = fmaf(q[d4*4+2], kv.z, s);
                s = fmaf(q[d4*4+3], kv.w, s);
            }
            int jg = t0 + j;
            int jy = jg >> 4, jx = jg & 15;
            s += rb[(iy - jy + 15) * 31 + (ix - jx + 15)];
            float mn = fmaxf(m, s);
            float p  = expf(s - mn);
            float sc = expf(m - mn);
            l = l * sc + p;
            const float4* vr = (const float4*)Vs[j];
            #pragma unroll
            for (int d4 = 0; d4 < 8; ++d4) {
                float4 vv = vr[d4];
                acc[d4*4+0] = fmaf(acc[d4*4+0], sc, p * vv.x);
                acc[d4*4+1] = fmaf(acc[d4*4+1], sc, p * vv.y);
                acc[d4*4+2] = fmaf(acc[d4*4+2], sc, p * vv.z);
                acc[d4*4+3] = fmaf(acc[d4*4+3], sc, p * vv.w);
            }
            m = mn;
        }
    }
    float inv = 1.0f / l;
    float* orow = out + nq * CDIM + h * HD;
    #pragma unroll
    for (int d4 = 0; d4 < 8; ++d4) {
        float4 o4;
        o4.x = acc[d4*4+0] * inv;
        o4.y = acc[d4*4+1] * inv;
        o4.z = acc[d4*4+2] * inv;
        o4.w = acc[d4*4+3] * inv;
        *(float4*)&orow[d4*4] = o4;
    }
}

// ---------------- AC-MSA attention: block = (group, head), 128 threads -------
// LDS = 32 KB.
__global__ void __launch_bounds__(128) aca_kernel(
        const bf16* __restrict__ qkv, const int* __restrict__ idxs,
        float* __restrict__ out) {
    int grp = blockIdx.x / NH;      // 0..575
    int h   = blockIdx.x % NH;
    int b = grp / NGRP;
    int g = grp % NGRP;
    __shared__ float Ks[GSZ][HD];
    __shared__ float Vs[GSZ][HD];
    int tid = threadIdx.x;
    int tokb = idxs[b * NTOK + g * GSZ + tid];
    long n = (long)b * NTOK + tokb;
    const bf16* base = qkv + n * C3;
    float q[HD];
    #pragma unroll
    for (int d = 0; d < HD; ++d) {
        q[d] = __bfloat162float(base[h * HD + d]) * 0.17677669529663687f;
        Ks[tid][d] = __bfloat162float(base[CDIM     + h * HD + d]);
        Vs[tid][d] = __bfloat162float(base[2 * CDIM + h * HD + d]);
    }
    __syncthreads();
    float m = -INFINITY, l = 0.0f;
    float acc[HD];
    #pragma unroll
    for (int d = 0; d < HD; ++d) acc[d] = 0.0f;
    for (int j = 0; j < GSZ; ++j) {
        float s = 0.0f;
        const float4* kr = (const float4*)Ks[j];
        #pragma unroll
        for (int d4 = 0; d4 < 8; ++d4) {
            float4 kv = kr[d4];
            s = fmaf(q[d4*4+0], kv.x, s);
            s = fmaf(q[d4*4+1], kv.y, s);
            s = fmaf(q[d4*4+2], kv.z, s);
            s = fmaf(q[d4*4+3], kv.w, s);
        }
        float mn = fmaxf(m, s);
        float p  = expf(s - mn);
        float sc = expf(m - mn);
        l = l * sc + p;
        const float4* vr = (const float4*)Vs[j];
        #pragma unroll
        for (int d4 = 0; d4 < 8; ++d4) {
            float4 vv = vr[d4];
            acc[d4*4+0] = fmaf(acc[d4*4+0], sc, p * vv.x);
            acc[d4*4+1] = fmaf(acc[d4*4+1], sc, p * vv.y);
            acc[d4*4+2] = fmaf(acc[d4*4+2], sc, p * vv.z);
            acc[d4*4+3] = fmaf(acc[d4*4+3], sc, p * vv.w);
        }
        m = mn;
    }
    float inv = 1.0f / l;
    float* orow = out + n * CDIM + h * HD;
    #pragma unroll
    for (int d4 = 0; d4 < 8; ++d4) {
        float4 o4;
        o4.x = acc[d4*4+0] * inv;
        o4.y = acc[d4*4+1] * inv;
        o4.z = acc[d4*4+2] * inv;
        o4.w = acc[d4*4+3] * inv;
        *(float4*)&orow[d4*4] = o4;
    }
}

// ---------------- x_td -> y[:, 384:432] copy (f32 -> bf16) -------------------
__global__ void xtdcopy_kernel(const float* __restrict__ xtd, bf16* __restrict__ y) {
    long i = (long)blockIdx.x * 256 + threadIdx.x;
    long ntk = i / TDF;
    int c = (int)(i - ntk * TDF);
    y[ntk * CH + MLP + c] = __float2bfloat16(xtd[i]);
}

// ---------------- depthwise 5x5 conv + gelu + residual over a 144-ch chunk ---
// z[:, 0:144] = y[:, z0:z0+144] + gelu(conv(y[:, z0:z0+144]))
// block = (batch, 16x16 spatial tile, 24-ch sub-chunk); LDS = 40.9 KB.
#define YSLD 401
__global__ void __launch_bounds__(256) conv_kernel(
        const bf16* __restrict__ y, const float* __restrict__ dw,
        float* __restrict__ z, int z0) {
    int bid = blockIdx.x;
    int ck   = bid % 6;             // 6 sub-chunks of 24 channels
    int tile = (bid / 6) % 144;     // 12x12 spatial tiles of 16x16
    int b    = bid / (6 * 144);
    int ty = tile / 12, tx = tile % 12;
    int c0 = z0 + ck * 24;          // global channel base
    __shared__ float ys[24 * YSLD];     // channel-major [c][p], p in 20x20
    __shared__ float wt[24 * 25];
    int tid = threadIdx.x;
    const bf16* yb = y + (long)b * NTOK * CH;
    for (int e = tid; e < 20 * 20 * 24; e += 256) {
        int p = e / 24, c = e - p * 24;
        int ly = p / 20, lx = p - ly * 20;
        int gy = ty * 16 + ly - 2, gx = tx * 16 + lx - 2;
        float v = 0.0f;
        if (gy >= 0 && gy < 192 && gx >= 0 && gx < 192)
            v = __bfloat162float(yb[(long)(gy * 192 + gx) * CH + c0 + c]);
        ys[c * YSLD + p] = v;
    }
    for (int e = tid; e < 24 * 25; e += 256)
        wt[e] = dw[(c0 + e / 25) * 25 + (e % 25)];
    __syncthreads();
    int py = tid >> 4, px = tid & 15;
    long obase = ((long)b * NTOK + (long)(ty * 16 + py) * 192 + (tx * 16 + px)) * 144 + ck * 24;
    for (int c = 0; c < 24; ++c) {
        const float* yc = &ys[c * YSLD];
        float a = 0.0f;
        #pragma unroll
        for (int dy = 0; dy < 5; ++dy)
            #pragma unroll
            for (int dx = 0; dx < 5; ++dx)
                a = fmaf(yc[(py + dy) * 20 + (px + dx)], wt[c * 25 + dy * 5 + dx], a);
        float center = yc[(py + 2) * 20 + (px + 2)];
        z[obase + c] = center + gelu_f(a);
    }
}

// =============================================================================
extern "C" void kernel_launch(void* const* d_in, const int* in_sizes, int n_in,
                              void* d_out, int out_size, void* d_ws, size_t ws_size,
                              hipStream_t stream) {
    (void)in_sizes; (void)n_in; (void)out_size; (void)ws_size;
    const float* x     = (const float*)d_in[0];
    const float* td    = (const float*)d_in[1];
    const float* n1g   = (const float*)d_in[2];
    const float* n1b   = (const float*)d_in[3];
    const float* n2g   = (const float*)d_in[4];
    const float* n2b   = (const float*)d_in[5];
    const float* wqkv  = (const float*)d_in[6];
    const float* rpb   = (const float*)d_in[7];
    const float* wproj = (const float*)d_in[8];
    const float* awq   = (const float*)d_in[9];
    const float* awk   = (const float*)d_in[10];
    const float* awv   = (const float*)d_in[11];
    const float* ascl  = (const float*)d_in[12];
    const float* aproj = (const float*)d_in[13];
    const float* fcw   = (const float*)d_in[14];
    const float* w1    = (const float*)d_in[15];
    const float* dw    = (const float*)d_in[16];
    const float* w2    = (const float*)d_in[17];
    float* out = (float*)d_out;

    char* ws = (char*)d_ws;
    size_t off = 0;
    auto alloc = [&](size_t bytes) -> char* {
        char* p = ws + off;
        off += (bytes + 255) & ~(size_t)255;
        return p;
    };
    // R0: qkv bf16 (84.9 MB) -> later y bf16 (63.7 MB, stride CH)
    bf16*  qkv  = (bf16*)alloc((size_t)NTOT * C3 * 2);
    // R1: xn f32 (56.6 MB) -> raw f32 -> xn2 f32
    float* xn   = (float*)alloc((size_t)NTOT * CDIM * 4);
    // R2: qn (5.9) + simb (37.7) + xtd (14.2); z (42.5) reuses qn+simb
    float* qn   = (float*)alloc((size_t)NTOT * RD * 4);
    float* simb = (float*)alloc((size_t)NTOT * NTD * 4);
    float* xtd  = (float*)alloc((size_t)NTOT * TDF * 4);
    // smalls
    float* kn   = (float*)alloc((size_t)2 * NTD * RD * 4);
    float* vtd  = (float*)alloc((size_t)2 * NTD * CDIM * 4);
    float* tdf  = (float*)alloc((size_t)2 * NTD * TDF * 4);
    int*   tkid = (int*)alloc((size_t)NTOT * 4);
    int*   idxs = (int*)alloc((size_t)NTOT * 4);
    int*   hist = (int*)alloc((size_t)576 * NTD * 4);
    bf16*  y    = qkv;    // reuse R0
    float* raw  = xn;     // reuse R1
    float* xn2  = xn;     // reuse R1
    float* z    = qn;     // reuse R2 head (42.5 MB <= qn+simb = 43.6 MB)
    // total ~201 MB

    // d_out = shortcut (x)
    hipMemcpyAsync(out, x, (size_t)NTOT * CDIM * 4, hipMemcpyDeviceToDevice, stream);

    // LN1
    ln_kernel<<<NTOT / 4, 256, 0, stream>>>(x, n1g, n1b, xn);

    // qkv (bf16) = xn @ wqkv
    gemm_kernel<0,0,1><<<dim3(9, 1152), 256, 0, stream>>>(xn, wqkv, qkv, NTOT, C3, CDIM, CDIM, C3, C3);
    // qn = xn @ atd_wq ; kn = td @ atd_wk ; vtd = td @ atd_wv ; tdf = td @ fc_td_w
    gemm_kernel<0,0,0><<<dim3(1, 1152), 256, 0, stream>>>(xn, awq, qn, NTOT, RD, CDIM, CDIM, RD, RD);
    gemm_kernel<0,0,0><<<dim3(1, 4), 256, 0, stream>>>(td, awk, kn, 2 * NTD, RD, CDIM, CDIM, RD, RD);
    gemm_kernel<0,0,0><<<dim3(3, 4), 256, 0, stream>>>(td, awv, vtd, 2 * NTD, CDIM, CDIM, CDIM, CDIM, CDIM);
    gemm_kernel<0,0,0><<<dim3(1, 4), 256, 0, stream>>>(td, fcw, tdf, 2 * NTD, TDF, CDIM, CDIM, TDF, TDF);

    l2n_kernel<<<(NTOT + 255) / 256, 256, 0, stream>>>(qn, NTOT);
    l2n_kernel<<<1, 256, 0, stream>>>(kn, 2 * NTD);

    // sim = softmax(qn @ kn^T * scale), tkid = argmax(sim)
    sim_kernel<<<NTOT, 128, 0, stream>>>(qn, kn, ascl, simb, tkid);

    // d_out += sim @ vtd ; xtd = sim @ tdf   (per batch)
    for (int b = 0; b < 2; ++b) {
        gemm_kernel<1,0,0><<<dim3(3, 576), 256, 0, stream>>>(
            simb + (size_t)b * NTOK * NTD, vtd + (size_t)b * NTD * CDIM,
            out + (size_t)b * NTOK * CDIM, NTOK, CDIM, NTD, NTD, CDIM, CDIM);
        gemm_kernel<0,0,0><<<dim3(1, 576), 256, 0, stream>>>(
            simb + (size_t)b * NTOK * NTD, tdf + (size_t)b * NTD * TDF,
            xtd + (size_t)b * NTOK * TDF, NTOK, TDF, NTD, NTD, TDF, TDF);
    }

    // stable counting sort of tokens by tkid
    hist_kernel<<<576, 128, 0, stream>>>(tkid, hist);
    scan_kernel<<<2, 128, 0, stream>>>(hist);
    scatter_kernel<<<576, 128, 0, stream>>>(tkid, hist, idxs);

    // window attention -> raw, then d_out += raw @ win_proj
    win_kernel<<<288 * NH, 256, 0, stream>>>(qkv, rpb, raw);
    gemm_kernel<1,0,0><<<dim3(3, 1152), 256, 0, stream>>>(raw, wproj, out, NTOT, CDIM, CDIM, CDIM, CDIM, CDIM);

    // AC-MSA -> raw, then d_out += raw @ aca_proj
    aca_kernel<<<576 * NH, 128, 0, stream>>>(qkv, idxs, raw);
    gemm_kernel<1,0,0><<<dim3(3, 1152), 256, 0, stream>>>(raw, aproj, out, NTOT, CDIM, CDIM, CDIM, CDIM, CDIM);

    // LN2 on x1 (= d_out); qkv is dead from here, R0 becomes y
    ln_kernel<<<NTOT / 4, 256, 0, stream>>>(out, n2g, n2b, xn2);

    // y[:, :384] = gelu(xn2 @ w1) (bf16) ; y[:, 384:432] = x_td
    gemm_kernel<0,1,1><<<dim3(6, 1152), 256, 0, stream>>>(xn2, w1, y, NTOT, MLP, CDIM, CDIM, MLP, CH);
    xtdcopy_kernel<<<(NTOT * TDF) / 256, 256, 0, stream>>>(xtd, y);

    // z = y + gelu(depthwise_conv5x5(y)) in 3 chunks of 144 channels,
    // each immediately folded into d_out via a K=144 GEMM.
    for (int c = 0; c < 3; ++c) {
        int z0 = c * 144;
        conv_kernel<<<2 * 144 * 6, 256, 0, stream>>>(y, dw, z, z0);
        gemm_kernel<1,0,0><<<dim3(3, 1152), 256, 0, stream>>>(
            z, w2 + (size_t)z0 * CDIM, out, NTOT, CDIM, 144, 144, CDIM, CDIM);
    }
}

// Round 3
// 1651.625 us; speedup vs baseline: 1.3351x; 1.3351x over previous
//
#include <hip/hip_runtime.h>
#include <hip/hip_bf16.h>
#include <math.h>

#define NTOK 36864   // tokens per batch (192*192)
#define NTOT 73728   // total tokens (B=2)
#define CDIM 192
#define C3   576
#define NH   6
#define HD   32
#define RD   20
#define NTD  128     // dictionary tokens
#define GSZ  128     // ac-msa group size
#define NGRP 288     // groups per batch
#define MLP  384
#define TDF  48
#define CH   432     // MLP+TDF

typedef __hip_bfloat16 bf16;
typedef __attribute__((ext_vector_type(8))) short short8;
typedef __attribute__((ext_vector_type(4))) float f32x4;

__device__ __forceinline__ float gelu_f(float x) {
    return 0.5f * x * (1.0f + erff(x * 0.7071067811865475f));
}

__device__ __forceinline__ unsigned short f32_to_bf16u(float f) {
    unsigned int u = __float_as_uint(f);
    u = (u + 0x7FFFu + ((u >> 16) & 1u)) >> 16;   // RNE
    return (unsigned short)u;
}

// ---------------- LayerNorm: one wave per token, 4 tokens per block ----------
__global__ void ln_kernel(const float* __restrict__ x, const float* __restrict__ g,
                          const float* __restrict__ be, float* __restrict__ out) {
    long tok = (long)blockIdx.x * 4 + (threadIdx.x >> 6);
    int lane = threadIdx.x & 63;
    const float* row = x + tok * CDIM;
    float v0 = row[lane], v1 = row[lane + 64], v2 = row[lane + 128];
    float s  = v0 + v1 + v2;
    float ss = v0 * v0 + v1 * v1 + v2 * v2;
    #pragma unroll
    for (int o = 32; o > 0; o >>= 1) {
        s  += __shfl_down(s, o);
        ss += __shfl_down(ss, o);
    }
    s = __shfl(s, 0); ss = __shfl(ss, 0);
    float mean = s * (1.0f / 192.0f);
    float var  = ss * (1.0f / 192.0f) - mean * mean;
    float rstd = rsqrtf(var + 1e-5f);
    float* orow = out + tok * CDIM;
    orow[lane]       = (v0 - mean) * rstd * g[lane]       + be[lane];
    orow[lane + 64]  = (v1 - mean) * rstd * g[lane + 64]  + be[lane + 64];
    orow[lane + 128] = (v2 - mean) * rstd * g[lane + 128] + be[lane + 128];
}

// ---------------- bf16 MFMA GEMM: C(M,N) (+)= A(M,K) @ B(K,N) ----------------
// f32 inputs, converted to bf16 during LDS staging. 128x64 tile, 4 waves 2x2,
// BK=64, K zero-padded. M must be a multiple of 128. LDS 27.6 KB.
#define LDT 72   // padded stride in bf16 units (144 B)
template<int ACC, int GELU, int BF16OUT>
__global__ void __launch_bounds__(256) gemm_mfma(
        const float* __restrict__ A, const float* __restrict__ B,
        void* __restrict__ Cv, int M, int N, int K, int lda, int ldb, int ldc) {
    __shared__ short As[128 * LDT];
    __shared__ short Bs[64 * LDT];
    int tid  = threadIdx.x;
    int lane = tid & 63;
    int w    = tid >> 6;
    int wr = w >> 1, wc = w & 1;
    int row0 = blockIdx.y * 128, col0 = blockIdx.x * 64;
    int fr = lane & 15, fq = lane >> 4;
    f32x4 acc[4][2];
    #pragma unroll
    for (int m = 0; m < 4; ++m)
        #pragma unroll
        for (int n = 0; n < 2; ++n) acc[m][n] = (f32x4)(0.0f);

    int sa_row = tid >> 3;          // 0..31
    int sa_kc  = (tid & 7) * 8;     // 0..56
    int sb_col = tid & 63;
    int sb_kb  = (tid >> 6) * 16;   // 0,16,32,48
    bool cok = (col0 + sb_col) < N;

    for (int k0 = 0; k0 < K; k0 += 64) {
        __syncthreads();
        // ---- stage A: 4 passes x 32 rows; thread loads 8 consecutive k ----
        #pragma unroll
        for (int p = 0; p < 4; ++p) {
            int r = sa_row + p * 32;
            const float* src = A + (long)(row0 + r) * lda + k0 + sa_kc;
            short8 v;
            if (k0 + sa_kc + 8 <= K) {
                float4 f0 = *(const float4*)&src[0];
                float4 f1 = *(const float4*)&src[4];
                v[0] = (short)f32_to_bf16u(f0.x); v[1] = (short)f32_to_bf16u(f0.y);
                v[2] = (short)f32_to_bf16u(f0.z); v[3] = (short)f32_to_bf16u(f0.w);
                v[4] = (short)f32_to_bf16u(f1.x); v[5] = (short)f32_to_bf16u(f1.y);
                v[6] = (short)f32_to_bf16u(f1.z); v[7] = (short)f32_to_bf16u(f1.w);
            } else {
                #pragma unroll
                for (int i = 0; i < 8; ++i) {
                    float f = (k0 + sa_kc + i < K) ? src[i] : 0.0f;
                    v[i] = (short)f32_to_bf16u(f);
                }
            }
            *(short8*)&As[r * LDT + sa_kc] = v;
        }
        // ---- stage B transposed: Bs[col][k]; thread covers 16 k values ----
        {
            short8 v0, v1;
            #pragma unroll
            for (int i = 0; i < 16; ++i) {
                int k = sb_kb + i;
                float f = (cok && (k0 + k) < K)
                          ? B[(long)(k0 + k) * ldb + col0 + sb_col] : 0.0f;
                unsigned short h = f32_to_bf16u(f);
                if (i < 8) v0[i] = (short)h; else v1[i - 8] = (short)h;
            }
            *(short8*)&Bs[sb_col * LDT + sb_kb]     = v0;
            *(short8*)&Bs[sb_col * LDT + sb_kb + 8] = v1;
        }
        __syncthreads();
        // ---- fragments + MFMA ----
        short8 af[4][2], bf_[2][2];
        #pragma unroll
        for (int m = 0; m < 4; ++m) {
            int r = wr * 64 + m * 16 + fr;
            af[m][0] = *(const short8*)&As[r * LDT + fq * 8];
            af[m][1] = *(const short8*)&As[r * LDT + 32 + fq * 8];
        }
        #pragma unroll
        for (int n = 0; n < 2; ++n) {
            int c = wc * 32 + n * 16 + fr;
            bf_[n][0] = *(const short8*)&Bs[c * LDT + fq * 8];
            bf_[n][1] = *(const short8*)&Bs[c * LDT + 32 + fq * 8];
        }
        #pragma unroll
        for (int m = 0; m < 4; ++m)
            #pragma unroll
            for (int n = 0; n < 2; ++n) {
                acc[m][n] = __builtin_amdgcn_mfma_f32_16x16x32_bf16(
                                af[m][0], bf_[n][0], acc[m][n], 0, 0, 0);
                acc[m][n] = __builtin_amdgcn_mfma_f32_16x16x32_bf16(
                                af[m][1], bf_[n][1], acc[m][n], 0, 0, 0);
            }
    }
    // ---- epilogue: C[row = 4*fq + r][col = fr] per 16x16 fragment ----
    #pragma unroll
    for (int m = 0; m < 4; ++m) {
        #pragma unroll
        for (int n = 0; n < 2; ++n) {
            int gc = col0 + wc * 32 + n * 16 + fr;
            if (gc >= N) continue;
            #pragma unroll
            for (int r = 0; r < 4; ++r) {
                int gr = row0 + wr * 64 + m * 16 + fq * 4 + r;
                float vv = acc[m][n][r];
                if (GELU) vv = gelu_f(vv);
                long o = (long)gr * ldc + gc;
                if (BF16OUT) {
                    ((bf16*)Cv)[o] = __float2bfloat16(vv);
                } else {
                    float* Cc = (float*)Cv;
                    if (ACC) Cc[o] += vv; else Cc[o] = vv;
                }
            }
        }
    }
}

// ---------------- Generic tiled f32 GEMM (small / precision-critical) --------
template<int ACC, int GELU, int BF16OUT>
__global__ void __launch_bounds__(256) gemm_kernel(
        const float* __restrict__ A, const float* __restrict__ B,
        void* __restrict__ Cv, int M, int N, int K, int lda, int ldb, int ldc) {
    __shared__ float As[16][68];
    __shared__ float Bs[16][68];
    int tid = threadIdx.x;
    int tr = tid >> 4, tc = tid & 15;
    int row0 = blockIdx.y * 64, col0 = blockIdx.x * 64;
    float acc[4][4] = {};
    int lm = tid >> 4;
    int lk = tid & 15;
    int bk = tid >> 6;
    int bn = tid & 63;
    for (int k0 = 0; k0 < K; k0 += 16) {
        #pragma unroll
        for (int i = 0; i < 4; ++i) {
            int m = lm + i * 16;
            int gr = row0 + m;
            As[lk][m] = (gr < M) ? A[(long)gr * lda + (k0 + lk)] : 0.0f;
        }
        #pragma unroll
        for (int i = 0; i < 4; ++i) {
            int kk = bk + i * 4;
            int gc = col0 + bn;
            Bs[kk][bn] = (gc < N) ? B[(long)(k0 + kk) * ldb + gc] : 0.0f;
        }
        __syncthreads();
        #pragma unroll
        for (int kk = 0; kk < 16; ++kk) {
            float4 av = *(const float4*)&As[kk][tr * 4];
            float4 bv = *(const float4*)&Bs[kk][tc * 4];
            float a[4] = {av.x, av.y, av.z, av.w};
            float b[4] = {bv.x, bv.y, bv.z, bv.w};
            #pragma unroll
            for (int i = 0; i < 4; ++i)
                #pragma unroll
                for (int j = 0; j < 4; ++j)
                    acc[i][j] = fmaf(a[i], b[j], acc[i][j]);
        }
        __syncthreads();
    }
    #pragma unroll
    for (int i = 0; i < 4; ++i) {
        int gr = row0 + tr * 4 + i;
        if (gr >= M) continue;
        #pragma unroll
        for (int j = 0; j < 4; ++j) {
            int gc = col0 + tc * 4 + j;
            if (gc >= N) continue;
            float v = acc[i][j];
            if (GELU) v = gelu_f(v);
            long o = (long)gr * ldc + gc;
            if (BF16OUT) {
                ((bf16*)Cv)[o] = __float2bfloat16(v);
            } else {
                float* Cc = (float*)Cv;
                if (ACC) Cc[o] += v; else Cc[o] = v;
            }
        }
    }
}

// ---------------- row-wise L2 normalize (RD=20), in place --------------------
__global__ void l2n_kernel(float* __restrict__ d, int nrows) {
    int i = blockIdx.x * blockDim.x + threadIdx.x;
    if (i >= nrows) return;
    float* r = d + (long)i * RD;
    float ss = 0.0f;
    #pragma unroll
    for (int k = 0; k < RD; ++k) ss += r[k] * r[k];
    float inv = 1.0f / fmaxf(sqrtf(ss), 1e-12f);
    #pragma unroll
    for (int k = 0; k < RD; ++k) r[k] *= inv;
}

// ---------------- ATD similarity softmax + argmax (block = token) ------------
__global__ void __launch_bounds__(128) sim_kernel(
        const float* __restrict__ qn, const float* __restrict__ kn,
        const float* __restrict__ scale_p, float* __restrict__ sim,
        int* __restrict__ tkid) {
    int tok = blockIdx.x;
    int b = tok / NTOK;
    int j = threadIdx.x;
    __shared__ float qv[RD];
    __shared__ float wred[4];
    __shared__ int   wredi[2];
    if (j < RD) qv[j] = qn[(long)tok * RD + j];
    __syncthreads();
    const float* kr = kn + ((long)b * NTD + j) * RD;
    float s = 0.0f;
    #pragma unroll
    for (int r = 0; r < RD; ++r) s = fmaf(qv[r], kr[r], s);
    float scl = 1.0f + fminf(fmaxf(scale_p[0], 0.0f), 3.0f) * logf(128.0f);
    s *= scl;
    float m = s; int mi = j;
    #pragma unroll
    for (int o = 32; o > 0; o >>= 1) {
        float om = __shfl_down(m, o); int oi = __shfl_down(mi, o);
        if (om > m || (om == m && oi < mi)) { m = om; mi = oi; }
    }
    int wv = j >> 6;
    if ((j & 63) == 0) { wred[wv] = m; wredi[wv] = mi; }
    __syncthreads();
    float m0 = wred[0], m1 = wred[1];
    float gm; int gi;
    if (m1 > m0) { gm = m1; gi = wredi[1]; } else { gm = m0; gi = wredi[0]; }
    float p = expf(s - gm);
    float t = p;
    #pragma unroll
    for (int o = 32; o > 0; o >>= 1) t += __shfl_down(t, o);
    if ((j & 63) == 0) wred[2 + wv] = t;
    __syncthreads();
    float tot = wred[2] + wred[3];
    sim[(long)tok * NTD + j] = p / tot;
    if (j == 0) tkid[tok] = gi;
}

// ---------------- stable counting sort: hist / scan / scatter ----------------
__global__ void hist_kernel(const int* __restrict__ tkid, int* __restrict__ hist) {
    int tile = blockIdx.x;
    int tid = threadIdx.x;
    __shared__ int h[NTD];
    h[tid] = 0;
    __syncthreads();
    atomicAdd(&h[tkid[tile * GSZ + tid]], 1);
    __syncthreads();
    hist[tile * NTD + tid] = h[tid];
}

__global__ void scan_kernel(int* __restrict__ hist) {
    int b = blockIdx.x;
    int c = threadIdx.x;
    __shared__ int tot[NTD];
    __shared__ int base[NTD];
    int run = 0;
    for (int t = 0; t < NGRP; ++t) {
        int id = (b * NGRP + t) * NTD + c;
        int v = hist[id];
        hist[id] = run;
        run += v;
    }
    tot[c] = run;
    __syncthreads();
    if (c == 0) {
        int a = 0;
        for (int i = 0; i < NTD; ++i) { base[i] = a; a += tot[i]; }
    }
    __syncthreads();
    int bc = base[c];
    for (int t = 0; t < NGRP; ++t)
        hist[(b * NGRP + t) * NTD + c] += bc;
}

__global__ void scatter_kernel(const int* __restrict__ tkid, const int* __restrict__ hist,
                               int* __restrict__ idxs) {
    int tile = blockIdx.x;
    int b = tile / NGRP;
    int gl = tile % NGRP;
    int tid = threadIdx.x;
    __shared__ int cats[GSZ];
    int cat = tkid[tile * GSZ + tid];
    cats[tid] = cat;
    __syncthreads();
    int rank = 0;
    for (int j = 0; j < tid; ++j) rank += (cats[j] == cat) ? 1 : 0;
    int pos = hist[tile * NTD + cat] + rank;
    idxs[b * NTOK + pos] = gl * GSZ + tid;
}

// ---------------- window attention: block = (window, head), 256 threads ------
__global__ void __launch_bounds__(256) win_kernel(
        const bf16* __restrict__ qkv, const float* __restrict__ rpb,
        float* __restrict__ out) {
    int wid = blockIdx.x / NH;
    int h   = blockIdx.x % NH;
    int b = wid / 144;
    int wrem = wid % 144;
    int wy = wrem / 12, wx = wrem % 12;
    __shared__ float Ks[128][HD];
    __shared__ float Vs[128][HD];
    __shared__ float rb[961];
    int tid = threadIdx.x;
    int iy = tid >> 4, ix = tid & 15;
    long nq = (long)b * NTOK + (long)(wy * 16 + iy) * 192 + (wx * 16 + ix);
    const bf16* qb = qkv + nq * C3 + h * HD;
    float q[HD];
    #pragma unroll
    for (int d = 0; d < HD; ++d) q[d] = __bfloat162float(qb[d]) * 0.17677669529663687f;
    for (int i = tid; i < 961; i += 256) rb[i] = rpb[i * NH + h];
    float m = -INFINITY, l = 0.0f;
    float acc[HD];
    #pragma unroll
    for (int d = 0; d < HD; ++d) acc[d] = 0.0f;
    int st = tid >> 1, sd = (tid & 1) * 16;
    for (int t0 = 0; t0 < 256; t0 += 128) {
        __syncthreads();
        {
            int p = t0 + st;
            int py = p >> 4, px = p & 15;
            long nk = (long)b * NTOK + (long)(wy * 16 + py) * 192 + (wx * 16 + px);
            const bf16* kb = qkv + nk * C3 + CDIM + h * HD;
            const bf16* vb = kb + CDIM;
            #pragma unroll
            for (int d = 0; d < 16; ++d) {
                Ks[st][sd + d] = __bfloat162float(kb[sd + d]);
                Vs[st][sd + d] = __bfloat162float(vb[sd + d]);
            }
        }
        __syncthreads();
        for (int j = 0; j < 128; ++j) {
            float s = 0.0f;
            const float4* kr = (const float4*)Ks[j];
            #pragma unroll
            for (int d4 = 0; d4 < 8; ++d4) {
                float4 kv = kr[d4];
                s = fmaf(q[d4*4+0], kv.x, s);
                s = fmaf(q[d4*4+1], kv.y, s);
                s = fmaf(q[d4*4+2], kv.z, s);
                s = fmaf(q[d4*4+3], kv.w, s);
            }
            int jg = t0 + j;
            int jy = jg >> 4, jx = jg & 15;
            s += rb[(iy - jy + 15) * 31 + (ix - jx + 15)];
            float mn = fmaxf(m, s);
            float p  = expf(s - mn);
            float sc = expf(m - mn);
            l = l * sc + p;
            const float4* vr = (const float4*)Vs[j];
            #pragma unroll
            for (int d4 = 0; d4 < 8; ++d4) {
                float4 vv = vr[d4];
                acc[d4*4+0] = fmaf(acc[d4*4+0], sc, p * vv.x);
                acc[d4*4+1] = fmaf(acc[d4*4+1], sc, p * vv.y);
                acc[d4*4+2] = fmaf(acc[d4*4+2], sc, p * vv.z);
                acc[d4*4+3] = fmaf(acc[d4*4+3], sc, p * vv.w);
            }
            m = mn;
        }
    }
    float inv = 1.0f / l;
    float* orow = out + nq * CDIM + h * HD;
    #pragma unroll
    for (int d4 = 0; d4 < 8; ++d4) {
        float4 o4;
        o4.x = acc[d4*4+0] * inv;
        o4.y = acc[d4*4+1] * inv;
        o4.z = acc[d4*4+2] * inv;
        o4.w = acc[d4*4+3] * inv;
        *(float4*)&orow[d4*4] = o4;
    }
}

// ---------------- AC-MSA attention: block = (group, head), 128 threads -------
__global__ void __launch_bounds__(128) aca_kernel(
        const bf16* __restrict__ qkv, const int* __restrict__ idxs,
        float* __restrict__ out) {
    int grp = blockIdx.x / NH;
    int h   = blockIdx.x % NH;
    int b = grp / NGRP;
    int g = grp % NGRP;
    __shared__ float Ks[GSZ][HD];
    __shared__ float Vs[GSZ][HD];
    int tid = threadIdx.x;
    int tokb = idxs[b * NTOK + g * GSZ + tid];
    long n = (long)b * NTOK + tokb;
    const bf16* base = qkv + n * C3;
    float q[HD];
    #pragma unroll
    for (int d = 0; d < HD; ++d) {
        q[d] = __bfloat162float(base[h * HD + d]) * 0.17677669529663687f;
        Ks[tid][d] = __bfloat162float(base[CDIM     + h * HD + d]);
        Vs[tid][d] = __bfloat162float(base[2 * CDIM + h * HD + d]);
    }
    __syncthreads();
    float m = -INFINITY, l = 0.0f;
    float acc[HD];
    #pragma unroll
    for (int d = 0; d < HD; ++d) acc[d] = 0.0f;
    for (int j = 0; j < GSZ; ++j) {
        float s = 0.0f;
        const float4* kr = (const float4*)Ks[j];
        #pragma unroll
        for (int d4 = 0; d4 < 8; ++d4) {
            float4 kv = kr[d4];
            s = fmaf(q[d4*4+0], kv.x, s);
            s = fmaf(q[d4*4+1], kv.y, s);
            s = fmaf(q[d4*4+2], kv.z, s);
            s = fmaf(q[d4*4+3], kv.w, s);
        }
        float mn = fmaxf(m, s);
        float p  = expf(s - mn);
        float sc = expf(m - mn);
        l = l * sc + p;
        const float4* vr = (const float4*)Vs[j];
        #pragma unroll
        for (int d4 = 0; d4 < 8; ++d4) {
            float4 vv = vr[d4];
            acc[d4*4+0] = fmaf(acc[d4*4+0], sc, p * vv.x);
            acc[d4*4+1] = fmaf(acc[d4*4+1], sc, p * vv.y);
            acc[d4*4+2] = fmaf(acc[d4*4+2], sc, p * vv.z);
            acc[d4*4+3] = fmaf(acc[d4*4+3], sc, p * vv.w);
        }
        m = mn;
    }
    float inv = 1.0f / l;
    float* orow = out + n * CDIM + h * HD;
    #pragma unroll
    for (int d4 = 0; d4 < 8; ++d4) {
        float4 o4;
        o4.x = acc[d4*4+0] * inv;
        o4.y = acc[d4*4+1] * inv;
        o4.z = acc[d4*4+2] * inv;
        o4.w = acc[d4*4+3] * inv;
        *(float4*)&orow[d4*4] = o4;
    }
}

// ---------------- x_td -> y[:, 384:432] copy (f32 -> bf16) -------------------
__global__ void xtdcopy_kernel(const float* __restrict__ xtd, bf16* __restrict__ y) {
    long i = (long)blockIdx.x * 256 + threadIdx.x;
    long ntk = i / TDF;
    int c = (int)(i - ntk * TDF);
    y[ntk * CH + MLP + c] = __float2bfloat16(xtd[i]);
}

// ---------------- depthwise 5x5 conv + gelu + residual over a 144-ch chunk ---
#define YSLD 401
__global__ void __launch_bounds__(256) conv_kernel(
        const bf16* __restrict__ y, const float* __restrict__ dw,
        float* __restrict__ z, int z0) {
    int bid = blockIdx.x;
    int ck   = bid % 6;
    int tile = (bid / 6) % 144;
    int b    = bid / (6 * 144);
    int ty = tile / 12, tx = tile % 12;
    int c0 = z0 + ck * 24;
    __shared__ float ys[24 * YSLD];
    __shared__ float wt[24 * 25];
    int tid = threadIdx.x;
    const bf16* yb = y + (long)b * NTOK * CH;
    for (int e = tid; e < 20 * 20 * 24; e += 256) {
        int p = e / 24, c = e - p * 24;
        int ly = p / 20, lx = p - ly * 20;
        int gy = ty * 16 + ly - 2, gx = tx * 16 + lx - 2;
        float v = 0.0f;
        if (gy >= 0 && gy < 192 && gx >= 0 && gx < 192)
            v = __bfloat162float(yb[(long)(gy * 192 + gx) * CH + c0 + c]);
        ys[c * YSLD + p] = v;
    }
    for (int e = tid; e < 24 * 25; e += 256)
        wt[e] = dw[(c0 + e / 25) * 25 + (e % 25)];
    __syncthreads();
    int py = tid >> 4, px = tid & 15;
    long obase = ((long)b * NTOK + (long)(ty * 16 + py) * 192 + (tx * 16 + px)) * 144 + ck * 24;
    for (int c = 0; c < 24; ++c) {
        const float* yc = &ys[c * YSLD];
        float a = 0.0f;
        #pragma unroll
        for (int dy = 0; dy < 5; ++dy)
            #pragma unroll
            for (int dx = 0; dx < 5; ++dx)
                a = fmaf(yc[(py + dy) * 20 + (px + dx)], wt[c * 25 + dy * 5 + dx], a);
        float center = yc[(py + 2) * 20 + (px + 2)];
        z[obase + c] = center + gelu_f(a);
    }
}

// =============================================================================
extern "C" void kernel_launch(void* const* d_in, const int* in_sizes, int n_in,
                              void* d_out, int out_size, void* d_ws, size_t ws_size,
                              hipStream_t stream) {
    (void)in_sizes; (void)n_in; (void)out_size; (void)ws_size;
    const float* x     = (const float*)d_in[0];
    const float* td    = (const float*)d_in[1];
    const float* n1g   = (const float*)d_in[2];
    const float* n1b   = (const float*)d_in[3];
    const float* n2g   = (const float*)d_in[4];
    const float* n2b   = (const float*)d_in[5];
    const float* wqkv  = (const float*)d_in[6];
    const float* rpb   = (const float*)d_in[7];
    const float* wproj = (const float*)d_in[8];
    const float* awq   = (const float*)d_in[9];
    const float* awk   = (const float*)d_in[10];
    const float* awv   = (const float*)d_in[11];
    const float* ascl  = (const float*)d_in[12];
    const float* aproj = (const float*)d_in[13];
    const float* fcw   = (const float*)d_in[14];
    const float* w1    = (const float*)d_in[15];
    const float* dw    = (const float*)d_in[16];
    const float* w2    = (const float*)d_in[17];
    float* out = (float*)d_out;

    char* ws = (char*)d_ws;
    size_t off = 0;
    auto alloc = [&](size_t bytes) -> char* {
        char* p = ws + off;
        off += (bytes + 255) & ~(size_t)255;
        return p;
    };
    bf16*  qkv  = (bf16*)alloc((size_t)NTOT * C3 * 2);      // R0, later y
    float* xn   = (float*)alloc((size_t)NTOT * CDIM * 4);   // R1: xn/raw/xn2
    float* qn   = (float*)alloc((size_t)NTOT * RD * 4);     // R2 head
    float* simb = (float*)alloc((size_t)NTOT * NTD * 4);
    float* xtd  = (float*)alloc((size_t)NTOT * TDF * 4);
    float* kn   = (float*)alloc((size_t)2 * NTD * RD * 4);
    float* vtd  = (float*)alloc((size_t)2 * NTD * CDIM * 4);
    float* tdf  = (float*)alloc((size_t)2 * NTD * TDF * 4);
    int*   tkid = (int*)alloc((size_t)NTOT * 4);
    int*   idxs = (int*)alloc((size_t)NTOT * 4);
    int*   hist = (int*)alloc((size_t)576 * NTD * 4);
    bf16*  y    = qkv;
    float* raw  = xn;
    float* xn2  = xn;
    float* z    = qn;     // 42.5 MB <= qn+simb

    hipMemcpyAsync(out, x, (size_t)NTOT * CDIM * 4, hipMemcpyDeviceToDevice, stream);

    // LN1
    ln_kernel<<<NTOT / 4, 256, 0, stream>>>(x, n1g, n1b, xn);

    // qkv (bf16) = xn @ wqkv  [MFMA]
    gemm_mfma<0,0,1><<<dim3(9, 576), 256, 0, stream>>>(xn, wqkv, qkv, NTOT, C3, CDIM, CDIM, C3, C3);
    // qn stays f32 (feeds discrete argmax path)
    gemm_kernel<0,0,0><<<dim3(1, 1152), 256, 0, stream>>>(xn, awq, qn, NTOT, RD, CDIM, CDIM, RD, RD);
    gemm_kernel<0,0,0><<<dim3(1, 4), 256, 0, stream>>>(td, awk, kn, 2 * NTD, RD, CDIM, CDIM, RD, RD);
    gemm_kernel<0,0,0><<<dim3(3, 4), 256, 0, stream>>>(td, awv, vtd, 2 * NTD, CDIM, CDIM, CDIM, CDIM, CDIM);
    gemm_kernel<0,0,0><<<dim3(1, 4), 256, 0, stream>>>(td, fcw, tdf, 2 * NTD, TDF, CDIM, CDIM, TDF, TDF);

    l2n_kernel<<<(NTOT + 255) / 256, 256, 0, stream>>>(qn, NTOT);
    l2n_kernel<<<1, 256, 0, stream>>>(kn, 2 * NTD);

    sim_kernel<<<NTOT, 128, 0, stream>>>(qn, kn, ascl, simb, tkid);

    // d_out += sim @ vtd ; xtd = sim @ tdf  [MFMA]
    for (int b = 0; b < 2; ++b) {
        gemm_mfma<1,0,0><<<dim3(3, 288), 256, 0, stream>>>(
            simb + (size_t)b * NTOK * NTD, vtd + (size_t)b * NTD * CDIM,
            out + (size_t)b * NTOK * CDIM, NTOK, CDIM, NTD, NTD, CDIM, CDIM);
        gemm_mfma<0,0,0><<<dim3(1, 288), 256, 0, stream>>>(
            simb + (size_t)b * NTOK * NTD, tdf + (size_t)b * NTD * TDF,
            xtd + (size_t)b * NTOK * TDF, NTOK, TDF, NTD, NTD, TDF, TDF);
    }

    hist_kernel<<<576, 128, 0, stream>>>(tkid, hist);
    scan_kernel<<<2, 128, 0, stream>>>(hist);
    scatter_kernel<<<576, 128, 0, stream>>>(tkid, hist, idxs);

    // window attention -> raw, then d_out += raw @ win_proj  [MFMA]
    win_kernel<<<288 * NH, 256, 0, stream>>>(qkv, rpb, raw);
    gemm_mfma<1,0,0><<<dim3(3, 576), 256, 0, stream>>>(raw, wproj, out, NTOT, CDIM, CDIM, CDIM, CDIM, CDIM);

    // AC-MSA -> raw, then d_out += raw @ aca_proj  [MFMA]
    aca_kernel<<<576 * NH, 128, 0, stream>>>(qkv, idxs, raw);
    gemm_mfma<1,0,0><<<dim3(3, 576), 256, 0, stream>>>(raw, aproj, out, NTOT, CDIM, CDIM, CDIM, CDIM, CDIM);

    // LN2; qkv dead, R0 becomes y
    ln_kernel<<<NTOT / 4, 256, 0, stream>>>(out, n2g, n2b, xn2);

    // y[:, :384] = gelu(xn2 @ w1) (bf16)  [MFMA]; y[:, 384:432] = x_td
    gemm_mfma<0,1,1><<<dim3(6, 576), 256, 0, stream>>>(xn2, w1, y, NTOT, MLP, CDIM, CDIM, MLP, CH);
    xtdcopy_kernel<<<(NTOT * TDF) / 256, 256, 0, stream>>>(xtd, y);

    // conv chunks + w2 GEMM chunks (K=144, zero-padded)  [MFMA]
    for (int c = 0; c < 3; ++c) {
        int z0 = c * 144;
        conv_kernel<<<2 * 144 * 6, 256, 0, stream>>>(y, dw, z, z0);
        gemm_mfma<1,0,0><<<dim3(3, 576), 256, 0, stream>>>(
            z, w2 + (size_t)z0 * CDIM, out, NTOT, CDIM, 144, 144, CDIM, CDIM);
    }
}

// Round 4
// 1284.719 us; speedup vs baseline: 1.7164x; 1.2856x over previous
//
#include <hip/hip_runtime.h>
#include <hip/hip_bf16.h>
#include <math.h>

#define NTOK 36864   // tokens per batch (192*192)
#define NTOT 73728   // total tokens (B=2)
#define CDIM 192
#define C3   576
#define NH   6
#define HD   32
#define RD   20
#define NTD  128     // dictionary tokens
#define GSZ  128     // ac-msa group size
#define NGRP 288     // groups per batch
#define MLP  384
#define TDF  48
#define CH   432     // MLP+TDF

typedef __hip_bfloat16 bf16;
typedef __attribute__((ext_vector_type(8))) short short8;
typedef __attribute__((ext_vector_type(4))) float f32x4;

__device__ __forceinline__ float gelu_f(float x) {
    return 0.5f * x * (1.0f + erff(x * 0.7071067811865475f));
}

__device__ __forceinline__ unsigned short f32_to_bf16u(float f) {
    unsigned int u = __float_as_uint(f);
    u = (u + 0x7FFFu + ((u >> 16) & 1u)) >> 16;   // RNE
    return (unsigned short)u;
}

// ---------------- LayerNorm: one wave per token, 4 tokens per block ----------
__global__ void ln_kernel(const float* __restrict__ x, const float* __restrict__ g,
                          const float* __restrict__ be, float* __restrict__ out) {
    long tok = (long)blockIdx.x * 4 + (threadIdx.x >> 6);
    int lane = threadIdx.x & 63;
    const float* row = x + tok * CDIM;
    float v0 = row[lane], v1 = row[lane + 64], v2 = row[lane + 128];
    float s  = v0 + v1 + v2;
    float ss = v0 * v0 + v1 * v1 + v2 * v2;
    #pragma unroll
    for (int o = 32; o > 0; o >>= 1) {
        s  += __shfl_down(s, o);
        ss += __shfl_down(ss, o);
    }
    s = __shfl(s, 0); ss = __shfl(ss, 0);
    float mean = s * (1.0f / 192.0f);
    float var  = ss * (1.0f / 192.0f) - mean * mean;
    float rstd = rsqrtf(var + 1e-5f);
    float* orow = out + tok * CDIM;
    orow[lane]       = (v0 - mean) * rstd * g[lane]       + be[lane];
    orow[lane + 64]  = (v1 - mean) * rstd * g[lane + 64]  + be[lane + 64];
    orow[lane + 128] = (v2 - mean) * rstd * g[lane + 128] + be[lane + 128];
}

// ---------------- bf16 MFMA GEMM: C(M,N) (+)= A(M,K) @ B(K,N) ----------------
// f32 inputs, converted to bf16 during LDS staging. 128x64 tile, 4 waves 2x2,
// BK=64, K zero-padded. M must be a multiple of 128. LDS 27.6 KB.
#define LDT 72   // padded stride in bf16 units (144 B)
template<int ACC, int GELU, int BF16OUT>
__global__ void __launch_bounds__(256) gemm_mfma(
        const float* __restrict__ A, const float* __restrict__ B,
        void* __restrict__ Cv, int M, int N, int K, int lda, int ldb, int ldc) {
    __shared__ short As[128 * LDT];
    __shared__ short Bs[64 * LDT];
    int tid  = threadIdx.x;
    int lane = tid & 63;
    int w    = tid >> 6;
    int wr = w >> 1, wc = w & 1;
    int row0 = blockIdx.y * 128, col0 = blockIdx.x * 64;
    int fr = lane & 15, fq = lane >> 4;
    f32x4 acc[4][2];
    #pragma unroll
    for (int m = 0; m < 4; ++m)
        #pragma unroll
        for (int n = 0; n < 2; ++n) acc[m][n] = (f32x4)(0.0f);

    int sa_row = tid >> 3;          // 0..31
    int sa_kc  = (tid & 7) * 8;     // 0..56
    int sb_col = tid & 63;
    int sb_kb  = (tid >> 6) * 16;   // 0,16,32,48
    bool cok = (col0 + sb_col) < N;

    for (int k0 = 0; k0 < K; k0 += 64) {
        __syncthreads();
        #pragma unroll
        for (int p = 0; p < 4; ++p) {
            int r = sa_row + p * 32;
            const float* src = A + (long)(row0 + r) * lda + k0 + sa_kc;
            short8 v;
            if (k0 + sa_kc + 8 <= K) {
                float4 f0 = *(const float4*)&src[0];
                float4 f1 = *(const float4*)&src[4];
                v[0] = (short)f32_to_bf16u(f0.x); v[1] = (short)f32_to_bf16u(f0.y);
                v[2] = (short)f32_to_bf16u(f0.z); v[3] = (short)f32_to_bf16u(f0.w);
                v[4] = (short)f32_to_bf16u(f1.x); v[5] = (short)f32_to_bf16u(f1.y);
                v[6] = (short)f32_to_bf16u(f1.z); v[7] = (short)f32_to_bf16u(f1.w);
            } else {
                #pragma unroll
                for (int i = 0; i < 8; ++i) {
                    float f = (k0 + sa_kc + i < K) ? src[i] : 0.0f;
                    v[i] = (short)f32_to_bf16u(f);
                }
            }
            *(short8*)&As[r * LDT + sa_kc] = v;
        }
        {
            short8 v0, v1;
            #pragma unroll
            for (int i = 0; i < 16; ++i) {
                int k = sb_kb + i;
                float f = (cok && (k0 + k) < K)
                          ? B[(long)(k0 + k) * ldb + col0 + sb_col] : 0.0f;
                unsigned short h = f32_to_bf16u(f);
                if (i < 8) v0[i] = (short)h; else v1[i - 8] = (short)h;
            }
            *(short8*)&Bs[sb_col * LDT + sb_kb]     = v0;
            *(short8*)&Bs[sb_col * LDT + sb_kb + 8] = v1;
        }
        __syncthreads();
        short8 af[4][2], bf_[2][2];
        #pragma unroll
        for (int m = 0; m < 4; ++m) {
            int r = wr * 64 + m * 16 + fr;
            af[m][0] = *(const short8*)&As[r * LDT + fq * 8];
            af[m][1] = *(const short8*)&As[r * LDT + 32 + fq * 8];
        }
        #pragma unroll
        for (int n = 0; n < 2; ++n) {
            int c = wc * 32 + n * 16 + fr;
            bf_[n][0] = *(const short8*)&Bs[c * LDT + fq * 8];
            bf_[n][1] = *(const short8*)&Bs[c * LDT + 32 + fq * 8];
        }
        #pragma unroll
        for (int m = 0; m < 4; ++m)
            #pragma unroll
            for (int n = 0; n < 2; ++n) {
                acc[m][n] = __builtin_amdgcn_mfma_f32_16x16x32_bf16(
                                af[m][0], bf_[n][0], acc[m][n], 0, 0, 0);
                acc[m][n] = __builtin_amdgcn_mfma_f32_16x16x32_bf16(
                                af[m][1], bf_[n][1], acc[m][n], 0, 0, 0);
            }
    }
    #pragma unroll
    for (int m = 0; m < 4; ++m) {
        #pragma unroll
        for (int n = 0; n < 2; ++n) {
            int gc = col0 + wc * 32 + n * 16 + fr;
            if (gc >= N) continue;
            #pragma unroll
            for (int r = 0; r < 4; ++r) {
                int gr = row0 + wr * 64 + m * 16 + fq * 4 + r;
                float vv = acc[m][n][r];
                if (GELU) vv = gelu_f(vv);
                long o = (long)gr * ldc + gc;
                if (BF16OUT) {
                    ((bf16*)Cv)[o] = __float2bfloat16(vv);
                } else {
                    float* Cc = (float*)Cv;
                    if (ACC) Cc[o] += vv; else Cc[o] = vv;
                }
            }
        }
    }
}

// ---------------- Generic tiled f32 GEMM (small / precision-critical) --------
template<int ACC, int GELU, int BF16OUT>
__global__ void __launch_bounds__(256) gemm_kernel(
        const float* __restrict__ A, const float* __restrict__ B,
        void* __restrict__ Cv, int M, int N, int K, int lda, int ldb, int ldc) {
    __shared__ float As[16][68];
    __shared__ float Bs[16][68];
    int tid = threadIdx.x;
    int tr = tid >> 4, tc = tid & 15;
    int row0 = blockIdx.y * 64, col0 = blockIdx.x * 64;
    float acc[4][4] = {};
    int lm = tid >> 4;
    int lk = tid & 15;
    int bk = tid >> 6;
    int bn = tid & 63;
    for (int k0 = 0; k0 < K; k0 += 16) {
        #pragma unroll
        for (int i = 0; i < 4; ++i) {
            int m = lm + i * 16;
            int gr = row0 + m;
            As[lk][m] = (gr < M) ? A[(long)gr * lda + (k0 + lk)] : 0.0f;
        }
        #pragma unroll
        for (int i = 0; i < 4; ++i) {
            int kk = bk + i * 4;
            int gc = col0 + bn;
            Bs[kk][bn] = (gc < N) ? B[(long)(k0 + kk) * ldb + gc] : 0.0f;
        }
        __syncthreads();
        #pragma unroll
        for (int kk = 0; kk < 16; ++kk) {
            float4 av = *(const float4*)&As[kk][tr * 4];
            float4 bv = *(const float4*)&Bs[kk][tc * 4];
            float a[4] = {av.x, av.y, av.z, av.w};
            float b[4] = {bv.x, bv.y, bv.z, bv.w};
            #pragma unroll
            for (int i = 0; i < 4; ++i)
                #pragma unroll
                for (int j = 0; j < 4; ++j)
                    acc[i][j] = fmaf(a[i], b[j], acc[i][j]);
        }
        __syncthreads();
    }
    #pragma unroll
    for (int i = 0; i < 4; ++i) {
        int gr = row0 + tr * 4 + i;
        if (gr >= M) continue;
        #pragma unroll
        for (int j = 0; j < 4; ++j) {
            int gc = col0 + tc * 4 + j;
            if (gc >= N) continue;
            float v = acc[i][j];
            if (GELU) v = gelu_f(v);
            long o = (long)gr * ldc + gc;
            if (BF16OUT) {
                ((bf16*)Cv)[o] = __float2bfloat16(v);
            } else {
                float* Cc = (float*)Cv;
                if (ACC) Cc[o] += v; else Cc[o] = v;
            }
        }
    }
}

// ---------------- row-wise L2 normalize (RD=20), in place --------------------
__global__ void l2n_kernel(float* __restrict__ d, int nrows) {
    int i = blockIdx.x * blockDim.x + threadIdx.x;
    if (i >= nrows) return;
    float* r = d + (long)i * RD;
    float ss = 0.0f;
    #pragma unroll
    for (int k = 0; k < RD; ++k) ss += r[k] * r[k];
    float inv = 1.0f / fmaxf(sqrtf(ss), 1e-12f);
    #pragma unroll
    for (int k = 0; k < RD; ++k) r[k] *= inv;
}

// ---------------- ATD similarity softmax + argmax (block = token) ------------
__global__ void __launch_bounds__(128) sim_kernel(
        const float* __restrict__ qn, const float* __restrict__ kn,
        const float* __restrict__ scale_p, float* __restrict__ sim,
        int* __restrict__ tkid) {
    int tok = blockIdx.x;
    int b = tok / NTOK;
    int j = threadIdx.x;
    __shared__ float qv[RD];
    __shared__ float wred[4];
    __shared__ int   wredi[2];
    if (j < RD) qv[j] = qn[(long)tok * RD + j];
    __syncthreads();
    const float* kr = kn + ((long)b * NTD + j) * RD;
    float s = 0.0f;
    #pragma unroll
    for (int r = 0; r < RD; ++r) s = fmaf(qv[r], kr[r], s);
    float scl = 1.0f + fminf(fmaxf(scale_p[0], 0.0f), 3.0f) * logf(128.0f);
    s *= scl;
    float m = s; int mi = j;
    #pragma unroll
    for (int o = 32; o > 0; o >>= 1) {
        float om = __shfl_down(m, o); int oi = __shfl_down(mi, o);
        if (om > m || (om == m && oi < mi)) { m = om; mi = oi; }
    }
    int wv = j >> 6;
    if ((j & 63) == 0) { wred[wv] = m; wredi[wv] = mi; }
    __syncthreads();
    float m0 = wred[0], m1 = wred[1];
    float gm; int gi;
    if (m1 > m0) { gm = m1; gi = wredi[1]; } else { gm = m0; gi = wredi[0]; }
    float p = expf(s - gm);
    float t = p;
    #pragma unroll
    for (int o = 32; o > 0; o >>= 1) t += __shfl_down(t, o);
    if ((j & 63) == 0) wred[2 + wv] = t;
    __syncthreads();
    float tot = wred[2] + wred[3];
    sim[(long)tok * NTD + j] = p / tot;
    if (j == 0) tkid[tok] = gi;
}

// ---------------- stable counting sort: hist / scan / scatter ----------------
__global__ void hist_kernel(const int* __restrict__ tkid, int* __restrict__ hist) {
    int tile = blockIdx.x;
    int tid = threadIdx.x;
    __shared__ int h[NTD];
    h[tid] = 0;
    __syncthreads();
    atomicAdd(&h[tkid[tile * GSZ + tid]], 1);
    __syncthreads();
    hist[tile * NTD + tid] = h[tid];
}

__global__ void scan_kernel(int* __restrict__ hist) {
    int b = blockIdx.x;
    int c = threadIdx.x;
    __shared__ int tot[NTD];
    __shared__ int base[NTD];
    int run = 0;
    for (int t = 0; t < NGRP; ++t) {
        int id = (b * NGRP + t) * NTD + c;
        int v = hist[id];
        hist[id] = run;
        run += v;
    }
    tot[c] = run;
    __syncthreads();
    if (c == 0) {
        int a = 0;
        for (int i = 0; i < NTD; ++i) { base[i] = a; a += tot[i]; }
    }
    __syncthreads();
    int bc = base[c];
    for (int t = 0; t < NGRP; ++t)
        hist[(b * NGRP + t) * NTD + c] += bc;
}

__global__ void scatter_kernel(const int* __restrict__ tkid, const int* __restrict__ hist,
                               int* __restrict__ idxs) {
    int tile = blockIdx.x;
    int b = tile / NGRP;
    int gl = tile % NGRP;
    int tid = threadIdx.x;
    __shared__ int cats[GSZ];
    int cat = tkid[tile * GSZ + tid];
    cats[tid] = cat;
    __syncthreads();
    int rank = 0;
    for (int j = 0; j < tid; ++j) rank += (cats[j] == cat) ? 1 : 0;
    int pos = hist[tile * NTD + cat] + rank;
    idxs[b * NTOK + pos] = gl * GSZ + tid;
}

// ---------------- MFMA window attention: block = (window, head) --------------
// 256 threads = 4 waves x 64 q-rows. KV tiles of 64. LDS ~49.3 KB.
#define PLD 72   // P/V row stride in bf16 (144 B, 16B-aligned)
__global__ void __launch_bounds__(256) win_mfma(
        const bf16* __restrict__ qkv, const float* __restrict__ rpb,
        float* __restrict__ out) {
    int wid = blockIdx.x / NH;
    int h   = blockIdx.x % NH;
    int b = wid / 144;
    int wrem = wid % 144;
    int wy = wrem / 12, wx = wrem % 12;
    long base_tok = (long)b * NTOK;

    __shared__ short Kt[64 * 40];
    __shared__ short Vt[32 * PLD];
    __shared__ short Pl[4][64 * PLD];
    __shared__ float rb[961];

    int tid = threadIdx.x;
    int lane = tid & 63;
    int wv = tid >> 6;
    int fr = lane & 15, fq = lane >> 4;
    const float scl = 0.17677669529663687f;

    for (int i = tid; i < 961; i += 256) rb[i] = rpb[i * NH + h];

    // Q fragments (A-layout: row=fr, k=8*fq+j), rows wv*64..wv*64+63
    short8 qf[4];
    #pragma unroll
    for (int m = 0; m < 4; ++m) {
        int qrow = wv * 64 + m * 16 + fr;
        long nq = base_tok + (long)(wy * 16 + (qrow >> 4)) * 192 + (wx * 16 + (qrow & 15));
        qf[m] = *(const short8*)(qkv + nq * C3 + h * HD + fq * 8);
    }

    f32x4 acc[4][2];
    float mrow[4][4], lrow[4][4];
    #pragma unroll
    for (int m = 0; m < 4; ++m) {
        acc[m][0] = (f32x4)(0.0f); acc[m][1] = (f32x4)(0.0f);
        #pragma unroll
        for (int r = 0; r < 4; ++r) { mrow[m][r] = -INFINITY; lrow[m][r] = 0.0f; }
    }

    for (int t = 0; t < 4; ++t) {
        __syncthreads();
        {   // stage K[64][32] row-major (pad 40) and V^T[32][64] (pad PLD)
            int s = tid >> 2, ch = tid & 3;
            int p = t * 64 + s;
            long nk = base_tok + (long)(wy * 16 + (p >> 4)) * 192 + (wx * 16 + (p & 15));
            const bf16* kb = qkv + nk * C3 + CDIM + h * HD + ch * 8;
            *(short8*)&Kt[s * 40 + ch * 8] = *(const short8*)kb;
            short8 vv = *(const short8*)(kb + CDIM);
            #pragma unroll
            for (int i = 0; i < 8; ++i)
                Vt[(ch * 8 + i) * PLD + s] = vv[i];
        }
        __syncthreads();

        // ---- S = Q @ K^T, bias, online softmax, P -> LDS ----
        short8 bk[4];
        #pragma unroll
        for (int c = 0; c < 4; ++c)
            bk[c] = *(const short8*)&Kt[(c * 16 + fr) * 40 + fq * 8];
        #pragma unroll
        for (int m = 0; m < 4; ++m) {
            float sf[4][4];
            #pragma unroll
            for (int c = 0; c < 4; ++c) {
                f32x4 s4 = (f32x4)(0.0f);
                s4 = __builtin_amdgcn_mfma_f32_16x16x32_bf16(qf[m], bk[c], s4, 0, 0, 0);
                int j = t * 64 + c * 16 + fr;
                int jy = j >> 4, jx = j & 15;
                #pragma unroll
                for (int r = 0; r < 4; ++r) {
                    int qrow = wv * 64 + m * 16 + 4 * fq + r;
                    sf[c][r] = s4[r] * scl
                             + rb[((qrow >> 4) - jy + 15) * 31 + ((qrow & 15) - jx + 15)];
                }
            }
            #pragma unroll
            for (int r = 0; r < 4; ++r) {
                float tmax = fmaxf(fmaxf(sf[0][r], sf[1][r]), fmaxf(sf[2][r], sf[3][r]));
                #pragma unroll
                for (int o = 1; o < 16; o <<= 1) tmax = fmaxf(tmax, __shfl_xor(tmax, o));
                float mo = mrow[m][r];
                float mn = fmaxf(mo, tmax);
                float sc_ = expf(mo - mn);
                mrow[m][r] = mn;
                float ps = 0.0f;
                #pragma unroll
                for (int c = 0; c < 4; ++c) {
                    float p = expf(sf[c][r] - mn);
                    sf[c][r] = p;
                    ps += p;
                }
                #pragma unroll
                for (int o = 1; o < 16; o <<= 1) ps += __shfl_xor(ps, o);
                lrow[m][r] = lrow[m][r] * sc_ + ps;
                acc[m][0][r] *= sc_;
                acc[m][1][r] *= sc_;
            }
            #pragma unroll
            for (int c = 0; c < 4; ++c)
                #pragma unroll
                for (int r = 0; r < 4; ++r)
                    Pl[wv][(m * 16 + 4 * fq + r) * PLD + c * 16 + fr] =
                        (short)f32_to_bf16u(sf[c][r]);
        }
        // ---- O += P @ V ----
        short8 bv[2][2];
        #pragma unroll
        for (int n = 0; n < 2; ++n)
            #pragma unroll
            for (int ks = 0; ks < 2; ++ks)
                bv[n][ks] = *(const short8*)&Vt[(n * 16 + fr) * PLD + ks * 32 + fq * 8];
        #pragma unroll
        for (int m = 0; m < 4; ++m)
            #pragma unroll
            for (int ks = 0; ks < 2; ++ks) {
                short8 pa = *(const short8*)&Pl[wv][(m * 16 + fr) * PLD + ks * 32 + fq * 8];
                #pragma unroll
                for (int n = 0; n < 2; ++n)
                    acc[m][n] = __builtin_amdgcn_mfma_f32_16x16x32_bf16(
                                    pa, bv[n][ks], acc[m][n], 0, 0, 0);
            }
    }
    // epilogue
    #pragma unroll
    for (int m = 0; m < 4; ++m)
        #pragma unroll
        for (int r = 0; r < 4; ++r) {
            int qrow = wv * 64 + m * 16 + 4 * fq + r;
            long nq = base_tok + (long)(wy * 16 + (qrow >> 4)) * 192 + (wx * 16 + (qrow & 15));
            float inv = 1.0f / lrow[m][r];
            float* orow = out + nq * CDIM + h * HD + fr;
            orow[0]  = acc[m][0][r] * inv;
            orow[16] = acc[m][1][r] * inv;
        }
}

// ---------------- MFMA AC-MSA attention: block = (group, head) ---------------
// 128 threads = 2 waves x 64 q-rows. 2 KV tiles of 64. LDS ~28 KB.
__global__ void __launch_bounds__(128) aca_mfma(
        const bf16* __restrict__ qkv, const int* __restrict__ idxs,
        float* __restrict__ out) {
    int grp = blockIdx.x / NH;
    int h   = blockIdx.x % NH;
    int b = grp / NGRP;
    int g = grp % NGRP;
    long btok = (long)b * NTOK;

    __shared__ short Kt[64 * 40];
    __shared__ short Vt[32 * PLD];
    __shared__ short Pl[2][64 * PLD];
    __shared__ int   sidx[GSZ];

    int tid = threadIdx.x;
    int lane = tid & 63;
    int wv = tid >> 6;
    int fr = lane & 15, fq = lane >> 4;
    const float scl = 0.17677669529663687f;

    sidx[tid] = idxs[btok + g * GSZ + tid];
    __syncthreads();

    short8 qf[4];
    #pragma unroll
    for (int m = 0; m < 4; ++m) {
        long n = btok + sidx[wv * 64 + m * 16 + fr];
        qf[m] = *(const short8*)(qkv + n * C3 + h * HD + fq * 8);
    }

    f32x4 acc[4][2];
    float mrow[4][4], lrow[4][4];
    #pragma unroll
    for (int m = 0; m < 4; ++m) {
        acc[m][0] = (f32x4)(0.0f); acc[m][1] = (f32x4)(0.0f);
        #pragma unroll
        for (int r = 0; r < 4; ++r) { mrow[m][r] = -INFINITY; lrow[m][r] = 0.0f; }
    }

    for (int t = 0; t < 2; ++t) {
        __syncthreads();
        {   // stage gathered K/V tile: thread = (token s, d-half hf)
            int s = tid & 63, hf = tid >> 6;
            int d0 = hf * 16;
            long n = btok + sidx[t * 64 + s];
            const bf16* kb = qkv + n * C3 + CDIM + h * HD + d0;
            *(short8*)&Kt[s * 40 + d0]     = *(const short8*)kb;
            *(short8*)&Kt[s * 40 + d0 + 8] = *(const short8*)(kb + 8);
            short8 v0 = *(const short8*)(kb + CDIM);
            short8 v1 = *(const short8*)(kb + CDIM + 8);
            #pragma unroll
            for (int i = 0; i < 8; ++i) {
                Vt[(d0 + i) * PLD + s]     = v0[i];
                Vt[(d0 + 8 + i) * PLD + s] = v1[i];
            }
        }
        __syncthreads();

        short8 bk[4];
        #pragma unroll
        for (int c = 0; c < 4; ++c)
            bk[c] = *(const short8*)&Kt[(c * 16 + fr) * 40 + fq * 8];
        #pragma unroll
        for (int m = 0; m < 4; ++m) {
            float sf[4][4];
            #pragma unroll
            for (int c = 0; c < 4; ++c) {
                f32x4 s4 = (f32x4)(0.0f);
                s4 = __builtin_amdgcn_mfma_f32_16x16x32_bf16(qf[m], bk[c], s4, 0, 0, 0);
                #pragma unroll
                for (int r = 0; r < 4; ++r) sf[c][r] = s4[r] * scl;
            }
            #pragma unroll
            for (int r = 0; r < 4; ++r) {
                float tmax = fmaxf(fmaxf(sf[0][r], sf[1][r]), fmaxf(sf[2][r], sf[3][r]));
                #pragma unroll
                for (int o = 1; o < 16; o <<= 1) tmax = fmaxf(tmax, __shfl_xor(tmax, o));
                float mo = mrow[m][r];
                float mn = fmaxf(mo, tmax);
                float sc_ = expf(mo - mn);
                mrow[m][r] = mn;
                float ps = 0.0f;
                #pragma unroll
                for (int c = 0; c < 4; ++c) {
                    float p = expf(sf[c][r] - mn);
                    sf[c][r] = p;
                    ps += p;
                }
                #pragma unroll
                for (int o = 1; o < 16; o <<= 1) ps += __shfl_xor(ps, o);
                lrow[m][r] = lrow[m][r] * sc_ + ps;
                acc[m][0][r] *= sc_;
                acc[m][1][r] *= sc_;
            }
            #pragma unroll
            for (int c = 0; c < 4; ++c)
                #pragma unroll
                for (int r = 0; r < 4; ++r)
                    Pl[wv][(m * 16 + 4 * fq + r) * PLD + c * 16 + fr] =
                        (short)f32_to_bf16u(sf[c][r]);
        }
        short8 bv[2][2];
        #pragma unroll
        for (int n = 0; n < 2; ++n)
            #pragma unroll
            for (int ks = 0; ks < 2; ++ks)
                bv[n][ks] = *(const short8*)&Vt[(n * 16 + fr) * PLD + ks * 32 + fq * 8];
        #pragma unroll
        for (int m = 0; m < 4; ++m)
            #pragma unroll
            for (int ks = 0; ks < 2; ++ks) {
                short8 pa = *(const short8*)&Pl[wv][(m * 16 + fr) * PLD + ks * 32 + fq * 8];
                #pragma unroll
                for (int n = 0; n < 2; ++n)
                    acc[m][n] = __builtin_amdgcn_mfma_f32_16x16x32_bf16(
                                    pa, bv[n][ks], acc[m][n], 0, 0, 0);
            }
    }
    #pragma unroll
    for (int m = 0; m < 4; ++m)
        #pragma unroll
        for (int r = 0; r < 4; ++r) {
            long n = btok + sidx[wv * 64 + m * 16 + 4 * fq + r];
            float inv = 1.0f / lrow[m][r];
            float* orow = out + n * CDIM + h * HD + fr;
            orow[0]  = acc[m][0][r] * inv;
            orow[16] = acc[m][1][r] * inv;
        }
}

// ---------------- x_td -> y[:, 384:432] copy (f32 -> bf16) -------------------
__global__ void xtdcopy_kernel(const float* __restrict__ xtd, bf16* __restrict__ y) {
    long i = (long)blockIdx.x * 256 + threadIdx.x;
    long ntk = i / TDF;
    int c = (int)(i - ntk * TDF);
    y[ntk * CH + MLP + c] = __float2bfloat16(xtd[i]);
}

// ---------------- depthwise 5x5 conv + gelu + residual over a 144-ch chunk ---
#define YSLD 401
__global__ void __launch_bounds__(256) conv_kernel(
        const bf16* __restrict__ y, const float* __restrict__ dw,
        float* __restrict__ z, int z0) {
    int bid = blockIdx.x;
    int ck   = bid % 6;
    int tile = (bid / 6) % 144;
    int b    = bid / (6 * 144);
    int ty = tile / 12, tx = tile % 12;
    int c0 = z0 + ck * 24;
    __shared__ float ys[24 * YSLD];
    __shared__ float wt[24 * 25];
    int tid = threadIdx.x;
    const bf16* yb = y + (long)b * NTOK * CH;
    for (int e = tid; e < 20 * 20 * 24; e += 256) {
        int p = e / 24, c = e - p * 24;
        int ly = p / 20, lx = p - ly * 20;
        int gy = ty * 16 + ly - 2, gx = tx * 16 + lx - 2;
        float v = 0.0f;
        if (gy >= 0 && gy < 192 && gx >= 0 && gx < 192)
            v = __bfloat162float(yb[(long)(gy * 192 + gx) * CH + c0 + c]);
        ys[c * YSLD + p] = v;
    }
    for (int e = tid; e < 24 * 25; e += 256)
        wt[e] = dw[(c0 + e / 25) * 25 + (e % 25)];
    __syncthreads();
    int py = tid >> 4, px = tid & 15;
    long obase = ((long)b * NTOK + (long)(ty * 16 + py) * 192 + (tx * 16 + px)) * 144 + ck * 24;
    for (int c = 0; c < 24; ++c) {
        const float* yc = &ys[c * YSLD];
        float a = 0.0f;
        #pragma unroll
        for (int dy = 0; dy < 5; ++dy)
            #pragma unroll
            for (int dx = 0; dx < 5; ++dx)
                a = fmaf(yc[(py + dy) * 20 + (px + dx)], wt[c * 25 + dy * 5 + dx], a);
        float center = yc[(py + 2) * 20 + (px + 2)];
        z[obase + c] = center + gelu_f(a);
    }
}

// =============================================================================
extern "C" void kernel_launch(void* const* d_in, const int* in_sizes, int n_in,
                              void* d_out, int out_size, void* d_ws, size_t ws_size,
                              hipStream_t stream) {
    (void)in_sizes; (void)n_in; (void)out_size; (void)ws_size;
    const float* x     = (const float*)d_in[0];
    const float* td    = (const float*)d_in[1];
    const float* n1g   = (const float*)d_in[2];
    const float* n1b   = (const float*)d_in[3];
    const float* n2g   = (const float*)d_in[4];
    const float* n2b   = (const float*)d_in[5];
    const float* wqkv  = (const float*)d_in[6];
    const float* rpb   = (const float*)d_in[7];
    const float* wproj = (const float*)d_in[8];
    const float* awq   = (const float*)d_in[9];
    const float* awk   = (const float*)d_in[10];
    const float* awv   = (const float*)d_in[11];
    const float* ascl  = (const float*)d_in[12];
    const float* aproj = (const float*)d_in[13];
    const float* fcw   = (const float*)d_in[14];
    const float* w1    = (const float*)d_in[15];
    const float* dw    = (const float*)d_in[16];
    const float* w2    = (const float*)d_in[17];
    float* out = (float*)d_out;

    char* ws = (char*)d_ws;
    size_t off = 0;
    auto alloc = [&](size_t bytes) -> char* {
        char* p = ws + off;
        off += (bytes + 255) & ~(size_t)255;
        return p;
    };
    bf16*  qkv  = (bf16*)alloc((size_t)NTOT * C3 * 2);      // R0, later y
    float* xn   = (float*)alloc((size_t)NTOT * CDIM * 4);   // R1: xn/raw/xn2
    float* qn   = (float*)alloc((size_t)NTOT * RD * 4);     // R2 head
    float* simb = (float*)alloc((size_t)NTOT * NTD * 4);
    float* xtd  = (float*)alloc((size_t)NTOT * TDF * 4);
    float* kn   = (float*)alloc((size_t)2 * NTD * RD * 4);
    float* vtd  = (float*)alloc((size_t)2 * NTD * CDIM * 4);
    float* tdf  = (float*)alloc((size_t)2 * NTD * TDF * 4);
    int*   tkid = (int*)alloc((size_t)NTOT * 4);
    int*   idxs = (int*)alloc((size_t)NTOT * 4);
    int*   hist = (int*)alloc((size_t)576 * NTD * 4);
    bf16*  y    = qkv;
    float* raw  = xn;
    float* xn2  = xn;
    float* z    = qn;     // 42.5 MB <= qn+simb

    hipMemcpyAsync(out, x, (size_t)NTOT * CDIM * 4, hipMemcpyDeviceToDevice, stream);

    // LN1
    ln_kernel<<<NTOT / 4, 256, 0, stream>>>(x, n1g, n1b, xn);

    // qkv (bf16) = xn @ wqkv  [MFMA]
    gemm_mfma<0,0,1><<<dim3(9, 576), 256, 0, stream>>>(xn, wqkv, qkv, NTOT, C3, CDIM, CDIM, C3, C3);
    // qn stays f32 (feeds discrete argmax path)
    gemm_kernel<0,0,0><<<dim3(1, 1152), 256, 0, stream>>>(xn, awq, qn, NTOT, RD, CDIM, CDIM, RD, RD);
    gemm_kernel<0,0,0><<<dim3(1, 4), 256, 0, stream>>>(td, awk, kn, 2 * NTD, RD, CDIM, CDIM, RD, RD);
    gemm_kernel<0,0,0><<<dim3(3, 4), 256, 0, stream>>>(td, awv, vtd, 2 * NTD, CDIM, CDIM, CDIM, CDIM, CDIM);
    gemm_kernel<0,0,0><<<dim3(1, 4), 256, 0, stream>>>(td, fcw, tdf, 2 * NTD, TDF, CDIM, CDIM, TDF, TDF);

    l2n_kernel<<<(NTOT + 255) / 256, 256, 0, stream>>>(qn, NTOT);
    l2n_kernel<<<1, 256, 0, stream>>>(kn, 2 * NTD);

    sim_kernel<<<NTOT, 128, 0, stream>>>(qn, kn, ascl, simb, tkid);

    // d_out += sim @ vtd ; xtd = sim @ tdf  [MFMA]
    for (int b = 0; b < 2; ++b) {
        gemm_mfma<1,0,0><<<dim3(3, 288), 256, 0, stream>>>(
            simb + (size_t)b * NTOK * NTD, vtd + (size_t)b * NTD * CDIM,
            out + (size_t)b * NTOK * CDIM, NTOK, CDIM, NTD, NTD, CDIM, CDIM);
        gemm_mfma<0,0,0><<<dim3(1, 288), 256, 0, stream>>>(
            simb + (size_t)b * NTOK * NTD, tdf + (size_t)b * NTD * TDF,
            xtd + (size_t)b * NTOK * TDF, NTOK, TDF, NTD, NTD, TDF, TDF);
    }

    hist_kernel<<<576, 128, 0, stream>>>(tkid, hist);
    scan_kernel<<<2, 128, 0, stream>>>(hist);
    scatter_kernel<<<576, 128, 0, stream>>>(tkid, hist, idxs);

    // window attention -> raw, then d_out += raw @ win_proj  [MFMA]
    win_mfma<<<288 * NH, 256, 0, stream>>>(qkv, rpb, raw);
    gemm_mfma<1,0,0><<<dim3(3, 576), 256, 0, stream>>>(raw, wproj, out, NTOT, CDIM, CDIM, CDIM, CDIM, CDIM);

    // AC-MSA -> raw, then d_out += raw @ aca_proj  [MFMA]
    aca_mfma<<<576 * NH, 128, 0, stream>>>(qkv, idxs, raw);
    gemm_mfma<1,0,0><<<dim3(3, 576), 256, 0, stream>>>(raw, aproj, out, NTOT, CDIM, CDIM, CDIM, CDIM, CDIM);

    // LN2; qkv dead, R0 becomes y
    ln_kernel<<<NTOT / 4, 256, 0, stream>>>(out, n2g, n2b, xn2);

    // y[:, :384] = gelu(xn2 @ w1) (bf16)  [MFMA]; y[:, 384:432] = x_td
    gemm_mfma<0,1,1><<<dim3(6, 576), 256, 0, stream>>>(xn2, w1, y, NTOT, MLP, CDIM, CDIM, MLP, CH);
    xtdcopy_kernel<<<(NTOT * TDF) / 256, 256, 0, stream>>>(xtd, y);

    // conv chunks + w2 GEMM chunks (K=144, zero-padded)  [MFMA]
    for (int c = 0; c < 3; ++c) {
        int z0 = c * 144;
        conv_kernel<<<2 * 144 * 6, 256, 0, stream>>>(y, dw, z, z0);
        gemm_mfma<1,0,0><<<dim3(3, 576), 256, 0, stream>>>(
            z, w2 + (size_t)z0 * CDIM, out, NTOT, CDIM, 144, 144, CDIM, CDIM);
    }
}

// Round 5
// 1118.767 us; speedup vs baseline: 1.9710x; 1.1483x over previous
//
#include <hip/hip_runtime.h>
#include <hip/hip_bf16.h>
#include <math.h>

#define NTOK 36864   // tokens per batch (192*192)
#define NTOT 73728   // total tokens (B=2)
#define CDIM 192
#define C3   576
#define NH   6
#define HD   32
#define RD   20
#define NTD  128     // dictionary tokens
#define GSZ  128     // ac-msa group size
#define NGRP 288     // groups per batch
#define MLP  384
#define TDF  48
#define CH   432     // MLP+TDF

typedef __hip_bfloat16 bf16;
typedef __attribute__((ext_vector_type(8))) short short8;
typedef __attribute__((ext_vector_type(4))) float f32x4;

__device__ __forceinline__ float gelu_f(float x) {
    return 0.5f * x * (1.0f + erff(x * 0.7071067811865475f));
}

__device__ __forceinline__ unsigned short f32_to_bf16u(float f) {
    unsigned int u = __float_as_uint(f);
    u = (u + 0x7FFFu + ((u >> 16) & 1u)) >> 16;   // RNE
    return (unsigned short)u;
}

// ---------------- LayerNorm: one wave per token; writes f32 and/or bf16 ------
template<int WF32>
__global__ void ln_kernel(const float* __restrict__ x, const float* __restrict__ g,
                          const float* __restrict__ be, float* __restrict__ outf,
                          bf16* __restrict__ outh) {
    long tok = (long)blockIdx.x * 4 + (threadIdx.x >> 6);
    int lane = threadIdx.x & 63;
    const float* row = x + tok * CDIM;
    float v0 = row[lane], v1 = row[lane + 64], v2 = row[lane + 128];
    float s  = v0 + v1 + v2;
    float ss = v0 * v0 + v1 * v1 + v2 * v2;
    #pragma unroll
    for (int o = 32; o > 0; o >>= 1) {
        s  += __shfl_down(s, o);
        ss += __shfl_down(ss, o);
    }
    s = __shfl(s, 0); ss = __shfl(ss, 0);
    float mean = s * (1.0f / 192.0f);
    float var  = ss * (1.0f / 192.0f) - mean * mean;
    float rstd = rsqrtf(var + 1e-5f);
    float r0 = (v0 - mean) * rstd * g[lane]       + be[lane];
    float r1 = (v1 - mean) * rstd * g[lane + 64]  + be[lane + 64];
    float r2 = (v2 - mean) * rstd * g[lane + 128] + be[lane + 128];
    if (WF32) {
        float* orow = outf + tok * CDIM;
        orow[lane] = r0; orow[lane + 64] = r1; orow[lane + 128] = r2;
    }
    bf16* hrow = outh + tok * CDIM;
    hrow[lane]       = __float2bfloat16(r0);
    hrow[lane + 64]  = __float2bfloat16(r1);
    hrow[lane + 128] = __float2bfloat16(r2);
}

// ---------------- bf16 MFMA GEMM: C(M,N) (+)= A(M,K) @ B(K,N) ----------------
// A is bf16 or f32 (template). 128x64 tile, 4 waves 2x2, BK=64, K zero-padded.
// M must be a multiple of 128. LDS 27.6 KB.
#define LDT 72   // padded stride in bf16 units (144 B)
template<typename AT, int ACC, int GELU, int BF16OUT>
__global__ void __launch_bounds__(256) gemm_mfma(
        const AT* __restrict__ A, const float* __restrict__ B,
        void* __restrict__ Cv, int M, int N, int K, int lda, int ldb, int ldc) {
    __shared__ short As[128 * LDT];
    __shared__ short Bs[64 * LDT];
    int tid  = threadIdx.x;
    int lane = tid & 63;
    int w    = tid >> 6;
    int wr = w >> 1, wc = w & 1;
    int row0 = blockIdx.y * 128, col0 = blockIdx.x * 64;
    int fr = lane & 15, fq = lane >> 4;
    f32x4 acc[4][2];
    #pragma unroll
    for (int m = 0; m < 4; ++m)
        #pragma unroll
        for (int n = 0; n < 2; ++n) acc[m][n] = (f32x4)(0.0f);

    int sa_row = tid >> 3;          // 0..31
    int sa_kc  = (tid & 7) * 8;     // 0..56
    int sb_col = tid & 63;
    int sb_kb  = (tid >> 6) * 16;   // 0,16,32,48
    bool cok = (col0 + sb_col) < N;

    for (int k0 = 0; k0 < K; k0 += 64) {
        __syncthreads();
        #pragma unroll
        for (int p = 0; p < 4; ++p) {
            int r = sa_row + p * 32;
            const AT* src = A + (long)(row0 + r) * lda + k0 + sa_kc;
            short8 v;
            if (k0 + sa_kc + 8 <= K) {
                if constexpr (sizeof(AT) == 2) {
                    v = *(const short8*)src;
                } else {
                    float4 f0 = *(const float4*)&src[0];
                    float4 f1 = *(const float4*)&src[4];
                    v[0] = (short)f32_to_bf16u(f0.x); v[1] = (short)f32_to_bf16u(f0.y);
                    v[2] = (short)f32_to_bf16u(f0.z); v[3] = (short)f32_to_bf16u(f0.w);
                    v[4] = (short)f32_to_bf16u(f1.x); v[5] = (short)f32_to_bf16u(f1.y);
                    v[6] = (short)f32_to_bf16u(f1.z); v[7] = (short)f32_to_bf16u(f1.w);
                }
            } else {
                #pragma unroll
                for (int i = 0; i < 8; ++i) {
                    if (k0 + sa_kc + i < K) {
                        if constexpr (sizeof(AT) == 2) v[i] = *(const short*)&src[i];
                        else v[i] = (short)f32_to_bf16u(((const float*)src)[i]);
                    } else v[i] = 0;
                }
            }
            *(short8*)&As[r * LDT + sa_kc] = v;
        }
        {
            short8 v0, v1;
            #pragma unroll
            for (int i = 0; i < 16; ++i) {
                int k = sb_kb + i;
                float f = (cok && (k0 + k) < K)
                          ? B[(long)(k0 + k) * ldb + col0 + sb_col] : 0.0f;
                unsigned short hsh = f32_to_bf16u(f);
                if (i < 8) v0[i] = (short)hsh; else v1[i - 8] = (short)hsh;
            }
            *(short8*)&Bs[sb_col * LDT + sb_kb]     = v0;
            *(short8*)&Bs[sb_col * LDT + sb_kb + 8] = v1;
        }
        __syncthreads();
        short8 af[4][2], bf_[2][2];
        #pragma unroll
        for (int m = 0; m < 4; ++m) {
            int r = wr * 64 + m * 16 + fr;
            af[m][0] = *(const short8*)&As[r * LDT + fq * 8];
            af[m][1] = *(const short8*)&As[r * LDT + 32 + fq * 8];
        }
        #pragma unroll
        for (int n = 0; n < 2; ++n) {
            int c = wc * 32 + n * 16 + fr;
            bf_[n][0] = *(const short8*)&Bs[c * LDT + fq * 8];
            bf_[n][1] = *(const short8*)&Bs[c * LDT + 32 + fq * 8];
        }
        #pragma unroll
        for (int m = 0; m < 4; ++m)
            #pragma unroll
            for (int n = 0; n < 2; ++n) {
                acc[m][n] = __builtin_amdgcn_mfma_f32_16x16x32_bf16(
                                af[m][0], bf_[n][0], acc[m][n], 0, 0, 0);
                acc[m][n] = __builtin_amdgcn_mfma_f32_16x16x32_bf16(
                                af[m][1], bf_[n][1], acc[m][n], 0, 0, 0);
            }
    }
    #pragma unroll
    for (int m = 0; m < 4; ++m) {
        #pragma unroll
        for (int n = 0; n < 2; ++n) {
            int gc = col0 + wc * 32 + n * 16 + fr;
            if (gc >= N) continue;
            #pragma unroll
            for (int r = 0; r < 4; ++r) {
                int gr = row0 + wr * 64 + m * 16 + fq * 4 + r;
                float vv = acc[m][n][r];
                if (GELU) vv = gelu_f(vv);
                long o = (long)gr * ldc + gc;
                if (BF16OUT) {
                    ((bf16*)Cv)[o] = __float2bfloat16(vv);
                } else {
                    float* Cc = (float*)Cv;
                    if (ACC) Cc[o] += vv; else Cc[o] = vv;
                }
            }
        }
    }
}

// ---------------- Generic tiled f32 GEMM (small / precision-critical) --------
template<int ACC, int GELU>
__global__ void __launch_bounds__(256) gemm_kernel(
        const float* __restrict__ A, const float* __restrict__ B,
        float* __restrict__ Cc, int M, int N, int K, int lda, int ldb, int ldc) {
    __shared__ float As[16][68];
    __shared__ float Bs[16][68];
    int tid = threadIdx.x;
    int tr = tid >> 4, tc = tid & 15;
    int row0 = blockIdx.y * 64, col0 = blockIdx.x * 64;
    float acc[4][4] = {};
    int lm = tid >> 4;
    int lk = tid & 15;
    int bk = tid >> 6;
    int bn = tid & 63;
    for (int k0 = 0; k0 < K; k0 += 16) {
        #pragma unroll
        for (int i = 0; i < 4; ++i) {
            int m = lm + i * 16;
            int gr = row0 + m;
            As[lk][m] = (gr < M) ? A[(long)gr * lda + (k0 + lk)] : 0.0f;
        }
        #pragma unroll
        for (int i = 0; i < 4; ++i) {
            int kk = bk + i * 4;
            int gc = col0 + bn;
            Bs[kk][bn] = (gc < N) ? B[(long)(k0 + kk) * ldb + gc] : 0.0f;
        }
        __syncthreads();
        #pragma unroll
        for (int kk = 0; kk < 16; ++kk) {
            float4 av = *(const float4*)&As[kk][tr * 4];
            float4 bv = *(const float4*)&Bs[kk][tc * 4];
            float a[4] = {av.x, av.y, av.z, av.w};
            float b[4] = {bv.x, bv.y, bv.z, bv.w};
            #pragma unroll
            for (int i = 0; i < 4; ++i)
                #pragma unroll
                for (int j = 0; j < 4; ++j)
                    acc[i][j] = fmaf(a[i], b[j], acc[i][j]);
        }
        __syncthreads();
    }
    #pragma unroll
    for (int i = 0; i < 4; ++i) {
        int gr = row0 + tr * 4 + i;
        if (gr >= M) continue;
        #pragma unroll
        for (int j = 0; j < 4; ++j) {
            int gc = col0 + tc * 4 + j;
            if (gc >= N) continue;
            float v = acc[i][j];
            if (GELU) v = gelu_f(v);
            long o = (long)gr * ldc + gc;
            if (ACC) Cc[o] += v; else Cc[o] = v;
        }
    }
}

// ---------------- row-wise L2 normalize (RD=20), in place --------------------
__global__ void l2n_kernel(float* __restrict__ d, int nrows) {
    int i = blockIdx.x * blockDim.x + threadIdx.x;
    if (i >= nrows) return;
    float* r = d + (long)i * RD;
    float ss = 0.0f;
    #pragma unroll
    for (int k = 0; k < RD; ++k) ss += r[k] * r[k];
    float inv = 1.0f / fmaxf(sqrtf(ss), 1e-12f);
    #pragma unroll
    for (int k = 0; k < RD; ++k) r[k] *= inv;
}

// ---------------- ATD similarity softmax + argmax (block = token) ------------
__global__ void __launch_bounds__(128) sim_kernel(
        const float* __restrict__ qn, const float* __restrict__ kn,
        const float* __restrict__ scale_p, bf16* __restrict__ sim,
        int* __restrict__ tkid) {
    int tok = blockIdx.x;
    int b = tok / NTOK;
    int j = threadIdx.x;
    __shared__ float qv[RD];
    __shared__ float wred[4];
    __shared__ int   wredi[2];
    if (j < RD) qv[j] = qn[(long)tok * RD + j];
    __syncthreads();
    const float* kr = kn + ((long)b * NTD + j) * RD;
    float s = 0.0f;
    #pragma unroll
    for (int r = 0; r < RD; ++r) s = fmaf(qv[r], kr[r], s);
    float scl = 1.0f + fminf(fmaxf(scale_p[0], 0.0f), 3.0f) * logf(128.0f);
    s *= scl;
    float m = s; int mi = j;
    #pragma unroll
    for (int o = 32; o > 0; o >>= 1) {
        float om = __shfl_down(m, o); int oi = __shfl_down(mi, o);
        if (om > m || (om == m && oi < mi)) { m = om; mi = oi; }
    }
    int wv = j >> 6;
    if ((j & 63) == 0) { wred[wv] = m; wredi[wv] = mi; }
    __syncthreads();
    float m0 = wred[0], m1 = wred[1];
    float gm; int gi;
    if (m1 > m0) { gm = m1; gi = wredi[1]; } else { gm = m0; gi = wredi[0]; }
    float p = __expf(s - gm);
    float t = p;
    #pragma unroll
    for (int o = 32; o > 0; o >>= 1) t += __shfl_down(t, o);
    if ((j & 63) == 0) wred[2 + wv] = t;
    __syncthreads();
    float tot = wred[2] + wred[3];
    sim[(long)tok * NTD + j] = __float2bfloat16(p / tot);
    if (j == 0) tkid[tok] = gi;
}

// ---------------- stable counting sort: hist / scan / scatter ----------------
__global__ void hist_kernel(const int* __restrict__ tkid, int* __restrict__ hist) {
    int tile = blockIdx.x;
    int tid = threadIdx.x;
    __shared__ int h[NTD];
    h[tid] = 0;
    __syncthreads();
    atomicAdd(&h[tkid[tile * GSZ + tid]], 1);
    __syncthreads();
    hist[tile * NTD + tid] = h[tid];
}

__global__ void scan_kernel(int* __restrict__ hist) {
    int b = blockIdx.x;
    int c = threadIdx.x;
    __shared__ int tot[NTD];
    __shared__ int base[NTD];
    int run = 0;
    for (int t = 0; t < NGRP; ++t) {
        int id = (b * NGRP + t) * NTD + c;
        int v = hist[id];
        hist[id] = run;
        run += v;
    }
    tot[c] = run;
    __syncthreads();
    if (c == 0) {
        int a = 0;
        for (int i = 0; i < NTD; ++i) { base[i] = a; a += tot[i]; }
    }
    __syncthreads();
    int bc = base[c];
    for (int t = 0; t < NGRP; ++t)
        hist[(b * NGRP + t) * NTD + c] += bc;
}

__global__ void scatter_kernel(const int* __restrict__ tkid, const int* __restrict__ hist,
                               int* __restrict__ idxs) {
    int tile = blockIdx.x;
    int b = tile / NGRP;
    int gl = tile % NGRP;
    int tid = threadIdx.x;
    __shared__ int cats[GSZ];
    int cat = tkid[tile * GSZ + tid];
    cats[tid] = cat;
    __syncthreads();
    int rank = 0;
    for (int j = 0; j < tid; ++j) rank += (cats[j] == cat) ? 1 : 0;
    int pos = hist[tile * NTD + cat] + rank;
    idxs[b * NTOK + pos] = gl * GSZ + tid;
}

#define PLD 72   // V^T row stride in bf16 (144 B)

// ---- shared softmax+PV helper structure is inlined in both attention kernels.
// S^T = mfma(K_frag, Q_frag): lane(fr,fq) holds S[kv=16c+4fq+r][q=m*16+fr].
// Softmax is lane-local over 16 regs + 2 shfl_xor(16,32).
// P -> PV A-frags via 16 bpermutes:
//   pa[ks][jj] = lane(fr, 2(fq&1)+(jj>>1)) :: pk[2ks+(fq>>1)][jj&1]

// ---------------- MFMA window attention: block = (window, head) --------------
// 256 threads = 4 waves x 64 q-rows. KV tiles of 64. LDS ~13.5 KB.
__global__ void __launch_bounds__(256) win_mfma(
        const bf16* __restrict__ qkv, const float* __restrict__ rpb,
        bf16* __restrict__ out) {
    int wid = blockIdx.x / NH;
    int h   = blockIdx.x % NH;
    int b = wid / 144;
    int wrem = wid % 144;
    int wy = wrem / 12, wx = wrem % 12;
    long base_tok = (long)b * NTOK;

    __shared__ short Kt[64 * 40];
    __shared__ short Vt[32 * PLD];
    __shared__ float rb[961];

    int tid = threadIdx.x;
    int lane = tid & 63;
    int wvv = tid >> 6;
    int fr = lane & 15, fq = lane >> 4;
    const float scl = 0.17677669529663687f;

    for (int i = tid; i < 961; i += 256) rb[i] = rpb[i * NH + h];

    // Q fragments: lane holds Q[q = m*16+fr][d = 8fq+j]
    short8 qf[4];
    #pragma unroll
    for (int m = 0; m < 4; ++m) {
        int qrow = wvv * 64 + m * 16 + fr;
        long nq = base_tok + (long)(wy * 16 + (qrow >> 4)) * 192 + (wx * 16 + (qrow & 15));
        qf[m] = *(const short8*)(qkv + nq * C3 + h * HD + fq * 8);
    }

    f32x4 acc[4][2];
    float mst[4], lst[4];
    #pragma unroll
    for (int m = 0; m < 4; ++m) {
        acc[m][0] = (f32x4)(0.0f); acc[m][1] = (f32x4)(0.0f);
        mst[m] = -INFINITY; lst[m] = 0.0f;
    }
    int half = fq >> 1;
    int abase = 2 * (fq & 1);

    for (int t = 0; t < 4; ++t) {
        __syncthreads();
        {   // stage K[64][32] (pad 40) and V^T[32][64] (pad PLD)
            int s = tid >> 2, ch = tid & 3;
            int p = t * 64 + s;
            long nk = base_tok + (long)(wy * 16 + (p >> 4)) * 192 + (wx * 16 + (p & 15));
            const bf16* kb = qkv + nk * C3 + CDIM + h * HD + ch * 8;
            *(short8*)&Kt[s * 40 + ch * 8] = *(const short8*)kb;
            short8 vv = *(const short8*)(kb + CDIM);
            #pragma unroll
            for (int i = 0; i < 8; ++i)
                Vt[(ch * 8 + i) * PLD + s] = vv[i];
        }
        __syncthreads();

        short8 bk[4], bv[2][2];
        #pragma unroll
        for (int c = 0; c < 4; ++c)
            bk[c] = *(const short8*)&Kt[(c * 16 + fr) * 40 + fq * 8];
        #pragma unroll
        for (int n = 0; n < 2; ++n)
            #pragma unroll
            for (int ks = 0; ks < 2; ++ks)
                bv[n][ks] = *(const short8*)&Vt[(n * 16 + fr) * PLD + ks * 32 + fq * 8];

        #pragma unroll
        for (int m = 0; m < 4; ++m) {
            int q_full = wvv * 64 + m * 16 + fr;
            int iy = q_full >> 4, ix = q_full & 15;
            float s[4][4];
            #pragma unroll
            for (int c = 0; c < 4; ++c) {
                f32x4 s4 = (f32x4)(0.0f);
                s4 = __builtin_amdgcn_mfma_f32_16x16x32_bf16(bk[c], qf[m], s4, 0, 0, 0);
                #pragma unroll
                for (int r = 0; r < 4; ++r) {
                    int j = t * 64 + c * 16 + 4 * fq + r;
                    int jy = j >> 4, jx = j & 15;
                    s[c][r] = s4[r] * scl + rb[(iy - jy + 15) * 31 + (ix - jx + 15)];
                }
            }
            float tmax = s[0][0];
            #pragma unroll
            for (int c = 0; c < 4; ++c)
                #pragma unroll
                for (int r = 0; r < 4; ++r) tmax = fmaxf(tmax, s[c][r]);
            tmax = fmaxf(tmax, __shfl_xor(tmax, 16));
            tmax = fmaxf(tmax, __shfl_xor(tmax, 32));
            float mo = mst[m];
            float mn = fmaxf(mo, tmax);
            float scf = __expf(mo - mn);
            mst[m] = mn;
            float ps = 0.0f;
            #pragma unroll
            for (int c = 0; c < 4; ++c)
                #pragma unroll
                for (int r = 0; r < 4; ++r) {
                    float p = __expf(s[c][r] - mn);
                    s[c][r] = p;
                    ps += p;
                }
            ps += __shfl_xor(ps, 16);
            ps += __shfl_xor(ps, 32);
            lst[m] = lst[m] * scf + ps;
            #pragma unroll
            for (int r = 0; r < 4; ++r) {
                float sr = __shfl(scf, 4 * fq + r);
                acc[m][0][r] *= sr;
                acc[m][1][r] *= sr;
            }
            // pack to bf16 pairs along kv
            unsigned pk[4][2];
            #pragma unroll
            for (int c = 0; c < 4; ++c) {
                pk[c][0] = (unsigned)f32_to_bf16u(s[c][0]) | ((unsigned)f32_to_bf16u(s[c][1]) << 16);
                pk[c][1] = (unsigned)f32_to_bf16u(s[c][2]) | ((unsigned)f32_to_bf16u(s[c][3]) << 16);
            }
            // register exchange -> PV A-frags
            unsigned pa[2][4];
            #pragma unroll
            for (int cc = 0; cc < 4; ++cc)
                #pragma unroll
                for (int jj = 0; jj < 4; ++jj) {
                    unsigned v = (unsigned)__shfl((int)pk[cc][jj & 1],
                                                  fr + 16 * (abase + (jj >> 1)));
                    if ((cc & 1) == half) pa[cc >> 1][jj] = v;
                }
            #pragma unroll
            for (int ks = 0; ks < 2; ++ks) {
                short8 pa8;
                #pragma unroll
                for (int jj = 0; jj < 4; ++jj) {
                    pa8[2 * jj]     = (short)(pa[ks][jj] & 0xFFFF);
                    pa8[2 * jj + 1] = (short)(pa[ks][jj] >> 16);
                }
                #pragma unroll
                for (int n = 0; n < 2; ++n)
                    acc[m][n] = __builtin_amdgcn_mfma_f32_16x16x32_bf16(
                                    pa8, bv[n][ks], acc[m][n], 0, 0, 0);
            }
        }
    }
    // epilogue: O row = q = m*16+4fq+r, col = d = fr (+16)
    #pragma unroll
    for (int m = 0; m < 4; ++m)
        #pragma unroll
        for (int r = 0; r < 4; ++r) {
            int q_full = wvv * 64 + m * 16 + 4 * fq + r;
            long nq = base_tok + (long)(wy * 16 + (q_full >> 4)) * 192 + (wx * 16 + (q_full & 15));
            float inv = 1.0f / __shfl(lst[m], 4 * fq + r);
            bf16* orow = out + nq * CDIM + h * HD + fr;
            orow[0]  = __float2bfloat16(acc[m][0][r] * inv);
            orow[16] = __float2bfloat16(acc[m][1][r] * inv);
        }
}

// ---------------- MFMA AC-MSA attention: block = (group, head) ---------------
// 128 threads = 2 waves x 64 q-rows. 2 KV tiles of 64. LDS ~10 KB.
__global__ void __launch_bounds__(128) aca_mfma(
        const bf16* __restrict__ qkv, const int* __restrict__ idxs,
        bf16* __restrict__ out) {
    int grp = blockIdx.x / NH;
    int h   = blockIdx.x % NH;
    int b = grp / NGRP;
    int g = grp % NGRP;
    long btok = (long)b * NTOK;

    __shared__ short Kt[64 * 40];
    __shared__ short Vt[32 * PLD];
    __shared__ int   sidx[GSZ];

    int tid = threadIdx.x;
    int lane = tid & 63;
    int wvv = tid >> 6;
    int fr = lane & 15, fq = lane >> 4;
    const float scl = 0.17677669529663687f;

    sidx[tid] = idxs[btok + g * GSZ + tid];
    __syncthreads();

    short8 qf[4];
    #pragma unroll
    for (int m = 0; m < 4; ++m) {
        long n = btok + sidx[wvv * 64 + m * 16 + fr];
        qf[m] = *(const short8*)(qkv + n * C3 + h * HD + fq * 8);
    }

    f32x4 acc[4][2];
    float mst[4], lst[4];
    #pragma unroll
    for (int m = 0; m < 4; ++m) {
        acc[m][0] = (f32x4)(0.0f); acc[m][1] = (f32x4)(0.0f);
        mst[m] = -INFINITY; lst[m] = 0.0f;
    }
    int half = fq >> 1;
    int abase = 2 * (fq & 1);

    for (int t = 0; t < 2; ++t) {
        __syncthreads();
        {   // stage gathered K/V tile
            int s = tid & 63, hf = tid >> 6;
            int d0 = hf * 16;
            long n = btok + sidx[t * 64 + s];
            const bf16* kb = qkv + n * C3 + CDIM + h * HD + d0;
            *(short8*)&Kt[s * 40 + d0]     = *(const short8*)kb;
            *(short8*)&Kt[s * 40 + d0 + 8] = *(const short8*)(kb + 8);
            short8 v0 = *(const short8*)(kb + CDIM);
            short8 v1 = *(const short8*)(kb + CDIM + 8);
            #pragma unroll
            for (int i = 0; i < 8; ++i) {
                Vt[(d0 + i) * PLD + s]     = v0[i];
                Vt[(d0 + 8 + i) * PLD + s] = v1[i];
            }
        }
        __syncthreads();

        short8 bk[4], bv[2][2];
        #pragma unroll
        for (int c = 0; c < 4; ++c)
            bk[c] = *(const short8*)&Kt[(c * 16 + fr) * 40 + fq * 8];
        #pragma unroll
        for (int n = 0; n < 2; ++n)
            #pragma unroll
            for (int ks = 0; ks < 2; ++ks)
                bv[n][ks] = *(const short8*)&Vt[(n * 16 + fr) * PLD + ks * 32 + fq * 8];

        #pragma unroll
        for (int m = 0; m < 4; ++m) {
            float s[4][4];
            #pragma unroll
            for (int c = 0; c < 4; ++c) {
                f32x4 s4 = (f32x4)(0.0f);
                s4 = __builtin_amdgcn_mfma_f32_16x16x32_bf16(bk[c], qf[m], s4, 0, 0, 0);
                #pragma unroll
                for (int r = 0; r < 4; ++r) s[c][r] = s4[r] * scl;
            }
            float tmax = s[0][0];
            #pragma unroll
            for (int c = 0; c < 4; ++c)
                #pragma unroll
                for (int r = 0; r < 4; ++r) tmax = fmaxf(tmax, s[c][r]);
            tmax = fmaxf(tmax, __shfl_xor(tmax, 16));
            tmax = fmaxf(tmax, __shfl_xor(tmax, 32));
            float mo = mst[m];
            float mn = fmaxf(mo, tmax);
            float scf = __expf(mo - mn);
            mst[m] = mn;
            float ps = 0.0f;
            #pragma unroll
            for (int c = 0; c < 4; ++c)
                #pragma unroll
                for (int r = 0; r < 4; ++r) {
                    float p = __expf(s[c][r] - mn);
                    s[c][r] = p;
                    ps += p;
                }
            ps += __shfl_xor(ps, 16);
            ps += __shfl_xor(ps, 32);
            lst[m] = lst[m] * scf + ps;
            #pragma unroll
            for (int r = 0; r < 4; ++r) {
                float sr = __shfl(scf, 4 * fq + r);
                acc[m][0][r] *= sr;
                acc[m][1][r] *= sr;
            }
            unsigned pk[4][2];
            #pragma unroll
            for (int c = 0; c < 4; ++c) {
                pk[c][0] = (unsigned)f32_to_bf16u(s[c][0]) | ((unsigned)f32_to_bf16u(s[c][1]) << 16);
                pk[c][1] = (unsigned)f32_to_bf16u(s[c][2]) | ((unsigned)f32_to_bf16u(s[c][3]) << 16);
            }
            unsigned pa[2][4];
            #pragma unroll
            for (int cc = 0; cc < 4; ++cc)
                #pragma unroll
                for (int jj = 0; jj < 4; ++jj) {
                    unsigned v = (unsigned)__shfl((int)pk[cc][jj & 1],
                                                  fr + 16 * (abase + (jj >> 1)));
                    if ((cc & 1) == half) pa[cc >> 1][jj] = v;
                }
            #pragma unroll
            for (int ks = 0; ks < 2; ++ks) {
                short8 pa8;
                #pragma unroll
                for (int jj = 0; jj < 4; ++jj) {
                    pa8[2 * jj]     = (short)(pa[ks][jj] & 0xFFFF);
                    pa8[2 * jj + 1] = (short)(pa[ks][jj] >> 16);
                }
                #pragma unroll
                for (int n = 0; n < 2; ++n)
                    acc[m][n] = __builtin_amdgcn_mfma_f32_16x16x32_bf16(
                                    pa8, bv[n][ks], acc[m][n], 0, 0, 0);
            }
        }
    }
    #pragma unroll
    for (int m = 0; m < 4; ++m)
        #pragma unroll
        for (int r = 0; r < 4; ++r) {
            long n = btok + sidx[wvv * 64 + m * 16 + 4 * fq + r];
            float inv = 1.0f / __shfl(lst[m], 4 * fq + r);
            bf16* orow = out + n * CDIM + h * HD + fr;
            orow[0]  = __float2bfloat16(acc[m][0][r] * inv);
            orow[16] = __float2bfloat16(acc[m][1][r] * inv);
        }
}

// ---------------- x_td -> y[:, 384:432] copy (bf16 -> bf16) ------------------
__global__ void xtdcopy_kernel(const bf16* __restrict__ xtd, bf16* __restrict__ y) {
    long i = (long)blockIdx.x * 256 + threadIdx.x;
    long ntk = i / TDF;
    int c = (int)(i - ntk * TDF);
    y[ntk * CH + MLP + c] = xtd[i];
}

// ---------------- depthwise 5x5 conv + gelu + residual over a 144-ch chunk ---
#define YSLD 401
__global__ void __launch_bounds__(256) conv_kernel(
        const bf16* __restrict__ y, const float* __restrict__ dw,
        bf16* __restrict__ z, int z0) {
    int bid = blockIdx.x;
    int ck   = bid % 6;
    int tile = (bid / 6) % 144;
    int b    = bid / (6 * 144);
    int ty = tile / 12, tx = tile % 12;
    int c0 = z0 + ck * 24;
    __shared__ float ys[24 * YSLD];
    __shared__ float wt[24 * 25];
    int tid = threadIdx.x;
    const bf16* yb = y + (long)b * NTOK * CH;
    for (int e = tid; e < 20 * 20 * 24; e += 256) {
        int p = e / 24, c = e - p * 24;
        int ly = p / 20, lx = p - ly * 20;
        int gy = ty * 16 + ly - 2, gx = tx * 16 + lx - 2;
        float v = 0.0f;
        if (gy >= 0 && gy < 192 && gx >= 0 && gx < 192)
            v = __bfloat162float(yb[(long)(gy * 192 + gx) * CH + c0 + c]);
        ys[c * YSLD + p] = v;
    }
    for (int e = tid; e < 24 * 25; e += 256)
        wt[e] = dw[(c0 + e / 25) * 25 + (e % 25)];
    __syncthreads();
    int py = tid >> 4, px = tid & 15;
    long obase = ((long)b * NTOK + (long)(ty * 16 + py) * 192 + (tx * 16 + px)) * 144 + ck * 24;
    for (int c = 0; c < 24; ++c) {
        const float* yc = &ys[c * YSLD];
        float a = 0.0f;
        #pragma unroll
        for (int dy = 0; dy < 5; ++dy)
            #pragma unroll
            for (int dx = 0; dx < 5; ++dx)
                a = fmaf(yc[(py + dy) * 20 + (px + dx)], wt[c * 25 + dy * 5 + dx], a);
        float center = yc[(py + 2) * 20 + (px + 2)];
        z[obase + c] = __float2bfloat16(center + gelu_f(a));
    }
}

// =============================================================================
extern "C" void kernel_launch(void* const* d_in, const int* in_sizes, int n_in,
                              void* d_out, int out_size, void* d_ws, size_t ws_size,
                              hipStream_t stream) {
    (void)in_sizes; (void)n_in; (void)out_size; (void)ws_size;
    const float* x     = (const float*)d_in[0];
    const float* td    = (const float*)d_in[1];
    const float* n1g   = (const float*)d_in[2];
    const float* n1b   = (const float*)d_in[3];
    const float* n2g   = (const float*)d_in[4];
    const float* n2b   = (const float*)d_in[5];
    const float* wqkv  = (const float*)d_in[6];
    const float* rpb   = (const float*)d_in[7];
    const float* wproj = (const float*)d_in[8];
    const float* awq   = (const float*)d_in[9];
    const float* awk   = (const float*)d_in[10];
    const float* awv   = (const float*)d_in[11];
    const float* ascl  = (const float*)d_in[12];
    const float* aproj = (const float*)d_in[13];
    const float* fcw   = (const float*)d_in[14];
    const float* w1    = (const float*)d_in[15];
    const float* dw    = (const float*)d_in[16];
    const float* w2    = (const float*)d_in[17];
    float* out = (float*)d_out;

    char* ws = (char*)d_ws;
    size_t off = 0;
    auto alloc = [&](size_t bytes) -> char* {
        char* p = ws + off;
        off += (bytes + 255) & ~(size_t)255;
        return p;
    };
    bf16*  qkv  = (bf16*)alloc((size_t)NTOT * C3 * 2);      // R0, later y
    float* xn   = (float*)alloc((size_t)NTOT * CDIM * 4);   // R1: xn f32, later raw bf16
    bf16*  xnh  = (bf16*)alloc((size_t)NTOT * CDIM * 2);    // bf16 LN out (LN1, later LN2)
    float* qn   = (float*)alloc((size_t)NTOT * RD * 4);     // R2 head, later z bf16
    bf16*  simb = (bf16*)alloc((size_t)NTOT * NTD * 2);
    bf16*  xtd  = (bf16*)alloc((size_t)NTOT * TDF * 2);
    float* kn   = (float*)alloc((size_t)2 * NTD * RD * 4);
    float* vtd  = (float*)alloc((size_t)2 * NTD * CDIM * 4);
    float* tdf  = (float*)alloc((size_t)2 * NTD * TDF * 4);
    int*   tkid = (int*)alloc((size_t)NTOT * 4);
    int*   idxs = (int*)alloc((size_t)NTOT * 4);
    int*   hist = (int*)alloc((size_t)576 * NTD * 4);
    bf16*  y    = qkv;          // reuse R0
    bf16*  raw  = (bf16*)xn;    // reuse R1 (xn f32 dead after qn gemm)
    bf16*  z    = (bf16*)qn;    // 21.2 MB <= qn+simb region (24.8 MB)

    hipMemcpyAsync(out, x, (size_t)NTOT * CDIM * 4, hipMemcpyDeviceToDevice, stream);

    // LN1: f32 (for qn path) + bf16 (for MFMA gemms)
    ln_kernel<1><<<NTOT / 4, 256, 0, stream>>>(x, n1g, n1b, xn, xnh);

    // qkv (bf16) = xnh @ wqkv  [MFMA, A=bf16]
    gemm_mfma<bf16,0,0,1><<<dim3(9, 576), 256, 0, stream>>>(xnh, wqkv, qkv, NTOT, C3, CDIM, CDIM, C3, C3);
    // qn stays f32 (feeds discrete argmax path)
    gemm_kernel<0,0><<<dim3(1, 1152), 256, 0, stream>>>(xn, awq, qn, NTOT, RD, CDIM, CDIM, RD, RD);
    gemm_kernel<0,0><<<dim3(1, 4), 256, 0, stream>>>(td, awk, kn, 2 * NTD, RD, CDIM, CDIM, RD, RD);
    gemm_kernel<0,0><<<dim3(3, 4), 256, 0, stream>>>(td, awv, vtd, 2 * NTD, CDIM, CDIM, CDIM, CDIM, CDIM);
    gemm_kernel<0,0><<<dim3(1, 4), 256, 0, stream>>>(td, fcw, tdf, 2 * NTD, TDF, CDIM, CDIM, TDF, TDF);

    l2n_kernel<<<(NTOT + 255) / 256, 256, 0, stream>>>(qn, NTOT);
    l2n_kernel<<<1, 256, 0, stream>>>(kn, 2 * NTD);

    sim_kernel<<<NTOT, 128, 0, stream>>>(qn, kn, ascl, simb, tkid);

    // d_out += sim @ vtd ; xtd = sim @ tdf  [MFMA, A=bf16]
    for (int b = 0; b < 2; ++b) {
        gemm_mfma<bf16,1,0,0><<<dim3(3, 288), 256, 0, stream>>>(
            simb + (size_t)b * NTOK * NTD, vtd + (size_t)b * NTD * CDIM,
            out + (size_t)b * NTOK * CDIM, NTOK, CDIM, NTD, NTD, CDIM, CDIM);
        gemm_mfma<bf16,0,0,1><<<dim3(1, 288), 256, 0, stream>>>(
            simb + (size_t)b * NTOK * NTD, tdf + (size_t)b * NTD * TDF,
            xtd + (size_t)b * NTOK * TDF, NTOK, TDF, NTD, NTD, TDF, TDF);
    }

    hist_kernel<<<576, 128, 0, stream>>>(tkid, hist);
    scan_kernel<<<2, 128, 0, stream>>>(hist);
    scatter_kernel<<<576, 128, 0, stream>>>(tkid, hist, idxs);

    // window attention -> raw (bf16), then d_out += raw @ win_proj
    win_mfma<<<288 * NH, 256, 0, stream>>>(qkv, rpb, raw);
    gemm_mfma<bf16,1,0,0><<<dim3(3, 576), 256, 0, stream>>>(raw, wproj, out, NTOT, CDIM, CDIM, CDIM, CDIM, CDIM);

    // AC-MSA -> raw (bf16), then d_out += raw @ aca_proj
    aca_mfma<<<576 * NH, 128, 0, stream>>>(qkv, idxs, raw);
    gemm_mfma<bf16,1,0,0><<<dim3(3, 576), 256, 0, stream>>>(raw, aproj, out, NTOT, CDIM, CDIM, CDIM, CDIM, CDIM);

    // LN2 (bf16 only); qkv dead, R0 becomes y
    ln_kernel<0><<<NTOT / 4, 256, 0, stream>>>(out, n2g, n2b, nullptr, xnh);

    // y[:, :384] = gelu(xnh @ w1) (bf16); y[:, 384:432] = x_td
    gemm_mfma<bf16,0,1,1><<<dim3(6, 576), 256, 0, stream>>>(xnh, w1, y, NTOT, MLP, CDIM, CDIM, MLP, CH);
    xtdcopy_kernel<<<(NTOT * TDF) / 256, 256, 0, stream>>>(xtd, y);

    // conv chunks (z bf16) + w2 GEMM chunks (K=144, zero-padded)
    for (int c = 0; c < 3; ++c) {
        int z0 = c * 144;
        conv_kernel<<<2 * 144 * 6, 256, 0, stream>>>(y, dw, z, z0);
        gemm_mfma<bf16,1,0,0><<<dim3(3, 576), 256, 0, stream>>>(
            z, w2 + (size_t)z0 * CDIM, out, NTOT, CDIM, 144, 144, CDIM, CDIM);
    }
}

// Round 6
// 1017.281 us; speedup vs baseline: 2.1676x; 1.0998x over previous
//
#include <hip/hip_runtime.h>
#include <hip/hip_bf16.h>
#include <math.h>

#define NTOK 36864   // tokens per batch (192*192)
#define NTOT 73728   // total tokens (B=2)
#define CDIM 192
#define C3   576
#define NH   6
#define HD   32
#define RD   20
#define NTD  128     // dictionary tokens
#define GSZ  128     // ac-msa group size
#define NGRP 288     // groups per batch
#define MLP  384
#define TDF  48
#define CH   432     // MLP+TDF
#define RAWLD 384    // concat(win, aca) raw stride

typedef __hip_bfloat16 bf16;
typedef __attribute__((ext_vector_type(8))) short short8;
typedef __attribute__((ext_vector_type(4))) float f32x4;

__device__ __forceinline__ float gelu_f(float x) {
    return 0.5f * x * (1.0f + erff(x * 0.7071067811865475f));
}

__device__ __forceinline__ unsigned short f32_to_bf16u(float f) {
    unsigned int u = __float_as_uint(f);
    u = (u + 0x7FFFu + ((u >> 16) & 1u)) >> 16;   // RNE
    return (unsigned short)u;
}

__device__ __forceinline__ unsigned pack2bf(float a, float b) {
    return (unsigned)f32_to_bf16u(a) | ((unsigned)f32_to_bf16u(b) << 16);
}

// ---------------- weight pack: src f32 [K][N] -> dst bf16 [N][ldk] (+koff) ---
__global__ void pack_bt(const float* __restrict__ src, bf16* __restrict__ dst,
                        int K, int N, int ldk, int koff) {
    int i = blockIdx.x * 256 + threadIdx.x;
    if (i >= K * N) return;
    int k = i / N, n = i - k * N;
    dst[(long)n * ldk + koff + k] = __float2bfloat16(src[i]);
}

// ---------------- LayerNorm: one wave per token; writes f32 and/or bf16 ------
template<int WF32>
__global__ void ln_kernel(const float* __restrict__ x, const float* __restrict__ g,
                          const float* __restrict__ be, float* __restrict__ outf,
                          bf16* __restrict__ outh) {
    long tok = (long)blockIdx.x * 4 + (threadIdx.x >> 6);
    int lane = threadIdx.x & 63;
    const float* row = x + tok * CDIM;
    float v0 = row[lane], v1 = row[lane + 64], v2 = row[lane + 128];
    float s  = v0 + v1 + v2;
    float ss = v0 * v0 + v1 * v1 + v2 * v2;
    #pragma unroll
    for (int o = 32; o > 0; o >>= 1) {
        s  += __shfl_down(s, o);
        ss += __shfl_down(ss, o);
    }
    s = __shfl(s, 0); ss = __shfl(ss, 0);
    float mean = s * (1.0f / 192.0f);
    float var  = ss * (1.0f / 192.0f) - mean * mean;
    float rstd = rsqrtf(var + 1e-5f);
    float r0 = (v0 - mean) * rstd * g[lane]       + be[lane];
    float r1 = (v1 - mean) * rstd * g[lane + 64]  + be[lane + 64];
    float r2 = (v2 - mean) * rstd * g[lane + 128] + be[lane + 128];
    if (WF32) {
        float* orow = outf + tok * CDIM;
        orow[lane] = r0; orow[lane + 64] = r1; orow[lane + 128] = r2;
    }
    bf16* hrow = outh + tok * CDIM;
    hrow[lane]       = __float2bfloat16(r0);
    hrow[lane + 64]  = __float2bfloat16(r1);
    hrow[lane + 128] = __float2bfloat16(r2);
}

// ---------------- bf16 MFMA GEMM, pre-transposed bf16 B ----------------------
// C(M,N) (+)= A(M,K) @ B(K,N), A bf16 [M][lda], Bt bf16 [N][ldbt] (= B^T,
// zero-padded to ldbt >= ceil64(K)). 128x64 tile, 4 waves 2x2, BK=64.
// M must be a multiple of 128. LDS 27.6 KB.
#define LDT 72   // padded stride in bf16 units (144 B)
template<int ACC, int GELU, int BF16OUT>
__global__ void __launch_bounds__(256) gemm_bt(
        const bf16* __restrict__ A, const bf16* __restrict__ Bt,
        void* __restrict__ Cv, int M, int N, int K, int lda, int ldbt, int ldc) {
    __shared__ short As[128 * LDT];
    __shared__ short Bs[64 * LDT];
    int tid  = threadIdx.x;
    int lane = tid & 63;
    int w    = tid >> 6;
    int wr = w >> 1, wc = w & 1;
    int row0 = blockIdx.y * 128, col0 = blockIdx.x * 64;
    int fr = lane & 15, fq = lane >> 4;
    f32x4 acc[4][2];
    #pragma unroll
    for (int m = 0; m < 4; ++m)
        #pragma unroll
        for (int n = 0; n < 2; ++n) acc[m][n] = (f32x4)(0.0f);

    int sa_row = tid >> 3;          // 0..31
    int sa_kc  = (tid & 7) * 8;     // 0..56
    int sb_col = tid & 63;
    int sb_kb  = (tid >> 6) * 16;   // 0,16,32,48
    bool cok = (col0 + sb_col) < N;

    for (int k0 = 0; k0 < K; k0 += 64) {
        __syncthreads();
        // ---- stage A ----
        #pragma unroll
        for (int p = 0; p < 4; ++p) {
            int r = sa_row + p * 32;
            const bf16* src = A + (long)(row0 + r) * lda + k0 + sa_kc;
            short8 v;
            if (k0 + sa_kc + 8 <= K) {
                v = *(const short8*)src;
            } else {
                #pragma unroll
                for (int i = 0; i < 8; ++i)
                    v[i] = (k0 + sa_kc + i < K) ? *(const short*)&src[i] : (short)0;
            }
            *(short8*)&As[r * LDT + sa_kc] = v;
        }
        // ---- stage B from Bt (contiguous) ----
        {
            short8 v0 = (short8)(0), v1 = (short8)(0);
            if (cok) {
                const bf16* src = Bt + (long)(col0 + sb_col) * ldbt + k0 + sb_kb;
                v0 = *(const short8*)src;
                v1 = *(const short8*)(src + 8);
            }
            *(short8*)&Bs[sb_col * LDT + sb_kb]     = v0;
            *(short8*)&Bs[sb_col * LDT + sb_kb + 8] = v1;
        }
        __syncthreads();
        short8 af[4][2], bf_[2][2];
        #pragma unroll
        for (int m = 0; m < 4; ++m) {
            int r = wr * 64 + m * 16 + fr;
            af[m][0] = *(const short8*)&As[r * LDT + fq * 8];
            af[m][1] = *(const short8*)&As[r * LDT + 32 + fq * 8];
        }
        #pragma unroll
        for (int n = 0; n < 2; ++n) {
            int c = wc * 32 + n * 16 + fr;
            bf_[n][0] = *(const short8*)&Bs[c * LDT + fq * 8];
            bf_[n][1] = *(const short8*)&Bs[c * LDT + 32 + fq * 8];
        }
        #pragma unroll
        for (int m = 0; m < 4; ++m)
            #pragma unroll
            for (int n = 0; n < 2; ++n) {
                acc[m][n] = __builtin_amdgcn_mfma_f32_16x16x32_bf16(
                                af[m][0], bf_[n][0], acc[m][n], 0, 0, 0);
                acc[m][n] = __builtin_amdgcn_mfma_f32_16x16x32_bf16(
                                af[m][1], bf_[n][1], acc[m][n], 0, 0, 0);
            }
    }
    #pragma unroll
    for (int m = 0; m < 4; ++m) {
        #pragma unroll
        for (int n = 0; n < 2; ++n) {
            int gc = col0 + wc * 32 + n * 16 + fr;
            if (gc >= N) continue;
            #pragma unroll
            for (int r = 0; r < 4; ++r) {
                int gr = row0 + wr * 64 + m * 16 + fq * 4 + r;
                float vv = acc[m][n][r];
                if (GELU) vv = gelu_f(vv);
                long o = (long)gr * ldc + gc;
                if (BF16OUT) {
                    ((bf16*)Cv)[o] = __float2bfloat16(vv);
                } else {
                    float* Cc = (float*)Cv;
                    if (ACC) Cc[o] += vv; else Cc[o] = vv;
                }
            }
        }
    }
}

// ---------------- Generic tiled f32 GEMM (small td-side matrices) ------------
template<int ACC, int GELU>
__global__ void __launch_bounds__(256) gemm_kernel(
        const float* __restrict__ A, const float* __restrict__ B,
        float* __restrict__ Cc, int M, int N, int K, int lda, int ldb, int ldc) {
    __shared__ float As[16][68];
    __shared__ float Bs[16][68];
    int tid = threadIdx.x;
    int tr = tid >> 4, tc = tid & 15;
    int row0 = blockIdx.y * 64, col0 = blockIdx.x * 64;
    float acc[4][4] = {};
    int lm = tid >> 4;
    int lk = tid & 15;
    int bk = tid >> 6;
    int bn = tid & 63;
    for (int k0 = 0; k0 < K; k0 += 16) {
        #pragma unroll
        for (int i = 0; i < 4; ++i) {
            int m = lm + i * 16;
            int gr = row0 + m;
            As[lk][m] = (gr < M) ? A[(long)gr * lda + (k0 + lk)] : 0.0f;
        }
        #pragma unroll
        for (int i = 0; i < 4; ++i) {
            int kk = bk + i * 4;
            int gc = col0 + bn;
            Bs[kk][bn] = (gc < N) ? B[(long)(k0 + kk) * ldb + gc] : 0.0f;
        }
        __syncthreads();
        #pragma unroll
        for (int kk = 0; kk < 16; ++kk) {
            float4 av = *(const float4*)&As[kk][tr * 4];
            float4 bv = *(const float4*)&Bs[kk][tc * 4];
            float a[4] = {av.x, av.y, av.z, av.w};
            float b[4] = {bv.x, bv.y, bv.z, bv.w};
            #pragma unroll
            for (int i = 0; i < 4; ++i)
                #pragma unroll
                for (int j = 0; j < 4; ++j)
                    acc[i][j] = fmaf(a[i], b[j], acc[i][j]);
        }
        __syncthreads();
    }
    #pragma unroll
    for (int i = 0; i < 4; ++i) {
        int gr = row0 + tr * 4 + i;
        if (gr >= M) continue;
        #pragma unroll
        for (int j = 0; j < 4; ++j) {
            int gc = col0 + tc * 4 + j;
            if (gc >= N) continue;
            float v = acc[i][j];
            if (GELU) v = gelu_f(v);
            long o = (long)gr * ldc + gc;
            if (ACC) Cc[o] += v; else Cc[o] = v;
        }
    }
}

// ---------------- qn = l2norm(xn @ awq) : block = 256 tokens -----------------
__global__ void __launch_bounds__(256) qn_kernel(
        const float* __restrict__ xn, const float* __restrict__ awq,
        float* __restrict__ qn) {
    __shared__ float aw[192 * RD];     // 15.4 KB
    __shared__ float xs[256 * 33];     // 33.8 KB
    int tid = threadIdx.x;
    long tok0 = (long)blockIdx.x * 256;
    for (int e = tid; e < 192 * RD; e += 256) aw[e] = awq[e];
    float acc[RD];
    #pragma unroll
    for (int j = 0; j < RD; ++j) acc[j] = 0.0f;
    for (int kc = 0; kc < 192; kc += 32) {
        __syncthreads();
        for (int e = tid; e < 256 * 32; e += 256) {
            int tk = e >> 5, kk = e & 31;
            xs[tk * 33 + kk] = xn[(tok0 + tk) * CDIM + kc + kk];
        }
        __syncthreads();
        #pragma unroll 8
        for (int kk = 0; kk < 32; ++kk) {
            float v = xs[tid * 33 + kk];
            const float* ar = &aw[(kc + kk) * RD];
            #pragma unroll
            for (int j = 0; j < RD; ++j) acc[j] = fmaf(v, ar[j], acc[j]);
        }
    }
    float ss = 0.0f;
    #pragma unroll
    for (int j = 0; j < RD; ++j) ss += acc[j] * acc[j];
    float inv = 1.0f / fmaxf(sqrtf(ss), 1e-12f);
    float* orow = qn + (tok0 + tid) * RD;
    #pragma unroll
    for (int j = 0; j < RD; ++j) orow[j] = acc[j] * inv;
}

// ---------------- row-wise L2 normalize (RD=20), in place (kn only) ----------
__global__ void l2n_kernel(float* __restrict__ d, int nrows) {
    int i = blockIdx.x * blockDim.x + threadIdx.x;
    if (i >= nrows) return;
    float* r = d + (long)i * RD;
    float ss = 0.0f;
    #pragma unroll
    for (int k = 0; k < RD; ++k) ss += r[k] * r[k];
    float inv = 1.0f / fmaxf(sqrtf(ss), 1e-12f);
    #pragma unroll
    for (int k = 0; k < RD; ++k) r[k] *= inv;
}

// ---------------- ATD similarity softmax + argmax (block = token) ------------
__global__ void __launch_bounds__(128) sim_kernel(
        const float* __restrict__ qn, const float* __restrict__ kn,
        const float* __restrict__ scale_p, bf16* __restrict__ sim,
        int* __restrict__ tkid) {
    int tok = blockIdx.x;
    int b = tok / NTOK;
    int j = threadIdx.x;
    __shared__ float qv[RD];
    __shared__ float wred[4];
    __shared__ int   wredi[2];
    if (j < RD) qv[j] = qn[(long)tok * RD + j];
    __syncthreads();
    const float* kr = kn + ((long)b * NTD + j) * RD;
    float s = 0.0f;
    #pragma unroll
    for (int r = 0; r < RD; ++r) s = fmaf(qv[r], kr[r], s);
    float scl = 1.0f + fminf(fmaxf(scale_p[0], 0.0f), 3.0f) * logf(128.0f);
    s *= scl;
    float m = s; int mi = j;
    #pragma unroll
    for (int o = 32; o > 0; o >>= 1) {
        float om = __shfl_down(m, o); int oi = __shfl_down(mi, o);
        if (om > m || (om == m && oi < mi)) { m = om; mi = oi; }
    }
    int wv = j >> 6;
    if ((j & 63) == 0) { wred[wv] = m; wredi[wv] = mi; }
    __syncthreads();
    float m0 = wred[0], m1 = wred[1];
    float gm; int gi;
    if (m1 > m0) { gm = m1; gi = wredi[1]; } else { gm = m0; gi = wredi[0]; }
    float p = __expf(s - gm);
    float t = p;
    #pragma unroll
    for (int o = 32; o > 0; o >>= 1) t += __shfl_down(t, o);
    if ((j & 63) == 0) wred[2 + wv] = t;
    __syncthreads();
    float tot = wred[2] + wred[3];
    sim[(long)tok * NTD + j] = __float2bfloat16(p / tot);
    if (j == 0) tkid[tok] = gi;
}

// ---------------- stable counting sort: hist / scan / scatter ----------------
__global__ void hist_kernel(const int* __restrict__ tkid, int* __restrict__ hist) {
    int tile = blockIdx.x;
    int tid = threadIdx.x;
    __shared__ int h[NTD];
    h[tid] = 0;
    __syncthreads();
    atomicAdd(&h[tkid[tile * GSZ + tid]], 1);
    __syncthreads();
    hist[tile * NTD + tid] = h[tid];
}

__global__ void scan_kernel(int* __restrict__ hist) {
    int b = blockIdx.x;
    int c = threadIdx.x;
    __shared__ int tot[NTD];
    __shared__ int base[NTD];
    int run = 0;
    for (int t = 0; t < NGRP; ++t) {
        int id = (b * NGRP + t) * NTD + c;
        int v = hist[id];
        hist[id] = run;
        run += v;
    }
    tot[c] = run;
    __syncthreads();
    if (c == 0) {
        int a = 0;
        for (int i = 0; i < NTD; ++i) { base[i] = a; a += tot[i]; }
    }
    __syncthreads();
    int bc = base[c];
    for (int t = 0; t < NGRP; ++t)
        hist[(b * NGRP + t) * NTD + c] += bc;
}

__global__ void scatter_kernel(const int* __restrict__ tkid, const int* __restrict__ hist,
                               int* __restrict__ idxs) {
    int tile = blockIdx.x;
    int b = tile / NGRP;
    int gl = tile % NGRP;
    int tid = threadIdx.x;
    __shared__ int cats[GSZ];
    int cat = tkid[tile * GSZ + tid];
    cats[tid] = cat;
    __syncthreads();
    int rank = 0;
    for (int j = 0; j < tid; ++j) rank += (cats[j] == cat) ? 1 : 0;
    int pos = hist[tile * NTD + cat] + rank;
    idxs[b * NTOK + pos] = gl * GSZ + tid;
}

#define PLD 72   // V^T row stride in bf16 (144 B)

// ===== O^T attention core (per wave, 64 q-rows):
// S^T = mfma(K_frag, Q_frag): lane(fr,fq) holds S[kv=16c+4fq+r][q=fr] -> softmax
// fully lane-local along q=fr (16 regs + xor16/xor32 over fq).
// PV: O^T = mfma(V^T_frag, P^T_frag): C cols = q = fr -> rescale & 1/l local.
// P^T B-frag exchange (16 bpermute + select):
//   u[jj] = sel(fq>>1, shfl(pk[2ks][jj&1], src), shfl(pk[2ks+1][jj&1], src)),
//   src = fr + 16*(2*(fq&1) + (jj>>1)).

// ---------------- window attention: 1 wave per (window, head, q-chunk) -------
__global__ void __launch_bounds__(64) win_mfma(
        const bf16* __restrict__ qkv, const float* __restrict__ rpb,
        bf16* __restrict__ raw) {
    int bid = blockIdx.x;
    int wv  = bid & 3;
    int t2  = bid >> 2;
    int h   = t2 % NH;
    int wid = t2 / NH;
    int b = wid / 144;
    int wrem = wid % 144;
    int wy = wrem / 12, wx = wrem % 12;
    long base_tok = (long)b * NTOK;

    __shared__ short Vt[32 * PLD];
    __shared__ float rb[961];

    int lane = threadIdx.x;
    int fr = lane & 15, fq = lane >> 4;
    const float scl = 0.17677669529663687f;

    for (int i = lane; i < 961; i += 64) rb[i] = rpb[i * NH + h];

    // Q fragments (B-layout): lane holds Q[q=wv*64+m*16+fr][d=8fq+j]
    short8 qf[4];
    #pragma unroll
    for (int m = 0; m < 4; ++m) {
        int q = wv * 64 + m * 16 + fr;
        long nq = base_tok + (long)(wy * 16 + (q >> 4)) * 192 + (wx * 16 + (q & 15));
        qf[m] = *(const short8*)(qkv + nq * C3 + h * HD + fq * 8);
    }

    f32x4 acc[4][2];
    float mst[4], lst[4];
    #pragma unroll
    for (int m = 0; m < 4; ++m) {
        acc[m][0] = (f32x4)(0.0f); acc[m][1] = (f32x4)(0.0f);
        mst[m] = -INFINITY; lst[m] = 0.0f;
    }

    for (int t = 0; t < 4; ++t) {
        __syncthreads();
        {   // stage V^T[32][64] for this tile (lane = token)
            int p = t * 64 + lane;
            long nk = base_tok + (long)(wy * 16 + (p >> 4)) * 192 + (wx * 16 + (p & 15));
            const bf16* vb = qkv + nk * C3 + 2 * CDIM + h * HD;
            #pragma unroll
            for (int c2 = 0; c2 < 4; ++c2) {
                short8 vv = *(const short8*)(vb + c2 * 8);
                #pragma unroll
                for (int i = 0; i < 8; ++i)
                    Vt[(c2 * 8 + i) * PLD + lane] = vv[i];
            }
        }
        // K fragments (A-layout) direct from global
        short8 ak[4];
        #pragma unroll
        for (int c = 0; c < 4; ++c) {
            int p = t * 64 + c * 16 + fr;
            long nk = base_tok + (long)(wy * 16 + (p >> 4)) * 192 + (wx * 16 + (p & 15));
            ak[c] = *(const short8*)(qkv + nk * C3 + CDIM + h * HD + fq * 8);
        }
        __syncthreads();
        short8 av[2][2];
        #pragma unroll
        for (int n = 0; n < 2; ++n)
            #pragma unroll
            for (int ks = 0; ks < 2; ++ks)
                av[n][ks] = *(const short8*)&Vt[(n * 16 + fr) * PLD + ks * 32 + fq * 8];

        #pragma unroll
        for (int m = 0; m < 4; ++m) {
            int q = wv * 64 + m * 16 + fr;
            int iy = q >> 4, ix = q & 15;
            float s[4][4];
            #pragma unroll
            for (int c = 0; c < 4; ++c) {
                f32x4 s4 = (f32x4)(0.0f);
                s4 = __builtin_amdgcn_mfma_f32_16x16x32_bf16(ak[c], qf[m], s4, 0, 0, 0);
                #pragma unroll
                for (int r = 0; r < 4; ++r) {
                    int j = t * 64 + c * 16 + 4 * fq + r;
                    int jy = j >> 4, jx = j & 15;
                    s[c][r] = s4[r] * scl + rb[(iy - jy + 15) * 31 + (ix - jx + 15)];
                }
            }
            float tmax = s[0][0];
            #pragma unroll
            for (int c = 0; c < 4; ++c)
                #pragma unroll
                for (int r = 0; r < 4; ++r) tmax = fmaxf(tmax, s[c][r]);
            tmax = fmaxf(tmax, __shfl_xor(tmax, 16));
            tmax = fmaxf(tmax, __shfl_xor(tmax, 32));
            float mo = mst[m];
            float mn = fmaxf(mo, tmax);
            float scf = __expf(mo - mn);
            mst[m] = mn;
            float ps = 0.0f;
            #pragma unroll
            for (int c = 0; c < 4; ++c)
                #pragma unroll
                for (int r = 0; r < 4; ++r) {
                    float p = __expf(s[c][r] - mn);
                    s[c][r] = p;
                    ps += p;
                }
            ps += __shfl_xor(ps, 16);
            ps += __shfl_xor(ps, 32);
            lst[m] = lst[m] * scf + ps;
            acc[m][0] *= scf;
            acc[m][1] *= scf;
            unsigned pk[4][2];
            #pragma unroll
            for (int c = 0; c < 4; ++c) {
                pk[c][0] = pack2bf(s[c][0], s[c][1]);
                pk[c][1] = pack2bf(s[c][2], s[c][3]);
            }
            #pragma unroll
            for (int ks = 0; ks < 2; ++ks) {
                unsigned u[4];
                #pragma unroll
                for (int jj = 0; jj < 4; ++jj) {
                    int src = fr + 16 * (2 * (fq & 1) + (jj >> 1));
                    unsigned lo = (unsigned)__shfl((int)pk[2 * ks][jj & 1], src);
                    unsigned hi = (unsigned)__shfl((int)pk[2 * ks + 1][jj & 1], src);
                    u[jj] = (fq & 2) ? hi : lo;
                }
                short8 pb;
                #pragma unroll
                for (int jj = 0; jj < 4; ++jj) {
                    pb[2 * jj]     = (short)(u[jj] & 0xFFFF);
                    pb[2 * jj + 1] = (short)(u[jj] >> 16);
                }
                #pragma unroll
                for (int n = 0; n < 2; ++n)
                    acc[m][n] = __builtin_amdgcn_mfma_f32_16x16x32_bf16(
                                    av[n][ks], pb, acc[m][n], 0, 0, 0);
            }
        }
    }
    // epilogue: lane holds O[q=wv*64+m*16+fr][d=16n+4fq+0..3] -> 8B stores
    #pragma unroll
    for (int m = 0; m < 4; ++m) {
        int q = wv * 64 + m * 16 + fr;
        long nq = base_tok + (long)(wy * 16 + (q >> 4)) * 192 + (wx * 16 + (q & 15));
        float inv = 1.0f / lst[m];
        #pragma unroll
        for (int n = 0; n < 2; ++n) {
            uint2 wv2;
            wv2.x = pack2bf(acc[m][n][0] * inv, acc[m][n][1] * inv);
            wv2.y = pack2bf(acc[m][n][2] * inv, acc[m][n][3] * inv);
            *(uint2*)(raw + nq * RAWLD + h * HD + n * 16 + 4 * fq) = wv2;
        }
    }
}

// ---------------- AC-MSA attention: 1 wave per (group, head, half) -----------
__global__ void __launch_bounds__(64) aca_mfma(
        const bf16* __restrict__ qkv, const int* __restrict__ idxs,
        bf16* __restrict__ raw) {
    int bid = blockIdx.x;
    int half = bid & 1;
    int t2   = bid >> 1;
    int h    = t2 % NH;
    int grp  = t2 / NH;
    int b = grp / NGRP;
    int g = grp % NGRP;
    long btok = (long)b * NTOK;

    __shared__ short Vt[32 * PLD];
    __shared__ int   sidx[GSZ];

    int lane = threadIdx.x;
    int fr = lane & 15, fq = lane >> 4;
    const float scl = 0.17677669529663687f;

    sidx[lane]      = idxs[btok + g * GSZ + lane];
    sidx[lane + 64] = idxs[btok + g * GSZ + lane + 64];
    __syncthreads();

    short8 qf[4];
    #pragma unroll
    for (int m = 0; m < 4; ++m) {
        long n = btok + sidx[half * 64 + m * 16 + fr];
        qf[m] = *(const short8*)(qkv + n * C3 + h * HD + fq * 8);
    }

    f32x4 acc[4][2];
    float mst[4], lst[4];
    #pragma unroll
    for (int m = 0; m < 4; ++m) {
        acc[m][0] = (f32x4)(0.0f); acc[m][1] = (f32x4)(0.0f);
        mst[m] = -INFINITY; lst[m] = 0.0f;
    }

    for (int t = 0; t < 2; ++t) {
        __syncthreads();
        {   // stage V^T (gathered; lane = token)
            long n = btok + sidx[t * 64 + lane];
            const bf16* vb = qkv + n * C3 + 2 * CDIM + h * HD;
            #pragma unroll
            for (int c2 = 0; c2 < 4; ++c2) {
                short8 vv = *(const short8*)(vb + c2 * 8);
                #pragma unroll
                for (int i = 0; i < 8; ++i)
                    Vt[(c2 * 8 + i) * PLD + lane] = vv[i];
            }
        }
        short8 ak[4];
        #pragma unroll
        for (int c = 0; c < 4; ++c) {
            long n = btok + sidx[t * 64 + c * 16 + fr];
            ak[c] = *(const short8*)(qkv + n * C3 + CDIM + h * HD + fq * 8);
        }
        __syncthreads();
        short8 av[2][2];
        #pragma unroll
        for (int n = 0; n < 2; ++n)
            #pragma unroll
            for (int ks = 0; ks < 2; ++ks)
                av[n][ks] = *(const short8*)&Vt[(n * 16 + fr) * PLD + ks * 32 + fq * 8];

        #pragma unroll
        for (int m = 0; m < 4; ++m) {
            float s[4][4];
            #pragma unroll
            for (int c = 0; c < 4; ++c) {
                f32x4 s4 = (f32x4)(0.0f);
                s4 = __builtin_amdgcn_mfma_f32_16x16x32_bf16(ak[c], qf[m], s4, 0, 0, 0);
                #pragma unroll
                for (int r = 0; r < 4; ++r) s[c][r] = s4[r] * scl;
            }
            float tmax = s[0][0];
            #pragma unroll
            for (int c = 0; c < 4; ++c)
                #pragma unroll
                for (int r = 0; r < 4; ++r) tmax = fmaxf(tmax, s[c][r]);
            tmax = fmaxf(tmax, __shfl_xor(tmax, 16));
            tmax = fmaxf(tmax, __shfl_xor(tmax, 32));
            float mo = mst[m];
            float mn = fmaxf(mo, tmax);
            float scf = __expf(mo - mn);
            mst[m] = mn;
            float ps = 0.0f;
            #pragma unroll
            for (int c = 0; c < 4; ++c)
                #pragma unroll
                for (int r = 0; r < 4; ++r) {
                    float p = __expf(s[c][r] - mn);
                    s[c][r] = p;
                    ps += p;
                }
            ps += __shfl_xor(ps, 16);
            ps += __shfl_xor(ps, 32);
            lst[m] = lst[m] * scf + ps;
            acc[m][0] *= scf;
            acc[m][1] *= scf;
            unsigned pk[4][2];
            #pragma unroll
            for (int c = 0; c < 4; ++c) {
                pk[c][0] = pack2bf(s[c][0], s[c][1]);
                pk[c][1] = pack2bf(s[c][2], s[c][3]);
            }
            #pragma unroll
            for (int ks = 0; ks < 2; ++ks) {
                unsigned u[4];
                #pragma unroll
                for (int jj = 0; jj < 4; ++jj) {
                    int src = fr + 16 * (2 * (fq & 1) + (jj >> 1));
                    unsigned lo = (unsigned)__shfl((int)pk[2 * ks][jj & 1], src);
                    unsigned hi = (unsigned)__shfl((int)pk[2 * ks + 1][jj & 1], src);
                    u[jj] = (fq & 2) ? hi : lo;
                }
                short8 pb;
                #pragma unroll
                for (int jj = 0; jj < 4; ++jj) {
                    pb[2 * jj]     = (short)(u[jj] & 0xFFFF);
                    pb[2 * jj + 1] = (short)(u[jj] >> 16);
                }
                #pragma unroll
                for (int n = 0; n < 2; ++n)
                    acc[m][n] = __builtin_amdgcn_mfma_f32_16x16x32_bf16(
                                    av[n][ks], pb, acc[m][n], 0, 0, 0);
            }
        }
    }
    #pragma unroll
    for (int m = 0; m < 4; ++m) {
        long n = btok + sidx[half * 64 + m * 16 + fr];
        float inv = 1.0f / lst[m];
        #pragma unroll
        for (int nn = 0; nn < 2; ++nn) {
            uint2 wv2;
            wv2.x = pack2bf(acc[m][nn][0] * inv, acc[m][nn][1] * inv);
            wv2.y = pack2bf(acc[m][nn][2] * inv, acc[m][nn][3] * inv);
            *(uint2*)(raw + n * RAWLD + CDIM + h * HD + nn * 16 + 4 * fq) = wv2;
        }
    }
}

// ---------------- x_td -> y[:, 384:432] copy ---------------------------------
__global__ void xtdcopy_kernel(const bf16* __restrict__ xtd, bf16* __restrict__ y) {
    long i = (long)blockIdx.x * 256 + threadIdx.x;
    long ntk = i / TDF;
    int c = (int)(i - ntk * TDF);
    y[ntk * CH + MLP + c] = xtd[i];
}

// ---------------- depthwise 5x5 conv + gelu + residual (all 432 ch) ----------
#define YSLD 401
__global__ void __launch_bounds__(256) conv_kernel(
        const bf16* __restrict__ y, const float* __restrict__ dw,
        bf16* __restrict__ z) {
    int bid = blockIdx.x;
    int ck   = bid % 18;
    int tile = (bid / 18) % 144;
    int b    = bid / (18 * 144);
    int ty = tile / 12, tx = tile % 12;
    int c0 = ck * 24;
    __shared__ float ys[24 * YSLD];
    __shared__ float wt[24 * 25];
    int tid = threadIdx.x;
    const bf16* yb = y + (long)b * NTOK * CH;
    for (int e = tid; e < 20 * 20 * 24; e += 256) {
        int p = e / 24, c = e - p * 24;
        int ly = p / 20, lx = p - ly * 20;
        int gy = ty * 16 + ly - 2, gx = tx * 16 + lx - 2;
        float v = 0.0f;
        if (gy >= 0 && gy < 192 && gx >= 0 && gx < 192)
            v = __bfloat162float(yb[(long)(gy * 192 + gx) * CH + c0 + c]);
        ys[c * YSLD + p] = v;
    }
    for (int e = tid; e < 24 * 25; e += 256)
        wt[e] = dw[(c0 + e / 25) * 25 + (e % 25)];
    __syncthreads();
    int py = tid >> 4, px = tid & 15;
    long obase = ((long)b * NTOK + (long)(ty * 16 + py) * 192 + (tx * 16 + px)) * CH + c0;
    for (int c = 0; c < 24; ++c) {
        const float* yc = &ys[c * YSLD];
        float a = 0.0f;
        #pragma unroll
        for (int dy = 0; dy < 5; ++dy)
            #pragma unroll
            for (int dx = 0; dx < 5; ++dx)
                a = fmaf(yc[(py + dy) * 20 + (px + dx)], wt[c * 25 + dy * 5 + dx], a);
        float center = yc[(py + 2) * 20 + (px + 2)];
        z[obase + c] = __float2bfloat16(center + gelu_f(a));
    }
}

// =============================================================================
extern "C" void kernel_launch(void* const* d_in, const int* in_sizes, int n_in,
                              void* d_out, int out_size, void* d_ws, size_t ws_size,
                              hipStream_t stream) {
    (void)in_sizes; (void)n_in; (void)out_size; (void)ws_size;
    const float* x     = (const float*)d_in[0];
    const float* td    = (const float*)d_in[1];
    const float* n1g   = (const float*)d_in[2];
    const float* n1b   = (const float*)d_in[3];
    const float* n2g   = (const float*)d_in[4];
    const float* n2b   = (const float*)d_in[5];
    const float* wqkv  = (const float*)d_in[6];
    const float* rpb   = (const float*)d_in[7];
    const float* wproj = (const float*)d_in[8];
    const float* awq   = (const float*)d_in[9];
    const float* awk   = (const float*)d_in[10];
    const float* awv   = (const float*)d_in[11];
    const float* ascl  = (const float*)d_in[12];
    const float* aproj = (const float*)d_in[13];
    const float* fcw   = (const float*)d_in[14];
    const float* w1    = (const float*)d_in[15];
    const float* dw    = (const float*)d_in[16];
    const float* w2    = (const float*)d_in[17];
    float* out = (float*)d_out;

    char* ws = (char*)d_ws;
    size_t off = 0;
    auto alloc = [&](size_t bytes) -> char* {
        char* p = ws + off;
        off += (bytes + 255) & ~(size_t)255;
        return p;
    };
    bf16*  qkv  = (bf16*)alloc((size_t)NTOT * C3 * 2);       // R0: qkv -> y
    float* xn   = (float*)alloc((size_t)NTOT * CDIM * 4);    // R1: xn f32 -> raw bf16 -> z head
    bf16*  xnh  = (bf16*)alloc((size_t)NTOT * CDIM * 2);     // R2: LN bf16 -> z tail
    float* qn   = (float*)alloc((size_t)NTOT * RD * 4);
    bf16*  simb = (bf16*)alloc((size_t)NTOT * NTD * 2);
    bf16*  xtd  = (bf16*)alloc((size_t)NTOT * TDF * 2);
    float* kn   = (float*)alloc((size_t)2 * NTD * RD * 4);
    float* vtd  = (float*)alloc((size_t)2 * NTD * CDIM * 4);
    float* tdf  = (float*)alloc((size_t)2 * NTD * TDF * 4);
    bf16*  vtdT = (bf16*)alloc((size_t)2 * CDIM * NTD * 2);
    bf16*  tdfT = (bf16*)alloc((size_t)2 * TDF * NTD * 2);
    bf16*  wqkvT= (bf16*)alloc((size_t)C3 * CDIM * 2);
    bf16*  projT= (bf16*)alloc((size_t)CDIM * 384 * 2);
    bf16*  w1T  = (bf16*)alloc((size_t)MLP * CDIM * 2);
    bf16*  w2T  = (bf16*)alloc((size_t)CDIM * 448 * 2);
    int*   tkid = (int*)alloc((size_t)NTOT * 4);
    int*   idxs = (int*)alloc((size_t)NTOT * 4);
    int*   hist = (int*)alloc((size_t)576 * NTD * 4);
    bf16*  y    = qkv;          // reuse R0
    bf16*  raw  = (bf16*)xn;    // reuse R1 (same byte size)
    bf16*  z    = (bf16*)xn;    // spans R1 + part of R2 (both dead by conv)

    hipMemcpyAsync(out, x, (size_t)NTOT * CDIM * 4, hipMemcpyDeviceToDevice, stream);

    // weight packs (bf16, transposed)
    pack_bt<<<(192 * 576 + 255) / 256, 256, 0, stream>>>(wqkv, wqkvT, 192, 576, 192, 0);
    pack_bt<<<(192 * 192 + 255) / 256, 256, 0, stream>>>(wproj, projT, 192, 192, 384, 0);
    pack_bt<<<(192 * 192 + 255) / 256, 256, 0, stream>>>(aproj, projT, 192, 192, 384, 192);
    pack_bt<<<(192 * 384 + 255) / 256, 256, 0, stream>>>(w1, w1T, 192, 384, 192, 0);
    hipMemsetAsync(w2T, 0, (size_t)CDIM * 448 * 2, stream);
    pack_bt<<<(432 * 192 + 255) / 256, 256, 0, stream>>>(w2, w2T, 432, 192, 448, 0);

    // LN1: f32 (qn path) + bf16 (MFMA)
    ln_kernel<1><<<NTOT / 4, 256, 0, stream>>>(x, n1g, n1b, xn, xnh);

    // qkv (bf16) = xnh @ wqkv
    gemm_bt<0,0,1><<<dim3(9, 576), 256, 0, stream>>>(xnh, wqkvT, qkv, NTOT, C3, CDIM, CDIM, CDIM, C3);

    // qn = l2norm(xn @ awq)   (f32 discrete path)
    qn_kernel<<<NTOT / 256, 256, 0, stream>>>(xn, awq, qn);

    // td-side small gemms (f32)
    gemm_kernel<0,0><<<dim3(1, 4), 256, 0, stream>>>(td, awk, kn, 2 * NTD, RD, CDIM, CDIM, RD, RD);
    gemm_kernel<0,0><<<dim3(3, 4), 256, 0, stream>>>(td, awv, vtd, 2 * NTD, CDIM, CDIM, CDIM, CDIM, CDIM);
    gemm_kernel<0,0><<<dim3(1, 4), 256, 0, stream>>>(td, fcw, tdf, 2 * NTD, TDF, CDIM, CDIM, TDF, TDF);
    l2n_kernel<<<1, 256, 0, stream>>>(kn, 2 * NTD);
    for (int b = 0; b < 2; ++b) {
        pack_bt<<<(NTD * CDIM + 255) / 256, 256, 0, stream>>>(
            vtd + (size_t)b * NTD * CDIM, vtdT + (size_t)b * CDIM * NTD, NTD, CDIM, NTD, 0);
        pack_bt<<<(NTD * TDF + 255) / 256, 256, 0, stream>>>(
            tdf + (size_t)b * NTD * TDF, tdfT + (size_t)b * TDF * NTD, NTD, TDF, NTD, 0);
    }

    sim_kernel<<<NTOT, 128, 0, stream>>>(qn, kn, ascl, simb, tkid);

    // d_out += sim @ vtd ; xtd = sim @ tdf
    for (int b = 0; b < 2; ++b) {
        gemm_bt<1,0,0><<<dim3(3, 288), 256, 0, stream>>>(
            simb + (size_t)b * NTOK * NTD, vtdT + (size_t)b * CDIM * NTD,
            out + (size_t)b * NTOK * CDIM, NTOK, CDIM, NTD, NTD, NTD, CDIM);
        gemm_bt<0,0,1><<<dim3(1, 288), 256, 0, stream>>>(
            simb + (size_t)b * NTOK * NTD, tdfT + (size_t)b * TDF * NTD,
            xtd + (size_t)b * NTOK * TDF, NTOK, TDF, NTD, NTD, NTD, TDF);
    }

    hist_kernel<<<576, 128, 0, stream>>>(tkid, hist);
    scan_kernel<<<2, 128, 0, stream>>>(hist);
    scatter_kernel<<<576, 128, 0, stream>>>(tkid, hist, idxs);

    // attentions -> raw (stride 384: win | aca), then one fused projection
    win_mfma<<<288 * NH * 4, 64, 0, stream>>>(qkv, rpb, raw);
    aca_mfma<<<576 * NH * 2, 64, 0, stream>>>(qkv, idxs, raw);
    gemm_bt<1,0,0><<<dim3(3, 576), 256, 0, stream>>>(raw, projT, out, NTOT, CDIM, 384, RAWLD, 384, CDIM);

    // LN2 (bf16 only); qkv dead -> y
    ln_kernel<0><<<NTOT / 4, 256, 0, stream>>>(out, n2g, n2b, nullptr, xnh);

    // y[:, :384] = gelu(xnh @ w1); y[:, 384:432] = x_td
    gemm_bt<0,1,1><<<dim3(6, 576), 256, 0, stream>>>(xnh, w1T, y, NTOT, MLP, CDIM, CDIM, CDIM, CH);
    xtdcopy_kernel<<<(NTOT * TDF) / 256, 256, 0, stream>>>(xtd, y);

    // z = y + gelu(dwconv5x5(y)) (all 432 ch), then d_out += z @ w2 (K=432)
    conv_kernel<<<2 * 144 * 18, 256, 0, stream>>>(y, dw, z);
    gemm_bt<1,0,0><<<dim3(3, 576), 256, 0, stream>>>(z, w2T, out, NTOT, CDIM, CH, CH, 448, CDIM);
}

// Round 7
// 887.290 us; speedup vs baseline: 2.4852x; 1.1465x over previous
//
#include <hip/hip_runtime.h>
#include <hip/hip_bf16.h>
#include <math.h>

#define NTOK 36864   // tokens per batch (192*192)
#define NTOT 73728   // total tokens (B=2)
#define CDIM 192
#define C3   576
#define NH   6
#define HD   32
#define RD   20
#define NTD  128     // dictionary tokens
#define GSZ  128     // ac-msa group size
#define NGRP 288     // groups per batch
#define MLP  384
#define TDF  48
#define CH   432     // MLP+TDF
#define RAWLD 384    // concat(win, aca) raw stride

typedef __hip_bfloat16 bf16;
typedef __attribute__((ext_vector_type(8))) short short8;
typedef __attribute__((ext_vector_type(4))) float f32x4;

__device__ __forceinline__ float gelu_f(float x) {
    return 0.5f * x * (1.0f + erff(x * 0.7071067811865475f));
}

__device__ __forceinline__ unsigned short f32_to_bf16u(float f) {
    unsigned int u = __float_as_uint(f);
    u = (u + 0x7FFFu + ((u >> 16) & 1u)) >> 16;   // RNE
    return (unsigned short)u;
}

__device__ __forceinline__ unsigned pack2bf(float a, float b) {
    return (unsigned)f32_to_bf16u(a) | ((unsigned)f32_to_bf16u(b) << 16);
}

__device__ __forceinline__ float bfbits2f(unsigned short u) {
    return __uint_as_float(((unsigned)u) << 16);
}

// ---------------- weight pack: src f32 [K][N] -> dst bf16 [N][ldk] (+koff) ---
__global__ void pack_bt(const float* __restrict__ src, bf16* __restrict__ dst,
                        int K, int N, int ldk, int koff) {
    int i = blockIdx.x * 256 + threadIdx.x;
    if (i >= K * N) return;
    int k = i / N, n = i - k * N;
    dst[(long)n * ldk + koff + k] = __float2bfloat16(src[i]);
}

// ---------------- LayerNorm: one wave per token; writes f32 and/or bf16 ------
template<int WF32>
__global__ void ln_kernel(const float* __restrict__ x, const float* __restrict__ g,
                          const float* __restrict__ be, float* __restrict__ outf,
                          bf16* __restrict__ outh) {
    long tok = (long)blockIdx.x * 4 + (threadIdx.x >> 6);
    int lane = threadIdx.x & 63;
    const float* row = x + tok * CDIM;
    float v0 = row[lane], v1 = row[lane + 64], v2 = row[lane + 128];
    float s  = v0 + v1 + v2;
    float ss = v0 * v0 + v1 * v1 + v2 * v2;
    #pragma unroll
    for (int o = 32; o > 0; o >>= 1) {
        s  += __shfl_down(s, o);
        ss += __shfl_down(ss, o);
    }
    s = __shfl(s, 0); ss = __shfl(ss, 0);
    float mean = s * (1.0f / 192.0f);
    float var  = ss * (1.0f / 192.0f) - mean * mean;
    float rstd = rsqrtf(var + 1e-5f);
    float r0 = (v0 - mean) * rstd * g[lane]       + be[lane];
    float r1 = (v1 - mean) * rstd * g[lane + 64]  + be[lane + 64];
    float r2 = (v2 - mean) * rstd * g[lane + 128] + be[lane + 128];
    if (WF32) {
        float* orow = outf + tok * CDIM;
        orow[lane] = r0; orow[lane + 64] = r1; orow[lane + 128] = r2;
    }
    bf16* hrow = outh + tok * CDIM;
    hrow[lane]       = __float2bfloat16(r0);
    hrow[lane + 64]  = __float2bfloat16(r1);
    hrow[lane + 128] = __float2bfloat16(r2);
}

// ---------------- bf16 MFMA GEMM, pre-transposed bf16 B ----------------------
// C(M,N) (+)= A(M,K) @ B(K,N), A bf16 [M][lda], Bt bf16 [N][ldbt] (= B^T,
// zero-padded to ldbt >= ceil64(K)). 128x64 tile, 4 waves 2x2, BK=64.
// CHUNKA: A is chunk-planar [K/24][NTOT][24] (conv z layout).
// ADDX:   C = Xadd + acc (f32 only).
#define LDT 72   // padded stride in bf16 units (144 B)
template<int ACC, int GELU, int BF16OUT, int CHUNKA, int ADDX>
__global__ void __launch_bounds__(256) gemm_bt(
        const bf16* __restrict__ A, const bf16* __restrict__ Bt,
        void* __restrict__ Cv, const float* __restrict__ Xadd,
        int M, int N, int K, int lda, int ldbt, int ldc) {
    __shared__ short As[128 * LDT];
    __shared__ short Bs[64 * LDT];
    int tid  = threadIdx.x;
    int lane = tid & 63;
    int w    = tid >> 6;
    int wr = w >> 1, wc = w & 1;
    int row0 = blockIdx.y * 128, col0 = blockIdx.x * 64;
    int fr = lane & 15, fq = lane >> 4;
    f32x4 acc[4][2];
    #pragma unroll
    for (int m = 0; m < 4; ++m)
        #pragma unroll
        for (int n = 0; n < 2; ++n) acc[m][n] = (f32x4)(0.0f);

    int sa_row = tid >> 3;          // 0..31
    int sa_kc  = (tid & 7) * 8;     // 0..56
    int sb_col = tid & 63;
    int sb_kb  = (tid >> 6) * 16;   // 0,16,32,48
    bool cok = (col0 + sb_col) < N;

    for (int k0 = 0; k0 < K; k0 += 64) {
        __syncthreads();
        // ---- stage A ----
        int kk = k0 + sa_kc;
        #pragma unroll
        for (int p = 0; p < 4; ++p) {
            int r = sa_row + p * 32;
            short8 v = (short8)(0);
            if (kk + 8 <= K) {
                const bf16* src;
                if (CHUNKA)
                    src = A + ((long)(kk / 24) * NTOT + row0 + r) * 24 + (kk % 24);
                else
                    src = A + (long)(row0 + r) * lda + kk;
                v = *(const short8*)src;
            } else if (!CHUNKA && kk < K) {
                #pragma unroll
                for (int i = 0; i < 8; ++i)
                    v[i] = (kk + i < K) ? *(const short*)&A[(long)(row0 + r) * lda + kk + i]
                                        : (short)0;
            }
            *(short8*)&As[r * LDT + sa_kc] = v;
        }
        // ---- stage B from Bt (contiguous) ----
        {
            short8 v0 = (short8)(0), v1 = (short8)(0);
            if (cok) {
                const bf16* src = Bt + (long)(col0 + sb_col) * ldbt + k0 + sb_kb;
                v0 = *(const short8*)src;
                v1 = *(const short8*)(src + 8);
            }
            *(short8*)&Bs[sb_col * LDT + sb_kb]     = v0;
            *(short8*)&Bs[sb_col * LDT + sb_kb + 8] = v1;
        }
        __syncthreads();
        short8 af[4][2], bf_[2][2];
        #pragma unroll
        for (int m = 0; m < 4; ++m) {
            int r = wr * 64 + m * 16 + fr;
            af[m][0] = *(const short8*)&As[r * LDT + fq * 8];
            af[m][1] = *(const short8*)&As[r * LDT + 32 + fq * 8];
        }
        #pragma unroll
        for (int n = 0; n < 2; ++n) {
            int c = wc * 32 + n * 16 + fr;
            bf_[n][0] = *(const short8*)&Bs[c * LDT + fq * 8];
            bf_[n][1] = *(const short8*)&Bs[c * LDT + 32 + fq * 8];
        }
        #pragma unroll
        for (int m = 0; m < 4; ++m)
            #pragma unroll
            for (int n = 0; n < 2; ++n) {
                acc[m][n] = __builtin_amdgcn_mfma_f32_16x16x32_bf16(
                                af[m][0], bf_[n][0], acc[m][n], 0, 0, 0);
                acc[m][n] = __builtin_amdgcn_mfma_f32_16x16x32_bf16(
                                af[m][1], bf_[n][1], acc[m][n], 0, 0, 0);
            }
    }
    #pragma unroll
    for (int m = 0; m < 4; ++m) {
        #pragma unroll
        for (int n = 0; n < 2; ++n) {
            int gc = col0 + wc * 32 + n * 16 + fr;
            if (gc >= N) continue;
            #pragma unroll
            for (int r = 0; r < 4; ++r) {
                int gr = row0 + wr * 64 + m * 16 + fq * 4 + r;
                float vv = acc[m][n][r];
                if (GELU) vv = gelu_f(vv);
                long o = (long)gr * ldc + gc;
                if (BF16OUT) {
                    ((bf16*)Cv)[o] = __float2bfloat16(vv);
                } else {
                    float* Cc = (float*)Cv;
                    if (ADDX) Cc[o] = Xadd[o] + vv;
                    else if (ACC) Cc[o] += vv;
                    else Cc[o] = vv;
                }
            }
        }
    }
}

// ---------------- Generic tiled f32 GEMM (small td-side matrices) ------------
template<int ACC, int GELU>
__global__ void __launch_bounds__(256) gemm_kernel(
        const float* __restrict__ A, const float* __restrict__ B,
        float* __restrict__ Cc, int M, int N, int K, int lda, int ldb, int ldc) {
    __shared__ float As[16][68];
    __shared__ float Bs[16][68];
    int tid = threadIdx.x;
    int tr = tid >> 4, tc = tid & 15;
    int row0 = blockIdx.y * 64, col0 = blockIdx.x * 64;
    float acc[4][4] = {};
    int lm = tid >> 4;
    int lk = tid & 15;
    int bk = tid >> 6;
    int bn = tid & 63;
    for (int k0 = 0; k0 < K; k0 += 16) {
        #pragma unroll
        for (int i = 0; i < 4; ++i) {
            int m = lm + i * 16;
            int gr = row0 + m;
            As[lk][m] = (gr < M) ? A[(long)gr * lda + (k0 + lk)] : 0.0f;
        }
        #pragma unroll
        for (int i = 0; i < 4; ++i) {
            int kk = bk + i * 4;
            int gc = col0 + bn;
            Bs[kk][bn] = (gc < N) ? B[(long)(k0 + kk) * ldb + gc] : 0.0f;
        }
        __syncthreads();
        #pragma unroll
        for (int kk = 0; kk < 16; ++kk) {
            float4 av = *(const float4*)&As[kk][tr * 4];
            float4 bv = *(const float4*)&Bs[kk][tc * 4];
            float a[4] = {av.x, av.y, av.z, av.w};
            float b[4] = {bv.x, bv.y, bv.z, bv.w};
            #pragma unroll
            for (int i = 0; i < 4; ++i)
                #pragma unroll
                for (int j = 0; j < 4; ++j)
                    acc[i][j] = fmaf(a[i], b[j], acc[i][j]);
        }
        __syncthreads();
    }
    #pragma unroll
    for (int i = 0; i < 4; ++i) {
        int gr = row0 + tr * 4 + i;
        if (gr >= M) continue;
        #pragma unroll
        for (int j = 0; j < 4; ++j) {
            int gc = col0 + tc * 4 + j;
            if (gc >= N) continue;
            float v = acc[i][j];
            if (GELU) v = gelu_f(v);
            long o = (long)gr * ldc + gc;
            if (ACC) Cc[o] += v; else Cc[o] = v;
        }
    }
}

// ---------------- qn = l2norm(xn @ awq) : block = 256 tokens -----------------
__global__ void __launch_bounds__(256) qn_kernel(
        const float* __restrict__ xn, const float* __restrict__ awq,
        float* __restrict__ qn) {
    __shared__ float aw[192 * RD];     // 15.4 KB
    __shared__ float xs[256 * 33];     // 33.8 KB
    int tid = threadIdx.x;
    long tok0 = (long)blockIdx.x * 256;
    for (int e = tid; e < 192 * RD; e += 256) aw[e] = awq[e];
    float acc[RD];
    #pragma unroll
    for (int j = 0; j < RD; ++j) acc[j] = 0.0f;
    for (int kc = 0; kc < 192; kc += 32) {
        __syncthreads();
        for (int e = tid; e < 256 * 32; e += 256) {
            int tk = e >> 5, kk = e & 31;
            xs[tk * 33 + kk] = xn[(tok0 + tk) * CDIM + kc + kk];
        }
        __syncthreads();
        #pragma unroll 8
        for (int kk = 0; kk < 32; ++kk) {
            float v = xs[tid * 33 + kk];
            const float* ar = &aw[(kc + kk) * RD];
            #pragma unroll
            for (int j = 0; j < RD; ++j) acc[j] = fmaf(v, ar[j], acc[j]);
        }
    }
    float ss = 0.0f;
    #pragma unroll
    for (int j = 0; j < RD; ++j) ss += acc[j] * acc[j];
    float inv = 1.0f / fmaxf(sqrtf(ss), 1e-12f);
    float* orow = qn + (tok0 + tid) * RD;
    #pragma unroll
    for (int j = 0; j < RD; ++j) orow[j] = acc[j] * inv;
}

// ---------------- row-wise L2 normalize (RD=20), in place (kn only) ----------
__global__ void l2n_kernel(float* __restrict__ d, int nrows) {
    int i = blockIdx.x * blockDim.x + threadIdx.x;
    if (i >= nrows) return;
    float* r = d + (long)i * RD;
    float ss = 0.0f;
    #pragma unroll
    for (int k = 0; k < RD; ++k) ss += r[k] * r[k];
    float inv = 1.0f / fmaxf(sqrtf(ss), 1e-12f);
    #pragma unroll
    for (int k = 0; k < RD; ++k) r[k] *= inv;
}

// ---------------- ATD similarity softmax + argmax (block = token) ------------
__global__ void __launch_bounds__(128) sim_kernel(
        const float* __restrict__ qn, const float* __restrict__ kn,
        const float* __restrict__ scale_p, bf16* __restrict__ sim,
        int* __restrict__ tkid) {
    int tok = blockIdx.x;
    int b = tok / NTOK;
    int j = threadIdx.x;
    __shared__ float qv[RD];
    __shared__ float wred[4];
    __shared__ int   wredi[2];
    if (j < RD) qv[j] = qn[(long)tok * RD + j];
    __syncthreads();
    const float* kr = kn + ((long)b * NTD + j) * RD;
    float s = 0.0f;
    #pragma unroll
    for (int r = 0; r < RD; ++r) s = fmaf(qv[r], kr[r], s);
    float scl = 1.0f + fminf(fmaxf(scale_p[0], 0.0f), 3.0f) * logf(128.0f);
    s *= scl;
    float m = s; int mi = j;
    #pragma unroll
    for (int o = 32; o > 0; o >>= 1) {
        float om = __shfl_down(m, o); int oi = __shfl_down(mi, o);
        if (om > m || (om == m && oi < mi)) { m = om; mi = oi; }
    }
    int wv = j >> 6;
    if ((j & 63) == 0) { wred[wv] = m; wredi[wv] = mi; }
    __syncthreads();
    float m0 = wred[0], m1 = wred[1];
    float gm; int gi;
    if (m1 > m0) { gm = m1; gi = wredi[1]; } else { gm = m0; gi = wredi[0]; }
    float p = __expf(s - gm);
    float t = p;
    #pragma unroll
    for (int o = 32; o > 0; o >>= 1) t += __shfl_down(t, o);
    if ((j & 63) == 0) wred[2 + wv] = t;
    __syncthreads();
    float tot = wred[2] + wred[3];
    sim[(long)tok * NTD + j] = __float2bfloat16(p / tot);
    if (j == 0) tkid[tok] = gi;
}

// ---------------- stable counting sort: hist / scan / scatter ----------------
__global__ void hist_kernel(const int* __restrict__ tkid, int* __restrict__ hist) {
    int tile = blockIdx.x;
    int tid = threadIdx.x;
    __shared__ int h[NTD];
    h[tid] = 0;
    __syncthreads();
    atomicAdd(&h[tkid[tile * GSZ + tid]], 1);
    __syncthreads();
    hist[tile * NTD + tid] = h[tid];
}

__global__ void scan_kernel(int* __restrict__ hist) {
    int b = blockIdx.x;
    int c = threadIdx.x;
    __shared__ int tot[NTD];
    __shared__ int base[NTD];
    int run = 0;
    for (int t = 0; t < NGRP; ++t) {
        int id = (b * NGRP + t) * NTD + c;
        int v = hist[id];
        hist[id] = run;
        run += v;
    }
    tot[c] = run;
    __syncthreads();
    if (c == 0) {
        int a = 0;
        for (int i = 0; i < NTD; ++i) { base[i] = a; a += tot[i]; }
    }
    __syncthreads();
    int bc = base[c];
    for (int t = 0; t < NGRP; ++t)
        hist[(b * NGRP + t) * NTD + c] += bc;
}

__global__ void scatter_kernel(const int* __restrict__ tkid, const int* __restrict__ hist,
                               int* __restrict__ idxs) {
    int tile = blockIdx.x;
    int b = tile / NGRP;
    int gl = tile % NGRP;
    int tid = threadIdx.x;
    __shared__ int cats[GSZ];
    int cat = tkid[tile * GSZ + tid];
    cats[tid] = cat;
    __syncthreads();
    int rank = 0;
    for (int j = 0; j < tid; ++j) rank += (cats[j] == cat) ? 1 : 0;
    int pos = hist[tile * NTD + cat] + rank;
    idxs[b * NTOK + pos] = gl * GSZ + tid;
}

#define PLD 72   // V^T row stride in bf16 (144 B)

// ===== O^T attention core (per wave, 64 q-rows):
// S^T = mfma(K_frag, Q_frag): lane(fr,fq) holds S[kv=16c+4fq+r][q=fr] -> softmax
// fully lane-local along q=fr (16 regs + xor16/xor32 over fq).
// PV: O^T = mfma(V^T_frag, P^T_frag): C cols = q = fr -> rescale & 1/l local.
// P^T B-frag exchange (16 bpermute + select):
//   u[jj] = sel(fq>>1, shfl(pk[2ks][jj&1], src), shfl(pk[2ks+1][jj&1], src)),
//   src = fr + 16*(2*(fq&1) + (jj>>1)).

// ---------------- window attention: 1 wave per (window, head, q-chunk) -------
__global__ void __launch_bounds__(64) win_mfma(
        const bf16* __restrict__ qkv, const float* __restrict__ rpb,
        bf16* __restrict__ raw) {
    int bid = blockIdx.x;
    int wv  = bid & 3;
    int t2  = bid >> 2;
    int h   = t2 % NH;
    int wid = t2 / NH;
    int b = wid / 144;
    int wrem = wid % 144;
    int wy = wrem / 12, wx = wrem % 12;
    long base_tok = (long)b * NTOK;

    __shared__ short Vt[32 * PLD];
    __shared__ float rb[961];

    int lane = threadIdx.x;
    int fr = lane & 15, fq = lane >> 4;
    const float scl = 0.17677669529663687f;

    for (int i = lane; i < 961; i += 64) rb[i] = rpb[i * NH + h];

    // Q fragments (B-layout): lane holds Q[q=wv*64+m*16+fr][d=8fq+j]
    short8 qf[4];
    #pragma unroll
    for (int m = 0; m < 4; ++m) {
        int q = wv * 64 + m * 16 + fr;
        long nq = base_tok + (long)(wy * 16 + (q >> 4)) * 192 + (wx * 16 + (q & 15));
        qf[m] = *(const short8*)(qkv + nq * C3 + h * HD + fq * 8);
    }

    f32x4 acc[4][2];
    float mst[4], lst[4];
    #pragma unroll
    for (int m = 0; m < 4; ++m) {
        acc[m][0] = (f32x4)(0.0f); acc[m][1] = (f32x4)(0.0f);
        mst[m] = -INFINITY; lst[m] = 0.0f;
    }

    for (int t = 0; t < 4; ++t) {
        __syncthreads();
        {   // stage V^T[32][64] for this tile (lane = token)
            int p = t * 64 + lane;
            long nk = base_tok + (long)(wy * 16 + (p >> 4)) * 192 + (wx * 16 + (p & 15));
            const bf16* vb = qkv + nk * C3 + 2 * CDIM + h * HD;
            #pragma unroll
            for (int c2 = 0; c2 < 4; ++c2) {
                short8 vv = *(const short8*)(vb + c2 * 8);
                #pragma unroll
                for (int i = 0; i < 8; ++i)
                    Vt[(c2 * 8 + i) * PLD + lane] = vv[i];
            }
        }
        // K fragments (A-layout) direct from global
        short8 ak[4];
        #pragma unroll
        for (int c = 0; c < 4; ++c) {
            int p = t * 64 + c * 16 + fr;
            long nk = base_tok + (long)(wy * 16 + (p >> 4)) * 192 + (wx * 16 + (p & 15));
            ak[c] = *(const short8*)(qkv + nk * C3 + CDIM + h * HD + fq * 8);
        }
        __syncthreads();
        short8 av[2][2];
        #pragma unroll
        for (int n = 0; n < 2; ++n)
            #pragma unroll
            for (int ks = 0; ks < 2; ++ks)
                av[n][ks] = *(const short8*)&Vt[(n * 16 + fr) * PLD + ks * 32 + fq * 8];

        #pragma unroll
        for (int m = 0; m < 4; ++m) {
            int q = wv * 64 + m * 16 + fr;
            int iy = q >> 4, ix = q & 15;
            float s[4][4];
            #pragma unroll
            for (int c = 0; c < 4; ++c) {
                f32x4 s4 = (f32x4)(0.0f);
                s4 = __builtin_amdgcn_mfma_f32_16x16x32_bf16(ak[c], qf[m], s4, 0, 0, 0);
                #pragma unroll
                for (int r = 0; r < 4; ++r) {
                    int j = t * 64 + c * 16 + 4 * fq + r;
                    int jy = j >> 4, jx = j & 15;
                    s[c][r] = s4[r] * scl + rb[(iy - jy + 15) * 31 + (ix - jx + 15)];
                }
            }
            float tmax = s[0][0];
            #pragma unroll
            for (int c = 0; c < 4; ++c)
                #pragma unroll
                for (int r = 0; r < 4; ++r) tmax = fmaxf(tmax, s[c][r]);
            tmax = fmaxf(tmax, __shfl_xor(tmax, 16));
            tmax = fmaxf(tmax, __shfl_xor(tmax, 32));
            float mo = mst[m];
            float mn = fmaxf(mo, tmax);
            float scf = __expf(mo - mn);
            mst[m] = mn;
            float ps = 0.0f;
            #pragma unroll
            for (int c = 0; c < 4; ++c)
                #pragma unroll
                for (int r = 0; r < 4; ++r) {
                    float p = __expf(s[c][r] - mn);
                    s[c][r] = p;
                    ps += p;
                }
            ps += __shfl_xor(ps, 16);
            ps += __shfl_xor(ps, 32);
            lst[m] = lst[m] * scf + ps;
            acc[m][0] *= scf;
            acc[m][1] *= scf;
            unsigned pk[4][2];
            #pragma unroll
            for (int c = 0; c < 4; ++c) {
                pk[c][0] = pack2bf(s[c][0], s[c][1]);
                pk[c][1] = pack2bf(s[c][2], s[c][3]);
            }
            #pragma unroll
            for (int ks = 0; ks < 2; ++ks) {
                unsigned u[4];
                #pragma unroll
                for (int jj = 0; jj < 4; ++jj) {
                    int src = fr + 16 * (2 * (fq & 1) + (jj >> 1));
                    unsigned lo = (unsigned)__shfl((int)pk[2 * ks][jj & 1], src);
                    unsigned hi = (unsigned)__shfl((int)pk[2 * ks + 1][jj & 1], src);
                    u[jj] = (fq & 2) ? hi : lo;
                }
                short8 pb;
                #pragma unroll
                for (int jj = 0; jj < 4; ++jj) {
                    pb[2 * jj]     = (short)(u[jj] & 0xFFFF);
                    pb[2 * jj + 1] = (short)(u[jj] >> 16);
                }
                #pragma unroll
                for (int n = 0; n < 2; ++n)
                    acc[m][n] = __builtin_amdgcn_mfma_f32_16x16x32_bf16(
                                    av[n][ks], pb, acc[m][n], 0, 0, 0);
            }
        }
    }
    // epilogue: lane holds O[q=wv*64+m*16+fr][d=16n+4fq+0..3] -> 8B stores
    #pragma unroll
    for (int m = 0; m < 4; ++m) {
        int q = wv * 64 + m * 16 + fr;
        long nq = base_tok + (long)(wy * 16 + (q >> 4)) * 192 + (wx * 16 + (q & 15));
        float inv = 1.0f / lst[m];
        #pragma unroll
        for (int n = 0; n < 2; ++n) {
            uint2 wv2;
            wv2.x = pack2bf(acc[m][n][0] * inv, acc[m][n][1] * inv);
            wv2.y = pack2bf(acc[m][n][2] * inv, acc[m][n][3] * inv);
            *(uint2*)(raw + nq * RAWLD + h * HD + n * 16 + 4 * fq) = wv2;
        }
    }
}

// ---------------- AC-MSA attention: 1 wave per (group, head, half) -----------
__global__ void __launch_bounds__(64) aca_mfma(
        const bf16* __restrict__ qkv, const int* __restrict__ idxs,
        bf16* __restrict__ raw) {
    int bid = blockIdx.x;
    int half = bid & 1;
    int t2   = bid >> 1;
    int h    = t2 % NH;
    int grp  = t2 / NH;
    int b = grp / NGRP;
    int g = grp % NGRP;
    long btok = (long)b * NTOK;

    __shared__ short Vt[32 * PLD];
    __shared__ int   sidx[GSZ];

    int lane = threadIdx.x;
    int fr = lane & 15, fq = lane >> 4;
    const float scl = 0.17677669529663687f;

    sidx[lane]      = idxs[btok + g * GSZ + lane];
    sidx[lane + 64] = idxs[btok + g * GSZ + lane + 64];
    __syncthreads();

    short8 qf[4];
    #pragma unroll
    for (int m = 0; m < 4; ++m) {
        long n = btok + sidx[half * 64 + m * 16 + fr];
        qf[m] = *(const short8*)(qkv + n * C3 + h * HD + fq * 8);
    }

    f32x4 acc[4][2];
    float mst[4], lst[4];
    #pragma unroll
    for (int m = 0; m < 4; ++m) {
        acc[m][0] = (f32x4)(0.0f); acc[m][1] = (f32x4)(0.0f);
        mst[m] = -INFINITY; lst[m] = 0.0f;
    }

    for (int t = 0; t < 2; ++t) {
        __syncthreads();
        {   // stage V^T (gathered; lane = token)
            long n = btok + sidx[t * 64 + lane];
            const bf16* vb = qkv + n * C3 + 2 * CDIM + h * HD;
            #pragma unroll
            for (int c2 = 0; c2 < 4; ++c2) {
                short8 vv = *(const short8*)(vb + c2 * 8);
                #pragma unroll
                for (int i = 0; i < 8; ++i)
                    Vt[(c2 * 8 + i) * PLD + lane] = vv[i];
            }
        }
        short8 ak[4];
        #pragma unroll
        for (int c = 0; c < 4; ++c) {
            long n = btok + sidx[t * 64 + c * 16 + fr];
            ak[c] = *(const short8*)(qkv + n * C3 + CDIM + h * HD + fq * 8);
        }
        __syncthreads();
        short8 av[2][2];
        #pragma unroll
        for (int n = 0; n < 2; ++n)
            #pragma unroll
            for (int ks = 0; ks < 2; ++ks)
                av[n][ks] = *(const short8*)&Vt[(n * 16 + fr) * PLD + ks * 32 + fq * 8];

        #pragma unroll
        for (int m = 0; m < 4; ++m) {
            float s[4][4];
            #pragma unroll
            for (int c = 0; c < 4; ++c) {
                f32x4 s4 = (f32x4)(0.0f);
                s4 = __builtin_amdgcn_mfma_f32_16x16x32_bf16(ak[c], qf[m], s4, 0, 0, 0);
                #pragma unroll
                for (int r = 0; r < 4; ++r) s[c][r] = s4[r] * scl;
            }
            float tmax = s[0][0];
            #pragma unroll
            for (int c = 0; c < 4; ++c)
                #pragma unroll
                for (int r = 0; r < 4; ++r) tmax = fmaxf(tmax, s[c][r]);
            tmax = fmaxf(tmax, __shfl_xor(tmax, 16));
            tmax = fmaxf(tmax, __shfl_xor(tmax, 32));
            float mo = mst[m];
            float mn = fmaxf(mo, tmax);
            float scf = __expf(mo - mn);
            mst[m] = mn;
            float ps = 0.0f;
            #pragma unroll
            for (int c = 0; c < 4; ++c)
                #pragma unroll
                for (int r = 0; r < 4; ++r) {
                    float p = __expf(s[c][r] - mn);
                    s[c][r] = p;
                    ps += p;
                }
            ps += __shfl_xor(ps, 16);
            ps += __shfl_xor(ps, 32);
            lst[m] = lst[m] * scf + ps;
            acc[m][0] *= scf;
            acc[m][1] *= scf;
            unsigned pk[4][2];
            #pragma unroll
            for (int c = 0; c < 4; ++c) {
                pk[c][0] = pack2bf(s[c][0], s[c][1]);
                pk[c][1] = pack2bf(s[c][2], s[c][3]);
            }
            #pragma unroll
            for (int ks = 0; ks < 2; ++ks) {
                unsigned u[4];
                #pragma unroll
                for (int jj = 0; jj < 4; ++jj) {
                    int src = fr + 16 * (2 * (fq & 1) + (jj >> 1));
                    unsigned lo = (unsigned)__shfl((int)pk[2 * ks][jj & 1], src);
                    unsigned hi = (unsigned)__shfl((int)pk[2 * ks + 1][jj & 1], src);
                    u[jj] = (fq & 2) ? hi : lo;
                }
                short8 pb;
                #pragma unroll
                for (int jj = 0; jj < 4; ++jj) {
                    pb[2 * jj]     = (short)(u[jj] & 0xFFFF);
                    pb[2 * jj + 1] = (short)(u[jj] >> 16);
                }
                #pragma unroll
                for (int n = 0; n < 2; ++n)
                    acc[m][n] = __builtin_amdgcn_mfma_f32_16x16x32_bf16(
                                    av[n][ks], pb, acc[m][n], 0, 0, 0);
            }
        }
    }
    #pragma unroll
    for (int m = 0; m < 4; ++m) {
        long n = btok + sidx[half * 64 + m * 16 + fr];
        float inv = 1.0f / lst[m];
        #pragma unroll
        for (int nn = 0; nn < 2; ++nn) {
            uint2 wv2;
            wv2.x = pack2bf(acc[m][nn][0] * inv, acc[m][nn][1] * inv);
            wv2.y = pack2bf(acc[m][nn][2] * inv, acc[m][nn][3] * inv);
            *(uint2*)(raw + n * RAWLD + CDIM + h * HD + nn * 16 + 4 * fq) = wv2;
        }
    }
}

// ---------------- x_td -> y[:, 384:432] copy ---------------------------------
__global__ void xtdcopy_kernel(const bf16* __restrict__ xtd, bf16* __restrict__ y) {
    long i = (long)blockIdx.x * 256 + threadIdx.x;
    long ntk = i / TDF;
    int c = (int)(i - ntk * TDF);
    y[ntk * CH + MLP + c] = xtd[i];
}

// ---------------- depthwise 5x5 conv + gelu + residual -----------------------
// Output zc is CHUNK-PLANAR: zc[18][NTOT][24] so each block writes fully
// contiguous, 64B-aligned runs it owns exclusively (kills the 7.5x write
// amplification from cross-XCD partial-line RMW on the [token][432] layout).
#define YSLD 401
__global__ void __launch_bounds__(256) conv_kernel(
        const bf16* __restrict__ y, const float* __restrict__ dw,
        bf16* __restrict__ zc) {
    int bid = blockIdx.x;
    int ck   = bid % 18;
    int tile = (bid / 18) % 144;
    int b    = bid / (18 * 144);
    int ty = tile / 12, tx = tile % 12;
    int c0 = ck * 24;
    __shared__ float ys[24 * YSLD];
    __shared__ float wt[24 * 25];
    int tid = threadIdx.x;
    const bf16* yb = y + (long)b * NTOK * CH;
    // stage: thread = (pixel p, 8-ch vector v); 16B coalesced loads
    for (int e = tid; e < 1200; e += 256) {
        int p = e / 3, v = e - p * 3;
        int ly = p / 20, lx = p - ly * 20;
        int gy = ty * 16 + ly - 2, gx = tx * 16 + lx - 2;
        float f[8];
        if (gy >= 0 && gy < 192 && gx >= 0 && gx < 192) {
            short8 hv = *(const short8*)(yb + (long)(gy * 192 + gx) * CH + c0 + v * 8);
            #pragma unroll
            for (int i = 0; i < 8; ++i) f[i] = bfbits2f((unsigned short)hv[i]);
        } else {
            #pragma unroll
            for (int i = 0; i < 8; ++i) f[i] = 0.0f;
        }
        #pragma unroll
        for (int i = 0; i < 8; ++i) ys[(v * 8 + i) * YSLD + p] = f[i];
    }
    for (int e = tid; e < 600; e += 256)
        wt[e] = dw[c0 * 25 + e];
    __syncthreads();
    int py = tid >> 4, px = tid & 15;
    long tok = (long)b * NTOK + (long)(ty * 16 + py) * 192 + (tx * 16 + px);
    unsigned hh[12];
    for (int c = 0; c < 24; ++c) {
        const float* yc = &ys[c * YSLD];
        float a = 0.0f;
        #pragma unroll
        for (int dy = 0; dy < 5; ++dy)
            #pragma unroll
            for (int dx = 0; dx < 5; ++dx)
                a = fmaf(yc[(py + dy) * 20 + (px + dx)], wt[c * 25 + dy * 5 + dx], a);
        float center = yc[(py + 2) * 20 + (px + 2)];
        unsigned short hsh = f32_to_bf16u(center + gelu_f(a));
        if (c & 1) hh[c >> 1] |= ((unsigned)hsh) << 16;
        else       hh[c >> 1] = (unsigned)hsh;
    }
    uint4* zr = (uint4*)(zc + ((long)ck * NTOT + tok) * 24);
    zr[0] = make_uint4(hh[0], hh[1], hh[2], hh[3]);
    zr[1] = make_uint4(hh[4], hh[5], hh[6], hh[7]);
    zr[2] = make_uint4(hh[8], hh[9], hh[10], hh[11]);
}

// =============================================================================
extern "C" void kernel_launch(void* const* d_in, const int* in_sizes, int n_in,
                              void* d_out, int out_size, void* d_ws, size_t ws_size,
                              hipStream_t stream) {
    (void)in_sizes; (void)n_in; (void)out_size; (void)ws_size;
    const float* x     = (const float*)d_in[0];
    const float* td    = (const float*)d_in[1];
    const float* n1g   = (const float*)d_in[2];
    const float* n1b   = (const float*)d_in[3];
    const float* n2g   = (const float*)d_in[4];
    const float* n2b   = (const float*)d_in[5];
    const float* wqkv  = (const float*)d_in[6];
    const float* rpb   = (const float*)d_in[7];
    const float* wproj = (const float*)d_in[8];
    const float* awq   = (const float*)d_in[9];
    const float* awk   = (const float*)d_in[10];
    const float* awv   = (const float*)d_in[11];
    const float* ascl  = (const float*)d_in[12];
    const float* aproj = (const float*)d_in[13];
    const float* fcw   = (const float*)d_in[14];
    const float* w1    = (const float*)d_in[15];
    const float* dw    = (const float*)d_in[16];
    const float* w2    = (const float*)d_in[17];
    float* out = (float*)d_out;

    char* ws = (char*)d_ws;
    size_t off = 0;
    auto alloc = [&](size_t bytes) -> char* {
        char* p = ws + off;
        off += (bytes + 255) & ~(size_t)255;
        return p;
    };
    bf16*  qkv  = (bf16*)alloc((size_t)NTOT * C3 * 2);       // R0: qkv -> y
    float* xn   = (float*)alloc((size_t)NTOT * CDIM * 4);    // R1: xn f32 -> raw bf16 -> zc head
    bf16*  xnh  = (bf16*)alloc((size_t)NTOT * CDIM * 2);     // R2: LN bf16 -> zc tail
    float* qn   = (float*)alloc((size_t)NTOT * RD * 4);
    bf16*  simb = (bf16*)alloc((size_t)NTOT * NTD * 2);
    bf16*  xtd  = (bf16*)alloc((size_t)NTOT * TDF * 2);
    float* kn   = (float*)alloc((size_t)2 * NTD * RD * 4);
    float* vtd  = (float*)alloc((size_t)2 * NTD * CDIM * 4);
    float* tdf  = (float*)alloc((size_t)2 * NTD * TDF * 4);
    bf16*  vtdT = (bf16*)alloc((size_t)2 * CDIM * NTD * 2);
    bf16*  tdfT = (bf16*)alloc((size_t)2 * TDF * NTD * 2);
    bf16*  wqkvT= (bf16*)alloc((size_t)C3 * CDIM * 2);
    bf16*  projT= (bf16*)alloc((size_t)CDIM * 384 * 2);
    bf16*  w1T  = (bf16*)alloc((size_t)MLP * CDIM * 2);
    bf16*  w2T  = (bf16*)alloc((size_t)CDIM * 448 * 2);
    int*   tkid = (int*)alloc((size_t)NTOT * 4);
    int*   idxs = (int*)alloc((size_t)NTOT * 4);
    int*   hist = (int*)alloc((size_t)576 * NTD * 4);
    bf16*  y    = qkv;          // reuse R0
    bf16*  raw  = (bf16*)xn;    // reuse R1
    bf16*  zc   = (bf16*)xn;    // chunk-planar z spans R1 + part of R2 (both dead)

    // weight packs (bf16, transposed)
    pack_bt<<<(192 * 576 + 255) / 256, 256, 0, stream>>>(wqkv, wqkvT, 192, 576, 192, 0);
    pack_bt<<<(192 * 192 + 255) / 256, 256, 0, stream>>>(wproj, projT, 192, 192, 384, 0);
    pack_bt<<<(192 * 192 + 255) / 256, 256, 0, stream>>>(aproj, projT, 192, 192, 384, 192);
    pack_bt<<<(192 * 384 + 255) / 256, 256, 0, stream>>>(w1, w1T, 192, 384, 192, 0);
    hipMemsetAsync(w2T, 0, (size_t)CDIM * 448 * 2, stream);
    pack_bt<<<(432 * 192 + 255) / 256, 256, 0, stream>>>(w2, w2T, 432, 192, 448, 0);

    // LN1: f32 (qn path) + bf16 (MFMA)
    ln_kernel<1><<<NTOT / 4, 256, 0, stream>>>(x, n1g, n1b, xn, xnh);

    // qkv (bf16) = xnh @ wqkv
    gemm_bt<0,0,1,0,0><<<dim3(9, 576), 256, 0, stream>>>(
        xnh, wqkvT, qkv, nullptr, NTOT, C3, CDIM, CDIM, CDIM, C3);

    // qn = l2norm(xn @ awq)   (f32 discrete path)
    qn_kernel<<<NTOT / 256, 256, 0, stream>>>(xn, awq, qn);

    // td-side small gemms (f32)
    gemm_kernel<0,0><<<dim3(1, 4), 256, 0, stream>>>(td, awk, kn, 2 * NTD, RD, CDIM, CDIM, RD, RD);
    gemm_kernel<0,0><<<dim3(3, 4), 256, 0, stream>>>(td, awv, vtd, 2 * NTD, CDIM, CDIM, CDIM, CDIM, CDIM);
    gemm_kernel<0,0><<<dim3(1, 4), 256, 0, stream>>>(td, fcw, tdf, 2 * NTD, TDF, CDIM, CDIM, TDF, TDF);
    l2n_kernel<<<1, 256, 0, stream>>>(kn, 2 * NTD);
    for (int b = 0; b < 2; ++b) {
        pack_bt<<<(NTD * CDIM + 255) / 256, 256, 0, stream>>>(
            vtd + (size_t)b * NTD * CDIM, vtdT + (size_t)b * CDIM * NTD, NTD, CDIM, NTD, 0);
        pack_bt<<<(NTD * TDF + 255) / 256, 256, 0, stream>>>(
            tdf + (size_t)b * NTD * TDF, tdfT + (size_t)b * TDF * NTD, NTD, TDF, NTD, 0);
    }

    sim_kernel<<<NTOT, 128, 0, stream>>>(qn, kn, ascl, simb, tkid);

    // out = x + sim @ vtd (fused residual; no memcpy) ; xtd = sim @ tdf
    for (int b = 0; b < 2; ++b) {
        gemm_bt<0,0,0,0,1><<<dim3(3, 288), 256, 0, stream>>>(
            simb + (size_t)b * NTOK * NTD, vtdT + (size_t)b * CDIM * NTD,
            out + (size_t)b * NTOK * CDIM, x + (size_t)b * NTOK * CDIM,
            NTOK, CDIM, NTD, NTD, NTD, CDIM);
        gemm_bt<0,0,1,0,0><<<dim3(1, 288), 256, 0, stream>>>(
            simb + (size_t)b * NTOK * NTD, tdfT + (size_t)b * TDF * NTD,
            xtd + (size_t)b * NTOK * TDF, nullptr, NTOK, TDF, NTD, NTD, NTD, TDF);
    }

    hist_kernel<<<576, 128, 0, stream>>>(tkid, hist);
    scan_kernel<<<2, 128, 0, stream>>>(hist);
    scatter_kernel<<<576, 128, 0, stream>>>(tkid, hist, idxs);

    // attentions -> raw (stride 384: win | aca), then one fused projection
    win_mfma<<<288 * NH * 4, 64, 0, stream>>>(qkv, rpb, raw);
    aca_mfma<<<576 * NH * 2, 64, 0, stream>>>(qkv, idxs, raw);
    gemm_bt<1,0,0,0,0><<<dim3(3, 576), 256, 0, stream>>>(
        raw, projT, out, nullptr, NTOT, CDIM, 384, RAWLD, 384, CDIM);

    // LN2 (bf16 only); qkv dead -> y
    ln_kernel<0><<<NTOT / 4, 256, 0, stream>>>(out, n2g, n2b, nullptr, xnh);

    // y[:, :384] = gelu(xnh @ w1); y[:, 384:432] = x_td
    gemm_bt<0,1,1,0,0><<<dim3(6, 576), 256, 0, stream>>>(
        xnh, w1T, y, nullptr, NTOT, MLP, CDIM, CDIM, CDIM, CH);
    xtdcopy_kernel<<<(NTOT * TDF) / 256, 256, 0, stream>>>(xtd, y);

    // zc = y + gelu(dwconv5x5(y)) (chunk-planar), then out += zc @ w2 (K=432)
    conv_kernel<<<2 * 144 * 18, 256, 0, stream>>>(y, dw, zc);
    gemm_bt<1,0,0,1,0><<<dim3(3, 576), 256, 0, stream>>>(
        zc, w2T, out, nullptr, NTOT, CDIM, CH, 0, 448, CDIM);
}

// Round 8
// 867.247 us; speedup vs baseline: 2.5426x; 1.0231x over previous
//
#include <hip/hip_runtime.h>
#include <hip/hip_bf16.h>
#include <math.h>

#define NTOK 36864   // tokens per batch (192*192)
#define NTOT 73728   // total tokens (B=2)
#define CDIM 192
#define C3   576
#define NH   6
#define HD   32
#define RD   20
#define NTD  128     // dictionary tokens
#define GSZ  128     // ac-msa group size
#define NGRP 288     // groups per batch
#define MLP  384
#define TDF  48
#define CH   432     // MLP+TDF
#define RAWLD 384    // concat(win, aca) raw stride

typedef __hip_bfloat16 bf16;
typedef __attribute__((ext_vector_type(8))) short short8;
typedef __attribute__((ext_vector_type(4))) float f32x4;

__device__ __forceinline__ float gelu_f(float x) {
    return 0.5f * x * (1.0f + erff(x * 0.7071067811865475f));
}

__device__ __forceinline__ unsigned short f32_to_bf16u(float f) {
    unsigned int u = __float_as_uint(f);
    u = (u + 0x7FFFu + ((u >> 16) & 1u)) >> 16;   // RNE
    return (unsigned short)u;
}

__device__ __forceinline__ unsigned pack2bf(float a, float b) {
    return (unsigned)f32_to_bf16u(a) | ((unsigned)f32_to_bf16u(b) << 16);
}

__device__ __forceinline__ float bfbits2f(unsigned short u) {
    return __uint_as_float(((unsigned)u) << 16);
}

// ---------------- weight pack: src f32 [K][N] -> dst bf16 [N][ldk] (+koff) ---
__global__ void pack_bt(const float* __restrict__ src, bf16* __restrict__ dst,
                        int K, int N, int ldk, int koff) {
    int i = blockIdx.x * 256 + threadIdx.x;
    if (i >= K * N) return;
    int k = i / N, n = i - k * N;
    dst[(long)n * ldk + koff + k] = __float2bfloat16(src[i]);
}

// ---------------- LayerNorm: one wave per token; writes f32 and/or bf16 ------
template<int WF32>
__global__ void ln_kernel(const float* __restrict__ x, const float* __restrict__ g,
                          const float* __restrict__ be, float* __restrict__ outf,
                          bf16* __restrict__ outh) {
    long tok = (long)blockIdx.x * 4 + (threadIdx.x >> 6);
    int lane = threadIdx.x & 63;
    const float* row = x + tok * CDIM;
    float v0 = row[lane], v1 = row[lane + 64], v2 = row[lane + 128];
    float s  = v0 + v1 + v2;
    float ss = v0 * v0 + v1 * v1 + v2 * v2;
    #pragma unroll
    for (int o = 32; o > 0; o >>= 1) {
        s  += __shfl_down(s, o);
        ss += __shfl_down(ss, o);
    }
    s = __shfl(s, 0); ss = __shfl(ss, 0);
    float mean = s * (1.0f / 192.0f);
    float var  = ss * (1.0f / 192.0f) - mean * mean;
    float rstd = rsqrtf(var + 1e-5f);
    float r0 = (v0 - mean) * rstd * g[lane]       + be[lane];
    float r1 = (v1 - mean) * rstd * g[lane + 64]  + be[lane + 64];
    float r2 = (v2 - mean) * rstd * g[lane + 128] + be[lane + 128];
    if (WF32) {
        float* orow = outf + tok * CDIM;
        orow[lane] = r0; orow[lane + 64] = r1; orow[lane + 128] = r2;
    }
    bf16* hrow = outh + tok * CDIM;
    hrow[lane]       = __float2bfloat16(r0);
    hrow[lane + 64]  = __float2bfloat16(r1);
    hrow[lane + 128] = __float2bfloat16(r2);
}

// ---------------- bf16 MFMA GEMM, pre-transposed bf16 B ----------------------
// C(M,N) (+)= A(M,K) @ B(K,N), A bf16 [M][lda], Bt bf16 [N][ldbt] (= B^T,
// zero-padded to ldbt >= ceil64(K)). 128x64 tile, 4 waves 2x2, BK=64.
// CHUNK8: A is chunk-planar [K/8][NTOT][8] (conv zc layout).
// ADDX:   C = Xadd + acc (f32 only).
#define LDT 72   // padded stride in bf16 units (144 B)
template<int ACC, int GELU, int BF16OUT, int CHUNK8, int ADDX>
__global__ void __launch_bounds__(256) gemm_bt(
        const bf16* __restrict__ A, const bf16* __restrict__ Bt,
        void* __restrict__ Cv, const float* __restrict__ Xadd,
        int M, int N, int K, int lda, int ldbt, int ldc) {
    __shared__ short As[128 * LDT];
    __shared__ short Bs[64 * LDT];
    int tid  = threadIdx.x;
    int lane = tid & 63;
    int w    = tid >> 6;
    int wr = w >> 1, wc = w & 1;
    int row0 = blockIdx.y * 128, col0 = blockIdx.x * 64;
    int fr = lane & 15, fq = lane >> 4;
    f32x4 acc[4][2];
    #pragma unroll
    for (int m = 0; m < 4; ++m)
        #pragma unroll
        for (int n = 0; n < 2; ++n) acc[m][n] = (f32x4)(0.0f);

    int sa_row = tid >> 3;          // 0..31
    int sa_kc  = (tid & 7) * 8;     // 0..56
    int sb_col = tid & 63;
    int sb_kb  = (tid >> 6) * 16;   // 0,16,32,48
    bool cok = (col0 + sb_col) < N;

    for (int k0 = 0; k0 < K; k0 += 64) {
        __syncthreads();
        // ---- stage A ----
        int kk = k0 + sa_kc;
        #pragma unroll
        for (int p = 0; p < 4; ++p) {
            int r = sa_row + p * 32;
            short8 v = (short8)(0);
            if (kk + 8 <= K) {
                const bf16* src;
                if (CHUNK8)
                    src = A + ((long)(kk >> 3) * NTOT + row0 + r) * 8;
                else
                    src = A + (long)(row0 + r) * lda + kk;
                v = *(const short8*)src;
            } else if (!CHUNK8 && kk < K) {
                #pragma unroll
                for (int i = 0; i < 8; ++i)
                    v[i] = (kk + i < K) ? *(const short*)&A[(long)(row0 + r) * lda + kk + i]
                                        : (short)0;
            }
            *(short8*)&As[r * LDT + sa_kc] = v;
        }
        // ---- stage B from Bt (contiguous) ----
        {
            short8 v0 = (short8)(0), v1 = (short8)(0);
            if (cok) {
                const bf16* src = Bt + (long)(col0 + sb_col) * ldbt + k0 + sb_kb;
                v0 = *(const short8*)src;
                v1 = *(const short8*)(src + 8);
            }
            *(short8*)&Bs[sb_col * LDT + sb_kb]     = v0;
            *(short8*)&Bs[sb_col * LDT + sb_kb + 8] = v1;
        }
        __syncthreads();
        short8 af[4][2], bf_[2][2];
        #pragma unroll
        for (int m = 0; m < 4; ++m) {
            int r = wr * 64 + m * 16 + fr;
            af[m][0] = *(const short8*)&As[r * LDT + fq * 8];
            af[m][1] = *(const short8*)&As[r * LDT + 32 + fq * 8];
        }
        #pragma unroll
        for (int n = 0; n < 2; ++n) {
            int c = wc * 32 + n * 16 + fr;
            bf_[n][0] = *(const short8*)&Bs[c * LDT + fq * 8];
            bf_[n][1] = *(const short8*)&Bs[c * LDT + 32 + fq * 8];
        }
        #pragma unroll
        for (int m = 0; m < 4; ++m)
            #pragma unroll
            for (int n = 0; n < 2; ++n) {
                acc[m][n] = __builtin_amdgcn_mfma_f32_16x16x32_bf16(
                                af[m][0], bf_[n][0], acc[m][n], 0, 0, 0);
                acc[m][n] = __builtin_amdgcn_mfma_f32_16x16x32_bf16(
                                af[m][1], bf_[n][1], acc[m][n], 0, 0, 0);
            }
    }
    #pragma unroll
    for (int m = 0; m < 4; ++m) {
        #pragma unroll
        for (int n = 0; n < 2; ++n) {
            int gc = col0 + wc * 32 + n * 16 + fr;
            if (gc >= N) continue;
            #pragma unroll
            for (int r = 0; r < 4; ++r) {
                int gr = row0 + wr * 64 + m * 16 + fq * 4 + r;
                float vv = acc[m][n][r];
                if (GELU) vv = gelu_f(vv);
                long o = (long)gr * ldc + gc;
                if (BF16OUT) {
                    ((bf16*)Cv)[o] = __float2bfloat16(vv);
                } else {
                    float* Cc = (float*)Cv;
                    if (ADDX) Cc[o] = Xadd[o] + vv;
                    else if (ACC) Cc[o] += vv;
                    else Cc[o] = vv;
                }
            }
        }
    }
}

// ---------------- Generic tiled f32 GEMM (small td-side matrices) ------------
template<int ACC, int GELU>
__global__ void __launch_bounds__(256) gemm_kernel(
        const float* __restrict__ A, const float* __restrict__ B,
        float* __restrict__ Cc, int M, int N, int K, int lda, int ldb, int ldc) {
    __shared__ float As[16][68];
    __shared__ float Bs[16][68];
    int tid = threadIdx.x;
    int tr = tid >> 4, tc = tid & 15;
    int row0 = blockIdx.y * 64, col0 = blockIdx.x * 64;
    float acc[4][4] = {};
    int lm = tid >> 4;
    int lk = tid & 15;
    int bk = tid >> 6;
    int bn = tid & 63;
    for (int k0 = 0; k0 < K; k0 += 16) {
        #pragma unroll
        for (int i = 0; i < 4; ++i) {
            int m = lm + i * 16;
            int gr = row0 + m;
            As[lk][m] = (gr < M) ? A[(long)gr * lda + (k0 + lk)] : 0.0f;
        }
        #pragma unroll
        for (int i = 0; i < 4; ++i) {
            int kk = bk + i * 4;
            int gc = col0 + bn;
            Bs[kk][bn] = (gc < N) ? B[(long)(k0 + kk) * ldb + gc] : 0.0f;
        }
        __syncthreads();
        #pragma unroll
        for (int kk = 0; kk < 16; ++kk) {
            float4 av = *(const float4*)&As[kk][tr * 4];
            float4 bv = *(const float4*)&Bs[kk][tc * 4];
            float a[4] = {av.x, av.y, av.z, av.w};
            float b[4] = {bv.x, bv.y, bv.z, bv.w};
            #pragma unroll
            for (int i = 0; i < 4; ++i)
                #pragma unroll
                for (int j = 0; j < 4; ++j)
                    acc[i][j] = fmaf(a[i], b[j], acc[i][j]);
        }
        __syncthreads();
    }
    #pragma unroll
    for (int i = 0; i < 4; ++i) {
        int gr = row0 + tr * 4 + i;
        if (gr >= M) continue;
        #pragma unroll
        for (int j = 0; j < 4; ++j) {
            int gc = col0 + tc * 4 + j;
            if (gc >= N) continue;
            float v = acc[i][j];
            if (GELU) v = gelu_f(v);
            long o = (long)gr * ldc + gc;
            if (ACC) Cc[o] += v; else Cc[o] = v;
        }
    }
}

// ---------------- qn = l2norm(xn @ awq) : block = 256 tokens -----------------
__global__ void __launch_bounds__(256) qn_kernel(
        const float* __restrict__ xn, const float* __restrict__ awq,
        float* __restrict__ qn) {
    __shared__ float aw[192 * RD];     // 15.4 KB
    __shared__ float xs[256 * 33];     // 33.8 KB
    int tid = threadIdx.x;
    long tok0 = (long)blockIdx.x * 256;
    for (int e = tid; e < 192 * RD; e += 256) aw[e] = awq[e];
    float acc[RD];
    #pragma unroll
    for (int j = 0; j < RD; ++j) acc[j] = 0.0f;
    for (int kc = 0; kc < 192; kc += 32) {
        __syncthreads();
        for (int e = tid; e < 256 * 32; e += 256) {
            int tk = e >> 5, kk = e & 31;
            xs[tk * 33 + kk] = xn[(tok0 + tk) * CDIM + kc + kk];
        }
        __syncthreads();
        #pragma unroll 8
        for (int kk = 0; kk < 32; ++kk) {
            float v = xs[tid * 33 + kk];
            const float* ar = &aw[(kc + kk) * RD];
            #pragma unroll
            for (int j = 0; j < RD; ++j) acc[j] = fmaf(v, ar[j], acc[j]);
        }
    }
    float ss = 0.0f;
    #pragma unroll
    for (int j = 0; j < RD; ++j) ss += acc[j] * acc[j];
    float inv = 1.0f / fmaxf(sqrtf(ss), 1e-12f);
    float* orow = qn + (tok0 + tid) * RD;
    #pragma unroll
    for (int j = 0; j < RD; ++j) orow[j] = acc[j] * inv;
}

// ---------------- row-wise L2 normalize (RD=20), in place (kn only) ----------
__global__ void l2n_kernel(float* __restrict__ d, int nrows) {
    int i = blockIdx.x * blockDim.x + threadIdx.x;
    if (i >= nrows) return;
    float* r = d + (long)i * RD;
    float ss = 0.0f;
    #pragma unroll
    for (int k = 0; k < RD; ++k) ss += r[k] * r[k];
    float inv = 1.0f / fmaxf(sqrtf(ss), 1e-12f);
    #pragma unroll
    for (int k = 0; k < RD; ++k) r[k] *= inv;
}

// ---------------- ATD similarity softmax + argmax (block = token) ------------
__global__ void __launch_bounds__(128) sim_kernel(
        const float* __restrict__ qn, const float* __restrict__ kn,
        const float* __restrict__ scale_p, bf16* __restrict__ sim,
        int* __restrict__ tkid) {
    int tok = blockIdx.x;
    int b = tok / NTOK;
    int j = threadIdx.x;
    __shared__ float qv[RD];
    __shared__ float wred[4];
    __shared__ int   wredi[2];
    if (j < RD) qv[j] = qn[(long)tok * RD + j];
    __syncthreads();
    const float* kr = kn + ((long)b * NTD + j) * RD;
    float s = 0.0f;
    #pragma unroll
    for (int r = 0; r < RD; ++r) s = fmaf(qv[r], kr[r], s);
    float scl = 1.0f + fminf(fmaxf(scale_p[0], 0.0f), 3.0f) * logf(128.0f);
    s *= scl;
    float m = s; int mi = j;
    #pragma unroll
    for (int o = 32; o > 0; o >>= 1) {
        float om = __shfl_down(m, o); int oi = __shfl_down(mi, o);
        if (om > m || (om == m && oi < mi)) { m = om; mi = oi; }
    }
    int wv = j >> 6;
    if ((j & 63) == 0) { wred[wv] = m; wredi[wv] = mi; }
    __syncthreads();
    float m0 = wred[0], m1 = wred[1];
    float gm; int gi;
    if (m1 > m0) { gm = m1; gi = wredi[1]; } else { gm = m0; gi = wredi[0]; }
    float p = __expf(s - gm);
    float t = p;
    #pragma unroll
    for (int o = 32; o > 0; o >>= 1) t += __shfl_down(t, o);
    if ((j & 63) == 0) wred[2 + wv] = t;
    __syncthreads();
    float tot = wred[2] + wred[3];
    sim[(long)tok * NTD + j] = __float2bfloat16(p / tot);
    if (j == 0) tkid[tok] = gi;
}

// ---------------- stable counting sort: hist / scan / scatter ----------------
__global__ void hist_kernel(const int* __restrict__ tkid, int* __restrict__ hist) {
    int tile = blockIdx.x;
    int tid = threadIdx.x;
    __shared__ int h[NTD];
    h[tid] = 0;
    __syncthreads();
    atomicAdd(&h[tkid[tile * GSZ + tid]], 1);
    __syncthreads();
    hist[tile * NTD + tid] = h[tid];
}

__global__ void scan_kernel(int* __restrict__ hist) {
    int b = blockIdx.x;
    int c = threadIdx.x;
    __shared__ int tot[NTD];
    __shared__ int base[NTD];
    int run = 0;
    for (int t = 0; t < NGRP; ++t) {
        int id = (b * NGRP + t) * NTD + c;
        int v = hist[id];
        hist[id] = run;
        run += v;
    }
    tot[c] = run;
    __syncthreads();
    if (c == 0) {
        int a = 0;
        for (int i = 0; i < NTD; ++i) { base[i] = a; a += tot[i]; }
    }
    __syncthreads();
    int bc = base[c];
    for (int t = 0; t < NGRP; ++t)
        hist[(b * NGRP + t) * NTD + c] += bc;
}

__global__ void scatter_kernel(const int* __restrict__ tkid, const int* __restrict__ hist,
                               int* __restrict__ idxs) {
    int tile = blockIdx.x;
    int b = tile / NGRP;
    int gl = tile % NGRP;
    int tid = threadIdx.x;
    __shared__ int cats[GSZ];
    int cat = tkid[tile * GSZ + tid];
    cats[tid] = cat;
    __syncthreads();
    int rank = 0;
    for (int j = 0; j < tid; ++j) rank += (cats[j] == cat) ? 1 : 0;
    int pos = hist[tile * NTD + cat] + rank;
    idxs[b * NTOK + pos] = gl * GSZ + tid;
}

#define PLD 72   // V^T row stride in bf16 (144 B)

// ===== O^T attention core (per wave, 64 q-rows):
// S^T = mfma(K_frag, Q_frag): lane(fr,fq) holds S[kv=16c+4fq+r][q=fr] -> softmax
// fully lane-local along q=fr (16 regs + xor16/xor32 over fq).
// PV: O^T = mfma(V^T_frag, P^T_frag): C cols = q = fr -> rescale & 1/l local.
// P^T B-frag exchange (16 bpermute + select):
//   u[jj] = sel(fq>>1, shfl(pk[2ks][jj&1], src), shfl(pk[2ks+1][jj&1], src)),
//   src = fr + 16*(2*(fq&1) + (jj>>1)).

// ---------------- window attention: 1 wave per (window, head, q-chunk) -------
__global__ void __launch_bounds__(64) win_mfma(
        const bf16* __restrict__ qkv, const float* __restrict__ rpb,
        bf16* __restrict__ raw) {
    int bid = blockIdx.x;
    int wv  = bid & 3;
    int t2  = bid >> 2;
    int h   = t2 % NH;
    int wid = t2 / NH;
    int b = wid / 144;
    int wrem = wid % 144;
    int wy = wrem / 12, wx = wrem % 12;
    long base_tok = (long)b * NTOK;

    __shared__ short Vt[32 * PLD];
    __shared__ float rb[961];

    int lane = threadIdx.x;
    int fr = lane & 15, fq = lane >> 4;
    const float scl = 0.17677669529663687f;

    for (int i = lane; i < 961; i += 64) rb[i] = rpb[i * NH + h];

    // Q fragments (B-layout): lane holds Q[q=wv*64+m*16+fr][d=8fq+j]
    short8 qf[4];
    #pragma unroll
    for (int m = 0; m < 4; ++m) {
        int q = wv * 64 + m * 16 + fr;
        long nq = base_tok + (long)(wy * 16 + (q >> 4)) * 192 + (wx * 16 + (q & 15));
        qf[m] = *(const short8*)(qkv + nq * C3 + h * HD + fq * 8);
    }

    f32x4 acc[4][2];
    float mst[4], lst[4];
    #pragma unroll
    for (int m = 0; m < 4; ++m) {
        acc[m][0] = (f32x4)(0.0f); acc[m][1] = (f32x4)(0.0f);
        mst[m] = -INFINITY; lst[m] = 0.0f;
    }

    for (int t = 0; t < 4; ++t) {
        __syncthreads();
        {   // stage V^T[32][64] for this tile (lane = token)
            int p = t * 64 + lane;
            long nk = base_tok + (long)(wy * 16 + (p >> 4)) * 192 + (wx * 16 + (p & 15));
            const bf16* vb = qkv + nk * C3 + 2 * CDIM + h * HD;
            #pragma unroll
            for (int c2 = 0; c2 < 4; ++c2) {
                short8 vv = *(const short8*)(vb + c2 * 8);
                #pragma unroll
                for (int i = 0; i < 8; ++i)
                    Vt[(c2 * 8 + i) * PLD + lane] = vv[i];
            }
        }
        // K fragments (A-layout) direct from global
        short8 ak[4];
        #pragma unroll
        for (int c = 0; c < 4; ++c) {
            int p = t * 64 + c * 16 + fr;
            long nk = base_tok + (long)(wy * 16 + (p >> 4)) * 192 + (wx * 16 + (p & 15));
            ak[c] = *(const short8*)(qkv + nk * C3 + CDIM + h * HD + fq * 8);
        }
        __syncthreads();
        short8 av[2][2];
        #pragma unroll
        for (int n = 0; n < 2; ++n)
            #pragma unroll
            for (int ks = 0; ks < 2; ++ks)
                av[n][ks] = *(const short8*)&Vt[(n * 16 + fr) * PLD + ks * 32 + fq * 8];

        #pragma unroll
        for (int m = 0; m < 4; ++m) {
            int q = wv * 64 + m * 16 + fr;
            int iy = q >> 4, ix = q & 15;
            float s[4][4];
            #pragma unroll
            for (int c = 0; c < 4; ++c) {
                f32x4 s4 = (f32x4)(0.0f);
                s4 = __builtin_amdgcn_mfma_f32_16x16x32_bf16(ak[c], qf[m], s4, 0, 0, 0);
                #pragma unroll
                for (int r = 0; r < 4; ++r) {
                    int j = t * 64 + c * 16 + 4 * fq + r;
                    int jy = j >> 4, jx = j & 15;
                    s[c][r] = s4[r] * scl + rb[(iy - jy + 15) * 31 + (ix - jx + 15)];
                }
            }
            float tmax = s[0][0];
            #pragma unroll
            for (int c = 0; c < 4; ++c)
                #pragma unroll
                for (int r = 0; r < 4; ++r) tmax = fmaxf(tmax, s[c][r]);
            tmax = fmaxf(tmax, __shfl_xor(tmax, 16));
            tmax = fmaxf(tmax, __shfl_xor(tmax, 32));
            float mo = mst[m];
            float mn = fmaxf(mo, tmax);
            float scf = __expf(mo - mn);
            mst[m] = mn;
            float ps = 0.0f;
            #pragma unroll
            for (int c = 0; c < 4; ++c)
                #pragma unroll
                for (int r = 0; r < 4; ++r) {
                    float p = __expf(s[c][r] - mn);
                    s[c][r] = p;
                    ps += p;
                }
            ps += __shfl_xor(ps, 16);
            ps += __shfl_xor(ps, 32);
            lst[m] = lst[m] * scf + ps;
            acc[m][0] *= scf;
            acc[m][1] *= scf;
            unsigned pk[4][2];
            #pragma unroll
            for (int c = 0; c < 4; ++c) {
                pk[c][0] = pack2bf(s[c][0], s[c][1]);
                pk[c][1] = pack2bf(s[c][2], s[c][3]);
            }
            #pragma unroll
            for (int ks = 0; ks < 2; ++ks) {
                unsigned u[4];
                #pragma unroll
                for (int jj = 0; jj < 4; ++jj) {
                    int src = fr + 16 * (2 * (fq & 1) + (jj >> 1));
                    unsigned lo = (unsigned)__shfl((int)pk[2 * ks][jj & 1], src);
                    unsigned hi = (unsigned)__shfl((int)pk[2 * ks + 1][jj & 1], src);
                    u[jj] = (fq & 2) ? hi : lo;
                }
                short8 pb;
                #pragma unroll
                for (int jj = 0; jj < 4; ++jj) {
                    pb[2 * jj]     = (short)(u[jj] & 0xFFFF);
                    pb[2 * jj + 1] = (short)(u[jj] >> 16);
                }
                #pragma unroll
                for (int n = 0; n < 2; ++n)
                    acc[m][n] = __builtin_amdgcn_mfma_f32_16x16x32_bf16(
                                    av[n][ks], pb, acc[m][n], 0, 0, 0);
            }
        }
    }
    // epilogue: lane holds O[q=wv*64+m*16+fr][d=16n+4fq+0..3] -> 8B stores
    #pragma unroll
    for (int m = 0; m < 4; ++m) {
        int q = wv * 64 + m * 16 + fr;
        long nq = base_tok + (long)(wy * 16 + (q >> 4)) * 192 + (wx * 16 + (q & 15));
        float inv = 1.0f / lst[m];
        #pragma unroll
        for (int n = 0; n < 2; ++n) {
            uint2 wv2;
            wv2.x = pack2bf(acc[m][n][0] * inv, acc[m][n][1] * inv);
            wv2.y = pack2bf(acc[m][n][2] * inv, acc[m][n][3] * inv);
            *(uint2*)(raw + nq * RAWLD + h * HD + n * 16 + 4 * fq) = wv2;
        }
    }
}

// ---------------- AC-MSA attention: 1 wave per (group, head, half) -----------
__global__ void __launch_bounds__(64) aca_mfma(
        const bf16* __restrict__ qkv, const int* __restrict__ idxs,
        bf16* __restrict__ raw) {
    int bid = blockIdx.x;
    int half = bid & 1;
    int t2   = bid >> 1;
    int h    = t2 % NH;
    int grp  = t2 / NH;
    int b = grp / NGRP;
    int g = grp % NGRP;
    long btok = (long)b * NTOK;

    __shared__ short Vt[32 * PLD];
    __shared__ int   sidx[GSZ];

    int lane = threadIdx.x;
    int fr = lane & 15, fq = lane >> 4;
    const float scl = 0.17677669529663687f;

    sidx[lane]      = idxs[btok + g * GSZ + lane];
    sidx[lane + 64] = idxs[btok + g * GSZ + lane + 64];
    __syncthreads();

    short8 qf[4];
    #pragma unroll
    for (int m = 0; m < 4; ++m) {
        long n = btok + sidx[half * 64 + m * 16 + fr];
        qf[m] = *(const short8*)(qkv + n * C3 + h * HD + fq * 8);
    }

    f32x4 acc[4][2];
    float mst[4], lst[4];
    #pragma unroll
    for (int m = 0; m < 4; ++m) {
        acc[m][0] = (f32x4)(0.0f); acc[m][1] = (f32x4)(0.0f);
        mst[m] = -INFINITY; lst[m] = 0.0f;
    }

    for (int t = 0; t < 2; ++t) {
        __syncthreads();
        {   // stage V^T (gathered; lane = token)
            long n = btok + sidx[t * 64 + lane];
            const bf16* vb = qkv + n * C3 + 2 * CDIM + h * HD;
            #pragma unroll
            for (int c2 = 0; c2 < 4; ++c2) {
                short8 vv = *(const short8*)(vb + c2 * 8);
                #pragma unroll
                for (int i = 0; i < 8; ++i)
                    Vt[(c2 * 8 + i) * PLD + lane] = vv[i];
            }
        }
        short8 ak[4];
        #pragma unroll
        for (int c = 0; c < 4; ++c) {
            long n = btok + sidx[t * 64 + c * 16 + fr];
            ak[c] = *(const short8*)(qkv + n * C3 + CDIM + h * HD + fq * 8);
        }
        __syncthreads();
        short8 av[2][2];
        #pragma unroll
        for (int n = 0; n < 2; ++n)
            #pragma unroll
            for (int ks = 0; ks < 2; ++ks)
                av[n][ks] = *(const short8*)&Vt[(n * 16 + fr) * PLD + ks * 32 + fq * 8];

        #pragma unroll
        for (int m = 0; m < 4; ++m) {
            float s[4][4];
            #pragma unroll
            for (int c = 0; c < 4; ++c) {
                f32x4 s4 = (f32x4)(0.0f);
                s4 = __builtin_amdgcn_mfma_f32_16x16x32_bf16(ak[c], qf[m], s4, 0, 0, 0);
                #pragma unroll
                for (int r = 0; r < 4; ++r) s[c][r] = s4[r] * scl;
            }
            float tmax = s[0][0];
            #pragma unroll
            for (int c = 0; c < 4; ++c)
                #pragma unroll
                for (int r = 0; r < 4; ++r) tmax = fmaxf(tmax, s[c][r]);
            tmax = fmaxf(tmax, __shfl_xor(tmax, 16));
            tmax = fmaxf(tmax, __shfl_xor(tmax, 32));
            float mo = mst[m];
            float mn = fmaxf(mo, tmax);
            float scf = __expf(mo - mn);
            mst[m] = mn;
            float ps = 0.0f;
            #pragma unroll
            for (int c = 0; c < 4; ++c)
                #pragma unroll
                for (int r = 0; r < 4; ++r) {
                    float p = __expf(s[c][r] - mn);
                    s[c][r] = p;
                    ps += p;
                }
            ps += __shfl_xor(ps, 16);
            ps += __shfl_xor(ps, 32);
            lst[m] = lst[m] * scf + ps;
            acc[m][0] *= scf;
            acc[m][1] *= scf;
            unsigned pk[4][2];
            #pragma unroll
            for (int c = 0; c < 4; ++c) {
                pk[c][0] = pack2bf(s[c][0], s[c][1]);
                pk[c][1] = pack2bf(s[c][2], s[c][3]);
            }
            #pragma unroll
            for (int ks = 0; ks < 2; ++ks) {
                unsigned u[4];
                #pragma unroll
                for (int jj = 0; jj < 4; ++jj) {
                    int src = fr + 16 * (2 * (fq & 1) + (jj >> 1));
                    unsigned lo = (unsigned)__shfl((int)pk[2 * ks][jj & 1], src);
                    unsigned hi = (unsigned)__shfl((int)pk[2 * ks + 1][jj & 1], src);
                    u[jj] = (fq & 2) ? hi : lo;
                }
                short8 pb;
                #pragma unroll
                for (int jj = 0; jj < 4; ++jj) {
                    pb[2 * jj]     = (short)(u[jj] & 0xFFFF);
                    pb[2 * jj + 1] = (short)(u[jj] >> 16);
                }
                #pragma unroll
                for (int n = 0; n < 2; ++n)
                    acc[m][n] = __builtin_amdgcn_mfma_f32_16x16x32_bf16(
                                    av[n][ks], pb, acc[m][n], 0, 0, 0);
            }
        }
    }
    #pragma unroll
    for (int m = 0; m < 4; ++m) {
        long n = btok + sidx[half * 64 + m * 16 + fr];
        float inv = 1.0f / lst[m];
        #pragma unroll
        for (int nn = 0; nn < 2; ++nn) {
            uint2 wv2;
            wv2.x = pack2bf(acc[m][nn][0] * inv, acc[m][nn][1] * inv);
            wv2.y = pack2bf(acc[m][nn][2] * inv, acc[m][nn][3] * inv);
            *(uint2*)(raw + n * RAWLD + CDIM + h * HD + nn * 16 + 4 * fq) = wv2;
        }
    }
}

// ---------------- x_td -> y[:, 384:432] copy ---------------------------------
__global__ void xtdcopy_kernel(const bf16* __restrict__ xtd, bf16* __restrict__ y) {
    long i = (long)blockIdx.x * 256 + threadIdx.x;
    long ntk = i / TDF;
    int c = (int)(i - ntk * TDF);
    y[ntk * CH + MLP + c] = xtd[i];
}

// ---------------- depthwise 5x5 conv + gelu + residual -----------------------
// 32x32 output tile, 256 threads, 4 pixels/thread (4 consecutive rows, same
// col), 8-channel chunks. wt in registers; window rows shared across the 4
// stacked 5x5 windows -> 3.2x fewer LDS reads per FMA than 1-pixel/thread.
// Output zc chunk-planar [54][NTOT][8]: exclusive 16B-aligned runs per block.
#define CPS 1296   // ys plane stride (36*36 floats)
__global__ void __launch_bounds__(256) conv_kernel(
        const bf16* __restrict__ y, const float* __restrict__ dw,
        bf16* __restrict__ zc) {
    int bid = blockIdx.x;
    int ck   = bid % 54;            // 8-channel chunk
    int tile = (bid / 54) % 36;     // 6x6 spatial tiles of 32x32
    int b    = bid / (54 * 36);
    int ty = tile / 6, tx = tile % 6;
    int c0 = ck * 8;
    __shared__ float ys[8 * CPS];   // 41.5 KB
    __shared__ float wt[8 * 25];
    int tid = threadIdx.x;
    const bf16* yb = y + (long)b * NTOK * CH;
    for (int p = tid; p < 1296; p += 256) {
        int ly = p / 36, lx = p - ly * 36;
        int gy = ty * 32 + ly - 2, gx = tx * 32 + lx - 2;
        float f[8];
        if (gy >= 0 && gy < 192 && gx >= 0 && gx < 192) {
            short8 hv = *(const short8*)(yb + (long)(gy * 192 + gx) * CH + c0);
            #pragma unroll
            for (int i = 0; i < 8; ++i) f[i] = bfbits2f((unsigned short)hv[i]);
        } else {
            #pragma unroll
            for (int i = 0; i < 8; ++i) f[i] = 0.0f;
        }
        #pragma unroll
        for (int i = 0; i < 8; ++i) ys[i * CPS + p] = f[i];
    }
    for (int e = tid; e < 200; e += 256) wt[e] = dw[c0 * 25 + e];
    __syncthreads();
    int col = tid & 31, r4 = tid >> 5;   // r4 0..7
    int py0 = r4 * 4;                    // output rows py0..py0+3
    long tok0 = (long)b * NTOK + (long)(ty * 32 + py0) * 192 + tx * 32 + col;
    unsigned hh[4][4];                   // [pixel][4 x bf16-pair]
    for (int c = 0; c < 8; ++c) {
        const float* yc = &ys[c * CPS];
        float w[25];
        #pragma unroll
        for (int t = 0; t < 25; ++t) w[t] = wt[c * 25 + t];
        float a[4] = {0.0f, 0.0f, 0.0f, 0.0f};
        #pragma unroll
        for (int dy2 = 0; dy2 < 8; ++dy2) {
            float rv[5];
            #pragma unroll
            for (int dx = 0; dx < 5; ++dx)
                rv[dx] = yc[(py0 + dy2) * 36 + col + dx];
            #pragma unroll
            for (int i = 0; i < 4; ++i) {
                int dy = dy2 - i;
                if (dy >= 0 && dy < 5) {
                    #pragma unroll
                    for (int dx = 0; dx < 5; ++dx)
                        a[i] = fmaf(rv[dx], w[dy * 5 + dx], a[i]);
                }
            }
        }
        #pragma unroll
        for (int i = 0; i < 4; ++i) {
            float center = yc[(py0 + i + 2) * 36 + col + 2];
            unsigned short hsh = f32_to_bf16u(center + gelu_f(a[i]));
            if (c & 1) hh[i][c >> 1] |= ((unsigned)hsh) << 16;
            else       hh[i][c >> 1] = (unsigned)hsh;
        }
    }
    #pragma unroll
    for (int i = 0; i < 4; ++i) {
        long tok = tok0 + (long)i * 192;
        *(uint4*)(zc + ((long)ck * NTOT + tok) * 8) =
            make_uint4(hh[i][0], hh[i][1], hh[i][2], hh[i][3]);
    }
}

// =============================================================================
extern "C" void kernel_launch(void* const* d_in, const int* in_sizes, int n_in,
                              void* d_out, int out_size, void* d_ws, size_t ws_size,
                              hipStream_t stream) {
    (void)in_sizes; (void)n_in; (void)out_size; (void)ws_size;
    const float* x     = (const float*)d_in[0];
    const float* td    = (const float*)d_in[1];
    const float* n1g   = (const float*)d_in[2];
    const float* n1b   = (const float*)d_in[3];
    const float* n2g   = (const float*)d_in[4];
    const float* n2b   = (const float*)d_in[5];
    const float* wqkv  = (const float*)d_in[6];
    const float* rpb   = (const float*)d_in[7];
    const float* wproj = (const float*)d_in[8];
    const float* awq   = (const float*)d_in[9];
    const float* awk   = (const float*)d_in[10];
    const float* awv   = (const float*)d_in[11];
    const float* ascl  = (const float*)d_in[12];
    const float* aproj = (const float*)d_in[13];
    const float* fcw   = (const float*)d_in[14];
    const float* w1    = (const float*)d_in[15];
    const float* dw    = (const float*)d_in[16];
    const float* w2    = (const float*)d_in[17];
    float* out = (float*)d_out;

    char* ws = (char*)d_ws;
    size_t off = 0;
    auto alloc = [&](size_t bytes) -> char* {
        char* p = ws + off;
        off += (bytes + 255) & ~(size_t)255;
        return p;
    };
    bf16*  qkv  = (bf16*)alloc((size_t)NTOT * C3 * 2);       // R0: qkv -> y
    float* xn   = (float*)alloc((size_t)NTOT * CDIM * 4);    // R1: xn f32 -> raw bf16 -> zc head
    bf16*  xnh  = (bf16*)alloc((size_t)NTOT * CDIM * 2);     // R2: LN bf16 -> zc tail
    float* qn   = (float*)alloc((size_t)NTOT * RD * 4);
    bf16*  simb = (bf16*)alloc((size_t)NTOT * NTD * 2);
    bf16*  xtd  = (bf16*)alloc((size_t)NTOT * TDF * 2);
    float* kn   = (float*)alloc((size_t)2 * NTD * RD * 4);
    float* vtd  = (float*)alloc((size_t)2 * NTD * CDIM * 4);
    float* tdf  = (float*)alloc((size_t)2 * NTD * TDF * 4);
    bf16*  vtdT = (bf16*)alloc((size_t)2 * CDIM * NTD * 2);
    bf16*  tdfT = (bf16*)alloc((size_t)2 * TDF * NTD * 2);
    bf16*  wqkvT= (bf16*)alloc((size_t)C3 * CDIM * 2);
    bf16*  projT= (bf16*)alloc((size_t)CDIM * 384 * 2);
    bf16*  w1T  = (bf16*)alloc((size_t)MLP * CDIM * 2);
    bf16*  w2T  = (bf16*)alloc((size_t)CDIM * 448 * 2);
    int*   tkid = (int*)alloc((size_t)NTOT * 4);
    int*   idxs = (int*)alloc((size_t)NTOT * 4);
    int*   hist = (int*)alloc((size_t)576 * NTD * 4);
    bf16*  y    = qkv;          // reuse R0
    bf16*  raw  = (bf16*)xn;    // reuse R1
    bf16*  zc   = (bf16*)xn;    // chunk-planar z spans R1 + part of R2 (both dead)

    // weight packs (bf16, transposed)
    pack_bt<<<(192 * 576 + 255) / 256, 256, 0, stream>>>(wqkv, wqkvT, 192, 576, 192, 0);
    pack_bt<<<(192 * 192 + 255) / 256, 256, 0, stream>>>(wproj, projT, 192, 192, 384, 0);
    pack_bt<<<(192 * 192 + 255) / 256, 256, 0, stream>>>(aproj, projT, 192, 192, 384, 192);
    pack_bt<<<(192 * 384 + 255) / 256, 256, 0, stream>>>(w1, w1T, 192, 384, 192, 0);
    hipMemsetAsync(w2T, 0, (size_t)CDIM * 448 * 2, stream);
    pack_bt<<<(432 * 192 + 255) / 256, 256, 0, stream>>>(w2, w2T, 432, 192, 448, 0);

    // LN1: f32 (qn path) + bf16 (MFMA)
    ln_kernel<1><<<NTOT / 4, 256, 0, stream>>>(x, n1g, n1b, xn, xnh);

    // qkv (bf16) = xnh @ wqkv
    gemm_bt<0,0,1,0,0><<<dim3(9, 576), 256, 0, stream>>>(
        xnh, wqkvT, qkv, nullptr, NTOT, C3, CDIM, CDIM, CDIM, C3);

    // qn = l2norm(xn @ awq)   (f32 discrete path)
    qn_kernel<<<NTOT / 256, 256, 0, stream>>>(xn, awq, qn);

    // td-side small gemms (f32)
    gemm_kernel<0,0><<<dim3(1, 4), 256, 0, stream>>>(td, awk, kn, 2 * NTD, RD, CDIM, CDIM, RD, RD);
    gemm_kernel<0,0><<<dim3(3, 4), 256, 0, stream>>>(td, awv, vtd, 2 * NTD, CDIM, CDIM, CDIM, CDIM, CDIM);
    gemm_kernel<0,0><<<dim3(1, 4), 256, 0, stream>>>(td, fcw, tdf, 2 * NTD, TDF, CDIM, CDIM, TDF, TDF);
    l2n_kernel<<<1, 256, 0, stream>>>(kn, 2 * NTD);
    for (int b = 0; b < 2; ++b) {
        pack_bt<<<(NTD * CDIM + 255) / 256, 256, 0, stream>>>(
            vtd + (size_t)b * NTD * CDIM, vtdT + (size_t)b * CDIM * NTD, NTD, CDIM, NTD, 0);
        pack_bt<<<(NTD * TDF + 255) / 256, 256, 0, stream>>>(
            tdf + (size_t)b * NTD * TDF, tdfT + (size_t)b * TDF * NTD, NTD, TDF, NTD, 0);
    }

    sim_kernel<<<NTOT, 128, 0, stream>>>(qn, kn, ascl, simb, tkid);

    // out = x + sim @ vtd (fused residual) ; xtd = sim @ tdf
    for (int b = 0; b < 2; ++b) {
        gemm_bt<0,0,0,0,1><<<dim3(3, 288), 256, 0, stream>>>(
            simb + (size_t)b * NTOK * NTD, vtdT + (size_t)b * CDIM * NTD,
            out + (size_t)b * NTOK * CDIM, x + (size_t)b * NTOK * CDIM,
            NTOK, CDIM, NTD, NTD, NTD, CDIM);
        gemm_bt<0,0,1,0,0><<<dim3(1, 288), 256, 0, stream>>>(
            simb + (size_t)b * NTOK * NTD, tdfT + (size_t)b * TDF * NTD,
            xtd + (size_t)b * NTOK * TDF, nullptr, NTOK, TDF, NTD, NTD, NTD, TDF);
    }

    hist_kernel<<<576, 128, 0, stream>>>(tkid, hist);
    scan_kernel<<<2, 128, 0, stream>>>(hist);
    scatter_kernel<<<576, 128, 0, stream>>>(tkid, hist, idxs);

    // attentions -> raw (stride 384: win | aca), then one fused projection
    win_mfma<<<288 * NH * 4, 64, 0, stream>>>(qkv, rpb, raw);
    aca_mfma<<<576 * NH * 2, 64, 0, stream>>>(qkv, idxs, raw);
    gemm_bt<1,0,0,0,0><<<dim3(3, 576), 256, 0, stream>>>(
        raw, projT, out, nullptr, NTOT, CDIM, 384, RAWLD, 384, CDIM);

    // LN2 (bf16 only); qkv dead -> y
    ln_kernel<0><<<NTOT / 4, 256, 0, stream>>>(out, n2g, n2b, nullptr, xnh);

    // y[:, :384] = gelu(xnh @ w1); y[:, 384:432] = x_td
    gemm_bt<0,1,1,0,0><<<dim3(6, 576), 256, 0, stream>>>(
        xnh, w1T, y, nullptr, NTOT, MLP, CDIM, CDIM, CDIM, CH);
    xtdcopy_kernel<<<(NTOT * TDF) / 256, 256, 0, stream>>>(xtd, y);

    // zc = y + gelu(dwconv5x5(y)) (8-ch planar), then out += zc @ w2 (K=432)
    conv_kernel<<<2 * 36 * 54, 256, 0, stream>>>(y, dw, zc);
    gemm_bt<1,0,0,1,0><<<dim3(3, 576), 256, 0, stream>>>(
        zc, w2T, out, nullptr, NTOT, CDIM, CH, 0, 448, CDIM);
}

// Round 9
// 824.731 us; speedup vs baseline: 2.6737x; 1.0516x over previous
//
#include <hip/hip_runtime.h>
#include <hip/hip_bf16.h>
#include <math.h>

#define NTOK 36864   // tokens per batch (192*192)
#define NTOT 73728   // total tokens (B=2)
#define CDIM 192
#define C3   576
#define NH   6
#define HD   32
#define RD   20
#define NTD  128     // dictionary tokens
#define GSZ  128     // ac-msa group size
#define NGRP 288     // groups per batch
#define MLP  384
#define TDF  48
#define CH   432     // MLP+TDF
#define RAWLD 384    // concat(win, aca) raw stride

typedef __hip_bfloat16 bf16;
typedef __attribute__((ext_vector_type(8))) short short8;
typedef __attribute__((ext_vector_type(4))) float f32x4;

__device__ __forceinline__ float gelu_f(float x) {
    return 0.5f * x * (1.0f + erff(x * 0.7071067811865475f));
}

__device__ __forceinline__ unsigned short f32_to_bf16u(float f) {
    unsigned int u = __float_as_uint(f);
    u = (u + 0x7FFFu + ((u >> 16) & 1u)) >> 16;   // RNE
    return (unsigned short)u;
}

__device__ __forceinline__ unsigned pack2bf(float a, float b) {
    return (unsigned)f32_to_bf16u(a) | ((unsigned)f32_to_bf16u(b) << 16);
}

__device__ __forceinline__ float bfbits2f(unsigned short u) {
    return __uint_as_float(((unsigned)u) << 16);
}

// ---------------- weight pack: src f32 [K][N] -> dst bf16 [N][ldk] (+koff) ---
__global__ void pack_bt(const float* __restrict__ src, bf16* __restrict__ dst,
                        int K, int N, int ldk, int koff) {
    int i = blockIdx.x * 256 + threadIdx.x;
    if (i >= K * N) return;
    int k = i / N, n = i - k * N;
    dst[(long)n * ldk + koff + k] = __float2bfloat16(src[i]);
}

// ---------------- LayerNorm: one wave per token; writes f32 and/or bf16 ------
template<int WF32>
__global__ void ln_kernel(const float* __restrict__ x, const float* __restrict__ g,
                          const float* __restrict__ be, float* __restrict__ outf,
                          bf16* __restrict__ outh) {
    long tok = (long)blockIdx.x * 4 + (threadIdx.x >> 6);
    int lane = threadIdx.x & 63;
    const float* row = x + tok * CDIM;
    float v0 = row[lane], v1 = row[lane + 64], v2 = row[lane + 128];
    float s  = v0 + v1 + v2;
    float ss = v0 * v0 + v1 * v1 + v2 * v2;
    #pragma unroll
    for (int o = 32; o > 0; o >>= 1) {
        s  += __shfl_down(s, o);
        ss += __shfl_down(ss, o);
    }
    s = __shfl(s, 0); ss = __shfl(ss, 0);
    float mean = s * (1.0f / 192.0f);
    float var  = ss * (1.0f / 192.0f) - mean * mean;
    float rstd = rsqrtf(var + 1e-5f);
    float r0 = (v0 - mean) * rstd * g[lane]       + be[lane];
    float r1 = (v1 - mean) * rstd * g[lane + 64]  + be[lane + 64];
    float r2 = (v2 - mean) * rstd * g[lane + 128] + be[lane + 128];
    if (WF32) {
        float* orow = outf + tok * CDIM;
        orow[lane] = r0; orow[lane + 64] = r1; orow[lane + 128] = r2;
    }
    bf16* hrow = outh + tok * CDIM;
    hrow[lane]       = __float2bfloat16(r0);
    hrow[lane + 64]  = __float2bfloat16(r1);
    hrow[lane + 128] = __float2bfloat16(r2);
}

// ---------------- bf16 MFMA GEMM, pre-transposed bf16 B ----------------------
// C(M,N) (+)= A(M,K) @ B(K,N), A bf16 [M][lda], Bt bf16 [N][ldbt] (= B^T,
// zero-padded to ldbt >= ceil64(K)). 128x64 tile, 4 waves 2x2, BK=64.
// CHUNK8: A is chunk-planar [K/8][NTOT][8] (conv zc / planar y layout).
// ADDX:   C = Xadd + acc (f32 only).
// PL8OUT: bf16 output written chunk-planar [N/8][NTOT][8].
#define LDT 72   // padded stride in bf16 units (144 B)
template<int ACC, int GELU, int BF16OUT, int CHUNK8, int ADDX, int PL8OUT = 0>
__global__ void __launch_bounds__(256) gemm_bt(
        const bf16* __restrict__ A, const bf16* __restrict__ Bt,
        void* __restrict__ Cv, const float* __restrict__ Xadd,
        int M, int N, int K, int lda, int ldbt, int ldc) {
    __shared__ short As[128 * LDT];
    __shared__ short Bs[64 * LDT];
    int tid  = threadIdx.x;
    int lane = tid & 63;
    int w    = tid >> 6;
    int wr = w >> 1, wc = w & 1;
    int row0 = blockIdx.y * 128, col0 = blockIdx.x * 64;
    int fr = lane & 15, fq = lane >> 4;
    f32x4 acc[4][2];
    #pragma unroll
    for (int m = 0; m < 4; ++m)
        #pragma unroll
        for (int n = 0; n < 2; ++n) acc[m][n] = (f32x4)(0.0f);

    int sa_row = tid >> 3;          // 0..31
    int sa_kc  = (tid & 7) * 8;     // 0..56
    int sb_col = tid & 63;
    int sb_kb  = (tid >> 6) * 16;   // 0,16,32,48
    bool cok = (col0 + sb_col) < N;

    for (int k0 = 0; k0 < K; k0 += 64) {
        __syncthreads();
        // ---- stage A ----
        int kk = k0 + sa_kc;
        #pragma unroll
        for (int p = 0; p < 4; ++p) {
            int r = sa_row + p * 32;
            short8 v = (short8)(0);
            if (kk + 8 <= K) {
                const bf16* src;
                if (CHUNK8)
                    src = A + ((long)(kk >> 3) * NTOT + row0 + r) * 8;
                else
                    src = A + (long)(row0 + r) * lda + kk;
                v = *(const short8*)src;
            } else if (!CHUNK8 && kk < K) {
                #pragma unroll
                for (int i = 0; i < 8; ++i)
                    v[i] = (kk + i < K) ? *(const short*)&A[(long)(row0 + r) * lda + kk + i]
                                        : (short)0;
            }
            *(short8*)&As[r * LDT + sa_kc] = v;
        }
        // ---- stage B from Bt (contiguous) ----
        {
            short8 v0 = (short8)(0), v1 = (short8)(0);
            if (cok) {
                const bf16* src = Bt + (long)(col0 + sb_col) * ldbt + k0 + sb_kb;
                v0 = *(const short8*)src;
                v1 = *(const short8*)(src + 8);
            }
            *(short8*)&Bs[sb_col * LDT + sb_kb]     = v0;
            *(short8*)&Bs[sb_col * LDT + sb_kb + 8] = v1;
        }
        __syncthreads();
        short8 af[4][2], bf_[2][2];
        #pragma unroll
        for (int m = 0; m < 4; ++m) {
            int r = wr * 64 + m * 16 + fr;
            af[m][0] = *(const short8*)&As[r * LDT + fq * 8];
            af[m][1] = *(const short8*)&As[r * LDT + 32 + fq * 8];
        }
        #pragma unroll
        for (int n = 0; n < 2; ++n) {
            int c = wc * 32 + n * 16 + fr;
            bf_[n][0] = *(const short8*)&Bs[c * LDT + fq * 8];
            bf_[n][1] = *(const short8*)&Bs[c * LDT + 32 + fq * 8];
        }
        #pragma unroll
        for (int m = 0; m < 4; ++m)
            #pragma unroll
            for (int n = 0; n < 2; ++n) {
                acc[m][n] = __builtin_amdgcn_mfma_f32_16x16x32_bf16(
                                af[m][0], bf_[n][0], acc[m][n], 0, 0, 0);
                acc[m][n] = __builtin_amdgcn_mfma_f32_16x16x32_bf16(
                                af[m][1], bf_[n][1], acc[m][n], 0, 0, 0);
            }
    }
    #pragma unroll
    for (int m = 0; m < 4; ++m) {
        #pragma unroll
        for (int n = 0; n < 2; ++n) {
            int gc = col0 + wc * 32 + n * 16 + fr;
            if (gc >= N) continue;
            #pragma unroll
            for (int r = 0; r < 4; ++r) {
                int gr = row0 + wr * 64 + m * 16 + fq * 4 + r;
                float vv = acc[m][n][r];
                if (GELU) vv = gelu_f(vv);
                if (BF16OUT) {
                    long o;
                    if (PL8OUT) o = ((long)(gc >> 3) * NTOT + gr) * 8 + (gc & 7);
                    else        o = (long)gr * ldc + gc;
                    ((bf16*)Cv)[o] = __float2bfloat16(vv);
                } else {
                    long o = (long)gr * ldc + gc;
                    float* Cc = (float*)Cv;
                    if (ADDX) Cc[o] = Xadd[o] + vv;
                    else if (ACC) Cc[o] += vv;
                    else Cc[o] = vv;
                }
            }
        }
    }
}

// ---------------- Generic tiled f32 GEMM (small td-side matrices) ------------
template<int ACC, int GELU>
__global__ void __launch_bounds__(256) gemm_kernel(
        const float* __restrict__ A, const float* __restrict__ B,
        float* __restrict__ Cc, int M, int N, int K, int lda, int ldb, int ldc) {
    __shared__ float As[16][68];
    __shared__ float Bs[16][68];
    int tid = threadIdx.x;
    int tr = tid >> 4, tc = tid & 15;
    int row0 = blockIdx.y * 64, col0 = blockIdx.x * 64;
    float acc[4][4] = {};
    int lm = tid >> 4;
    int lk = tid & 15;
    int bk = tid >> 6;
    int bn = tid & 63;
    for (int k0 = 0; k0 < K; k0 += 16) {
        #pragma unroll
        for (int i = 0; i < 4; ++i) {
            int m = lm + i * 16;
            int gr = row0 + m;
            As[lk][m] = (gr < M) ? A[(long)gr * lda + (k0 + lk)] : 0.0f;
        }
        #pragma unroll
        for (int i = 0; i < 4; ++i) {
            int kk = bk + i * 4;
            int gc = col0 + bn;
            Bs[kk][bn] = (gc < N) ? B[(long)(k0 + kk) * ldb + gc] : 0.0f;
        }
        __syncthreads();
        #pragma unroll
        for (int kk = 0; kk < 16; ++kk) {
            float4 av = *(const float4*)&As[kk][tr * 4];
            float4 bv = *(const float4*)&Bs[kk][tc * 4];
            float a[4] = {av.x, av.y, av.z, av.w};
            float b[4] = {bv.x, bv.y, bv.z, bv.w};
            #pragma unroll
            for (int i = 0; i < 4; ++i)
                #pragma unroll
                for (int j = 0; j < 4; ++j)
                    acc[i][j] = fmaf(a[i], b[j], acc[i][j]);
        }
        __syncthreads();
    }
    #pragma unroll
    for (int i = 0; i < 4; ++i) {
        int gr = row0 + tr * 4 + i;
        if (gr >= M) continue;
        #pragma unroll
        for (int j = 0; j < 4; ++j) {
            int gc = col0 + tc * 4 + j;
            if (gc >= N) continue;
            float v = acc[i][j];
            if (GELU) v = gelu_f(v);
            long o = (long)gr * ldc + gc;
            if (ACC) Cc[o] += v; else Cc[o] = v;
        }
    }
}

// ---------------- qn = l2norm(xn @ awq) : block = 256 tokens -----------------
__global__ void __launch_bounds__(256) qn_kernel(
        const float* __restrict__ xn, const float* __restrict__ awq,
        float* __restrict__ qn) {
    __shared__ float aw[192 * RD];     // 15.4 KB
    __shared__ float xs[256 * 33];     // 33.8 KB
    int tid = threadIdx.x;
    long tok0 = (long)blockIdx.x * 256;
    for (int e = tid; e < 192 * RD; e += 256) aw[e] = awq[e];
    float acc[RD];
    #pragma unroll
    for (int j = 0; j < RD; ++j) acc[j] = 0.0f;
    for (int kc = 0; kc < 192; kc += 32) {
        __syncthreads();
        for (int e = tid; e < 256 * 32; e += 256) {
            int tk = e >> 5, kk = e & 31;
            xs[tk * 33 + kk] = xn[(tok0 + tk) * CDIM + kc + kk];
        }
        __syncthreads();
        #pragma unroll 8
        for (int kk = 0; kk < 32; ++kk) {
            float v = xs[tid * 33 + kk];
            const float* ar = &aw[(kc + kk) * RD];
            #pragma unroll
            for (int j = 0; j < RD; ++j) acc[j] = fmaf(v, ar[j], acc[j]);
        }
    }
    float ss = 0.0f;
    #pragma unroll
    for (int j = 0; j < RD; ++j) ss += acc[j] * acc[j];
    float inv = 1.0f / fmaxf(sqrtf(ss), 1e-12f);
    float* orow = qn + (tok0 + tid) * RD;
    #pragma unroll
    for (int j = 0; j < RD; ++j) orow[j] = acc[j] * inv;
}

// ---------------- row-wise L2 normalize (RD=20), in place (kn only) ----------
__global__ void l2n_kernel(float* __restrict__ d, int nrows) {
    int i = blockIdx.x * blockDim.x + threadIdx.x;
    if (i >= nrows) return;
    float* r = d + (long)i * RD;
    float ss = 0.0f;
    #pragma unroll
    for (int k = 0; k < RD; ++k) ss += r[k] * r[k];
    float inv = 1.0f / fmaxf(sqrtf(ss), 1e-12f);
    #pragma unroll
    for (int k = 0; k < RD; ++k) r[k] *= inv;
}

// ---------------- ATD similarity softmax + argmax (block = token) ------------
__global__ void __launch_bounds__(128) sim_kernel(
        const float* __restrict__ qn, const float* __restrict__ kn,
        const float* __restrict__ scale_p, bf16* __restrict__ sim,
        int* __restrict__ tkid) {
    int tok = blockIdx.x;
    int b = tok / NTOK;
    int j = threadIdx.x;
    __shared__ float qv[RD];
    __shared__ float wred[4];
    __shared__ int   wredi[2];
    if (j < RD) qv[j] = qn[(long)tok * RD + j];
    __syncthreads();
    const float* kr = kn + ((long)b * NTD + j) * RD;
    float s = 0.0f;
    #pragma unroll
    for (int r = 0; r < RD; ++r) s = fmaf(qv[r], kr[r], s);
    float scl = 1.0f + fminf(fmaxf(scale_p[0], 0.0f), 3.0f) * logf(128.0f);
    s *= scl;
    float m = s; int mi = j;
    #pragma unroll
    for (int o = 32; o > 0; o >>= 1) {
        float om = __shfl_down(m, o); int oi = __shfl_down(mi, o);
        if (om > m || (om == m && oi < mi)) { m = om; mi = oi; }
    }
    int wv = j >> 6;
    if ((j & 63) == 0) { wred[wv] = m; wredi[wv] = mi; }
    __syncthreads();
    float m0 = wred[0], m1 = wred[1];
    float gm; int gi;
    if (m1 > m0) { gm = m1; gi = wredi[1]; } else { gm = m0; gi = wredi[0]; }
    float p = __expf(s - gm);
    float t = p;
    #pragma unroll
    for (int o = 32; o > 0; o >>= 1) t += __shfl_down(t, o);
    if ((j & 63) == 0) wred[2 + wv] = t;
    __syncthreads();
    float tot = wred[2] + wred[3];
    sim[(long)tok * NTD + j] = __float2bfloat16(p / tot);
    if (j == 0) tkid[tok] = gi;
}

// ---------------- stable counting sort: hist / scan / scatter ----------------
__global__ void hist_kernel(const int* __restrict__ tkid, int* __restrict__ hist) {
    int tile = blockIdx.x;
    int tid = threadIdx.x;
    __shared__ int h[NTD];
    h[tid] = 0;
    __syncthreads();
    atomicAdd(&h[tkid[tile * GSZ + tid]], 1);
    __syncthreads();
    hist[tile * NTD + tid] = h[tid];
}

__global__ void scan_kernel(int* __restrict__ hist) {
    int b = blockIdx.x;
    int c = threadIdx.x;
    __shared__ int tot[NTD];
    __shared__ int base[NTD];
    int run = 0;
    for (int t = 0; t < NGRP; ++t) {
        int id = (b * NGRP + t) * NTD + c;
        int v = hist[id];
        hist[id] = run;
        run += v;
    }
    tot[c] = run;
    __syncthreads();
    if (c == 0) {
        int a = 0;
        for (int i = 0; i < NTD; ++i) { base[i] = a; a += tot[i]; }
    }
    __syncthreads();
    int bc = base[c];
    for (int t = 0; t < NGRP; ++t)
        hist[(b * NGRP + t) * NTD + c] += bc;
}

__global__ void scatter_kernel(const int* __restrict__ tkid, const int* __restrict__ hist,
                               int* __restrict__ idxs) {
    int tile = blockIdx.x;
    int b = tile / NGRP;
    int gl = tile % NGRP;
    int tid = threadIdx.x;
    __shared__ int cats[GSZ];
    int cat = tkid[tile * GSZ + tid];
    cats[tid] = cat;
    __syncthreads();
    int rank = 0;
    for (int j = 0; j < tid; ++j) rank += (cats[j] == cat) ? 1 : 0;
    int pos = hist[tile * NTD + cat] + rank;
    idxs[b * NTOK + pos] = gl * GSZ + tid;
}

#define PLD 72   // V^T row stride in bf16 (144 B)

// ===== O^T attention core (per wave, 64 q-rows):
// S^T = mfma(K_frag, Q_frag): lane(fr,fq) holds S[kv=16c+4fq+r][q=fr] -> softmax
// fully lane-local along q=fr (16 regs + xor16/xor32 over fq).
// PV: O^T = mfma(V^T_frag, P^T_frag): C cols = q = fr -> rescale & 1/l local.
// P^T B-frag exchange (16 bpermute + select):
//   u[jj] = sel(fq>>1, shfl(pk[2ks][jj&1], src), shfl(pk[2ks+1][jj&1], src)),
//   src = fr + 16*(2*(fq&1) + (jj>>1)).

// ---------------- window attention: 1 wave per (window, head, q-chunk) -------
__global__ void __launch_bounds__(64) win_mfma(
        const bf16* __restrict__ qkv, const float* __restrict__ rpb,
        bf16* __restrict__ raw) {
    int bid = blockIdx.x;
    int wv  = bid & 3;
    int t2  = bid >> 2;
    int h   = t2 % NH;
    int wid = t2 / NH;
    int b = wid / 144;
    int wrem = wid % 144;
    int wy = wrem / 12, wx = wrem % 12;
    long base_tok = (long)b * NTOK;

    __shared__ short Vt[32 * PLD];
    __shared__ float rb[961];

    int lane = threadIdx.x;
    int fr = lane & 15, fq = lane >> 4;
    const float scl = 0.17677669529663687f;

    for (int i = lane; i < 961; i += 64) rb[i] = rpb[i * NH + h];

    // Q fragments (B-layout): lane holds Q[q=wv*64+m*16+fr][d=8fq+j]
    short8 qf[4];
    #pragma unroll
    for (int m = 0; m < 4; ++m) {
        int q = wv * 64 + m * 16 + fr;
        long nq = base_tok + (long)(wy * 16 + (q >> 4)) * 192 + (wx * 16 + (q & 15));
        qf[m] = *(const short8*)(qkv + nq * C3 + h * HD + fq * 8);
    }

    f32x4 acc[4][2];
    float mst[4], lst[4];
    #pragma unroll
    for (int m = 0; m < 4; ++m) {
        acc[m][0] = (f32x4)(0.0f); acc[m][1] = (f32x4)(0.0f);
        mst[m] = -INFINITY; lst[m] = 0.0f;
    }

    for (int t = 0; t < 4; ++t) {
        __syncthreads();
        {   // stage V^T[32][64] for this tile (lane = token)
            int p = t * 64 + lane;
            long nk = base_tok + (long)(wy * 16 + (p >> 4)) * 192 + (wx * 16 + (p & 15));
            const bf16* vb = qkv + nk * C3 + 2 * CDIM + h * HD;
            #pragma unroll
            for (int c2 = 0; c2 < 4; ++c2) {
                short8 vv = *(const short8*)(vb + c2 * 8);
                #pragma unroll
                for (int i = 0; i < 8; ++i)
                    Vt[(c2 * 8 + i) * PLD + lane] = vv[i];
            }
        }
        // K fragments (A-layout) direct from global
        short8 ak[4];
        #pragma unroll
        for (int c = 0; c < 4; ++c) {
            int p = t * 64 + c * 16 + fr;
            long nk = base_tok + (long)(wy * 16 + (p >> 4)) * 192 + (wx * 16 + (p & 15));
            ak[c] = *(const short8*)(qkv + nk * C3 + CDIM + h * HD + fq * 8);
        }
        __syncthreads();
        short8 av[2][2];
        #pragma unroll
        for (int n = 0; n < 2; ++n)
            #pragma unroll
            for (int ks = 0; ks < 2; ++ks)
                av[n][ks] = *(const short8*)&Vt[(n * 16 + fr) * PLD + ks * 32 + fq * 8];

        #pragma unroll
        for (int m = 0; m < 4; ++m) {
            int q = wv * 64 + m * 16 + fr;
            int iy = q >> 4, ix = q & 15;
            float s[4][4];
            #pragma unroll
            for (int c = 0; c < 4; ++c) {
                f32x4 s4 = (f32x4)(0.0f);
                s4 = __builtin_amdgcn_mfma_f32_16x16x32_bf16(ak[c], qf[m], s4, 0, 0, 0);
                #pragma unroll
                for (int r = 0; r < 4; ++r) {
                    int j = t * 64 + c * 16 + 4 * fq + r;
                    int jy = j >> 4, jx = j & 15;
                    s[c][r] = s4[r] * scl + rb[(iy - jy + 15) * 31 + (ix - jx + 15)];
                }
            }
            float tmax = s[0][0];
            #pragma unroll
            for (int c = 0; c < 4; ++c)
                #pragma unroll
                for (int r = 0; r < 4; ++r) tmax = fmaxf(tmax, s[c][r]);
            tmax = fmaxf(tmax, __shfl_xor(tmax, 16));
            tmax = fmaxf(tmax, __shfl_xor(tmax, 32));
            float mo = mst[m];
            float mn = fmaxf(mo, tmax);
            float scf = __expf(mo - mn);
            mst[m] = mn;
            float ps = 0.0f;
            #pragma unroll
            for (int c = 0; c < 4; ++c)
                #pragma unroll
                for (int r = 0; r < 4; ++r) {
                    float p = __expf(s[c][r] - mn);
                    s[c][r] = p;
                    ps += p;
                }
            ps += __shfl_xor(ps, 16);
            ps += __shfl_xor(ps, 32);
            lst[m] = lst[m] * scf + ps;
            acc[m][0] *= scf;
            acc[m][1] *= scf;
            unsigned pk[4][2];
            #pragma unroll
            for (int c = 0; c < 4; ++c) {
                pk[c][0] = pack2bf(s[c][0], s[c][1]);
                pk[c][1] = pack2bf(s[c][2], s[c][3]);
            }
            #pragma unroll
            for (int ks = 0; ks < 2; ++ks) {
                unsigned u[4];
                #pragma unroll
                for (int jj = 0; jj < 4; ++jj) {
                    int src = fr + 16 * (2 * (fq & 1) + (jj >> 1));
                    unsigned lo = (unsigned)__shfl((int)pk[2 * ks][jj & 1], src);
                    unsigned hi = (unsigned)__shfl((int)pk[2 * ks + 1][jj & 1], src);
                    u[jj] = (fq & 2) ? hi : lo;
                }
                short8 pb;
                #pragma unroll
                for (int jj = 0; jj < 4; ++jj) {
                    pb[2 * jj]     = (short)(u[jj] & 0xFFFF);
                    pb[2 * jj + 1] = (short)(u[jj] >> 16);
                }
                #pragma unroll
                for (int n = 0; n < 2; ++n)
                    acc[m][n] = __builtin_amdgcn_mfma_f32_16x16x32_bf16(
                                    av[n][ks], pb, acc[m][n], 0, 0, 0);
            }
        }
    }
    // epilogue: lane holds O[q=wv*64+m*16+fr][d=16n+4fq+0..3] -> 8B stores
    #pragma unroll
    for (int m = 0; m < 4; ++m) {
        int q = wv * 64 + m * 16 + fr;
        long nq = base_tok + (long)(wy * 16 + (q >> 4)) * 192 + (wx * 16 + (q & 15));
        float inv = 1.0f / lst[m];
        #pragma unroll
        for (int n = 0; n < 2; ++n) {
            uint2 wv2;
            wv2.x = pack2bf(acc[m][n][0] * inv, acc[m][n][1] * inv);
            wv2.y = pack2bf(acc[m][n][2] * inv, acc[m][n][3] * inv);
            *(uint2*)(raw + nq * RAWLD + h * HD + n * 16 + 4 * fq) = wv2;
        }
    }
}

// ---------------- AC-MSA attention: 1 wave per (group, head, half) -----------
__global__ void __launch_bounds__(64) aca_mfma(
        const bf16* __restrict__ qkv, const int* __restrict__ idxs,
        bf16* __restrict__ raw) {
    int bid = blockIdx.x;
    int half = bid & 1;
    int t2   = bid >> 1;
    int h    = t2 % NH;
    int grp  = t2 / NH;
    int b = grp / NGRP;
    int g = grp % NGRP;
    long btok = (long)b * NTOK;

    __shared__ short Vt[32 * PLD];
    __shared__ int   sidx[GSZ];

    int lane = threadIdx.x;
    int fr = lane & 15, fq = lane >> 4;
    const float scl = 0.17677669529663687f;

    sidx[lane]      = idxs[btok + g * GSZ + lane];
    sidx[lane + 64] = idxs[btok + g * GSZ + lane + 64];
    __syncthreads();

    short8 qf[4];
    #pragma unroll
    for (int m = 0; m < 4; ++m) {
        long n = btok + sidx[half * 64 + m * 16 + fr];
        qf[m] = *(const short8*)(qkv + n * C3 + h * HD + fq * 8);
    }

    f32x4 acc[4][2];
    float mst[4], lst[4];
    #pragma unroll
    for (int m = 0; m < 4; ++m) {
        acc[m][0] = (f32x4)(0.0f); acc[m][1] = (f32x4)(0.0f);
        mst[m] = -INFINITY; lst[m] = 0.0f;
    }

    for (int t = 0; t < 2; ++t) {
        __syncthreads();
        {   // stage V^T (gathered; lane = token)
            long n = btok + sidx[t * 64 + lane];
            const bf16* vb = qkv + n * C3 + 2 * CDIM + h * HD;
            #pragma unroll
            for (int c2 = 0; c2 < 4; ++c2) {
                short8 vv = *(const short8*)(vb + c2 * 8);
                #pragma unroll
                for (int i = 0; i < 8; ++i)
                    Vt[(c2 * 8 + i) * PLD + lane] = vv[i];
            }
        }
        short8 ak[4];
        #pragma unroll
        for (int c = 0; c < 4; ++c) {
            long n = btok + sidx[t * 64 + c * 16 + fr];
            ak[c] = *(const short8*)(qkv + n * C3 + CDIM + h * HD + fq * 8);
        }
        __syncthreads();
        short8 av[2][2];
        #pragma unroll
        for (int n = 0; n < 2; ++n)
            #pragma unroll
            for (int ks = 0; ks < 2; ++ks)
                av[n][ks] = *(const short8*)&Vt[(n * 16 + fr) * PLD + ks * 32 + fq * 8];

        #pragma unroll
        for (int m = 0; m < 4; ++m) {
            float s[4][4];
            #pragma unroll
            for (int c = 0; c < 4; ++c) {
                f32x4 s4 = (f32x4)(0.0f);
                s4 = __builtin_amdgcn_mfma_f32_16x16x32_bf16(ak[c], qf[m], s4, 0, 0, 0);
                #pragma unroll
                for (int r = 0; r < 4; ++r) s[c][r] = s4[r] * scl;
            }
            float tmax = s[0][0];
            #pragma unroll
            for (int c = 0; c < 4; ++c)
                #pragma unroll
                for (int r = 0; r < 4; ++r) tmax = fmaxf(tmax, s[c][r]);
            tmax = fmaxf(tmax, __shfl_xor(tmax, 16));
            tmax = fmaxf(tmax, __shfl_xor(tmax, 32));
            float mo = mst[m];
            float mn = fmaxf(mo, tmax);
            float scf = __expf(mo - mn);
            mst[m] = mn;
            float ps = 0.0f;
            #pragma unroll
            for (int c = 0; c < 4; ++c)
                #pragma unroll
                for (int r = 0; r < 4; ++r) {
                    float p = __expf(s[c][r] - mn);
                    s[c][r] = p;
                    ps += p;
                }
            ps += __shfl_xor(ps, 16);
            ps += __shfl_xor(ps, 32);
            lst[m] = lst[m] * scf + ps;
            acc[m][0] *= scf;
            acc[m][1] *= scf;
            unsigned pk[4][2];
            #pragma unroll
            for (int c = 0; c < 4; ++c) {
                pk[c][0] = pack2bf(s[c][0], s[c][1]);
                pk[c][1] = pack2bf(s[c][2], s[c][3]);
            }
            #pragma unroll
            for (int ks = 0; ks < 2; ++ks) {
                unsigned u[4];
                #pragma unroll
                for (int jj = 0; jj < 4; ++jj) {
                    int src = fr + 16 * (2 * (fq & 1) + (jj >> 1));
                    unsigned lo = (unsigned)__shfl((int)pk[2 * ks][jj & 1], src);
                    unsigned hi = (unsigned)__shfl((int)pk[2 * ks + 1][jj & 1], src);
                    u[jj] = (fq & 2) ? hi : lo;
                }
                short8 pb;
                #pragma unroll
                for (int jj = 0; jj < 4; ++jj) {
                    pb[2 * jj]     = (short)(u[jj] & 0xFFFF);
                    pb[2 * jj + 1] = (short)(u[jj] >> 16);
                }
                #pragma unroll
                for (int n = 0; n < 2; ++n)
                    acc[m][n] = __builtin_amdgcn_mfma_f32_16x16x32_bf16(
                                    av[n][ks], pb, acc[m][n], 0, 0, 0);
            }
        }
    }
    #pragma unroll
    for (int m = 0; m < 4; ++m) {
        long n = btok + sidx[half * 64 + m * 16 + fr];
        float inv = 1.0f / lst[m];
        #pragma unroll
        for (int nn = 0; nn < 2; ++nn) {
            uint2 wv2;
            wv2.x = pack2bf(acc[m][nn][0] * inv, acc[m][nn][1] * inv);
            wv2.y = pack2bf(acc[m][nn][2] * inv, acc[m][nn][3] * inv);
            *(uint2*)(raw + n * RAWLD + CDIM + h * HD + nn * 16 + 4 * fq) = wv2;
        }
    }
}

// ---------------- x_td -> y planes 48..53 (planar, vectorized) ---------------
__global__ void xtdcopy_kernel(const bf16* __restrict__ xtd, bf16* __restrict__ y) {
    long tok = (long)blockIdx.x * 256 + threadIdx.x;
    const uint4* src = (const uint4*)(xtd + tok * TDF);
    #pragma unroll
    for (int j = 0; j < 6; ++j)
        *(uint4*)(y + ((long)(48 + j) * NTOT + tok) * 8) = src[j];
}

// ---------------- depthwise 5x5 conv + gelu + residual -----------------------
// Input y AND output zc are 8-channel-planar [54][NTOT][8]: block (ck) reads
// and writes only plane ck -> dense 576B-contiguous row segments, no
// cross-block cache-line sharing (read amp ~= halo only).
#define CPS 1296   // ys plane stride (36*36 floats)
__global__ void __launch_bounds__(256) conv_kernel(
        const bf16* __restrict__ y, const float* __restrict__ dw,
        bf16* __restrict__ zc) {
    int bid = blockIdx.x;
    int ck   = bid % 54;            // 8-channel chunk (plane)
    int tile = (bid / 54) % 36;     // 6x6 spatial tiles of 32x32
    int b    = bid / (54 * 36);
    int ty = tile / 6, tx = tile % 6;
    int c0 = ck * 8;
    __shared__ float ys[8 * CPS];   // 41.5 KB
    __shared__ float wt[8 * 25];
    int tid = threadIdx.x;
    const bf16* ypl = y + ((long)ck * NTOT + (long)b * NTOK) * 8;
    for (int p = tid; p < 1296; p += 256) {
        int ly = p / 36, lx = p - ly * 36;
        int gy = ty * 32 + ly - 2, gx = tx * 32 + lx - 2;
        float f[8];
        if (gy >= 0 && gy < 192 && gx >= 0 && gx < 192) {
            short8 hv = *(const short8*)(ypl + (long)(gy * 192 + gx) * 8);
            #pragma unroll
            for (int i = 0; i < 8; ++i) f[i] = bfbits2f((unsigned short)hv[i]);
        } else {
            #pragma unroll
            for (int i = 0; i < 8; ++i) f[i] = 0.0f;
        }
        #pragma unroll
        for (int i = 0; i < 8; ++i) ys[i * CPS + p] = f[i];
    }
    for (int e = tid; e < 200; e += 256) wt[e] = dw[c0 * 25 + e];
    __syncthreads();
    int col = tid & 31, r4 = tid >> 5;   // r4 0..7
    int py0 = r4 * 4;                    // output rows py0..py0+3
    long tok0 = (long)b * NTOK + (long)(ty * 32 + py0) * 192 + tx * 32 + col;
    unsigned hh[4][4];                   // [pixel][4 x bf16-pair]
    for (int c = 0; c < 8; ++c) {
        const float* yc = &ys[c * CPS];
        float w[25];
        #pragma unroll
        for (int t = 0; t < 25; ++t) w[t] = wt[c * 25 + t];
        float a[4] = {0.0f, 0.0f, 0.0f, 0.0f};
        #pragma unroll
        for (int dy2 = 0; dy2 < 8; ++dy2) {
            float rv[5];
            #pragma unroll
            for (int dx = 0; dx < 5; ++dx)
                rv[dx] = yc[(py0 + dy2) * 36 + col + dx];
            #pragma unroll
            for (int i = 0; i < 4; ++i) {
                int dy = dy2 - i;
                if (dy >= 0 && dy < 5) {
                    #pragma unroll
                    for (int dx = 0; dx < 5; ++dx)
                        a[i] = fmaf(rv[dx], w[dy * 5 + dx], a[i]);
                }
            }
        }
        #pragma unroll
        for (int i = 0; i < 4; ++i) {
            float center = yc[(py0 + i + 2) * 36 + col + 2];
            unsigned short hsh = f32_to_bf16u(center + gelu_f(a[i]));
            if (c & 1) hh[i][c >> 1] |= ((unsigned)hsh) << 16;
            else       hh[i][c >> 1] = (unsigned)hsh;
        }
    }
    #pragma unroll
    for (int i = 0; i < 4; ++i) {
        long tok = tok0 + (long)i * 192;
        *(uint4*)(zc + ((long)ck * NTOT + tok) * 8) =
            make_uint4(hh[i][0], hh[i][1], hh[i][2], hh[i][3]);
    }
}

// =============================================================================
extern "C" void kernel_launch(void* const* d_in, const int* in_sizes, int n_in,
                              void* d_out, int out_size, void* d_ws, size_t ws_size,
                              hipStream_t stream) {
    (void)in_sizes; (void)n_in; (void)out_size; (void)ws_size;
    const float* x     = (const float*)d_in[0];
    const float* td    = (const float*)d_in[1];
    const float* n1g   = (const float*)d_in[2];
    const float* n1b   = (const float*)d_in[3];
    const float* n2g   = (const float*)d_in[4];
    const float* n2b   = (const float*)d_in[5];
    const float* wqkv  = (const float*)d_in[6];
    const float* rpb   = (const float*)d_in[7];
    const float* wproj = (const float*)d_in[8];
    const float* awq   = (const float*)d_in[9];
    const float* awk   = (const float*)d_in[10];
    const float* awv   = (const float*)d_in[11];
    const float* ascl  = (const float*)d_in[12];
    const float* aproj = (const float*)d_in[13];
    const float* fcw   = (const float*)d_in[14];
    const float* w1    = (const float*)d_in[15];
    const float* dw    = (const float*)d_in[16];
    const float* w2    = (const float*)d_in[17];
    float* out = (float*)d_out;

    char* ws = (char*)d_ws;
    size_t off = 0;
    auto alloc = [&](size_t bytes) -> char* {
        char* p = ws + off;
        off += (bytes + 255) & ~(size_t)255;
        return p;
    };
    bf16*  qkv  = (bf16*)alloc((size_t)NTOT * C3 * 2);       // R0: qkv -> y (planar)
    float* xn   = (float*)alloc((size_t)NTOT * CDIM * 4);    // R1: xn f32 -> raw bf16 -> zc head
    bf16*  xnh  = (bf16*)alloc((size_t)NTOT * CDIM * 2);     // R2: LN bf16 -> zc tail
    float* qn   = (float*)alloc((size_t)NTOT * RD * 4);
    bf16*  simb = (bf16*)alloc((size_t)NTOT * NTD * 2);
    bf16*  xtd  = (bf16*)alloc((size_t)NTOT * TDF * 2);
    float* kn   = (float*)alloc((size_t)2 * NTD * RD * 4);
    float* vtd  = (float*)alloc((size_t)2 * NTD * CDIM * 4);
    float* tdf  = (float*)alloc((size_t)2 * NTD * TDF * 4);
    bf16*  vtdT = (bf16*)alloc((size_t)2 * CDIM * NTD * 2);
    bf16*  tdfT = (bf16*)alloc((size_t)2 * TDF * NTD * 2);
    bf16*  wqkvT= (bf16*)alloc((size_t)C3 * CDIM * 2);
    bf16*  projT= (bf16*)alloc((size_t)CDIM * 384 * 2);
    bf16*  w1T  = (bf16*)alloc((size_t)MLP * CDIM * 2);
    bf16*  w2T  = (bf16*)alloc((size_t)CDIM * 448 * 2);
    int*   tkid = (int*)alloc((size_t)NTOT * 4);
    int*   idxs = (int*)alloc((size_t)NTOT * 4);
    int*   hist = (int*)alloc((size_t)576 * NTD * 4);
    bf16*  y    = qkv;          // reuse R0 (planar [54][NTOT][8], 63.7 MB)
    bf16*  raw  = (bf16*)xn;    // reuse R1
    bf16*  zc   = (bf16*)xn;    // chunk-planar z spans R1 + part of R2 (both dead)

    // weight packs (bf16, transposed)
    pack_bt<<<(192 * 576 + 255) / 256, 256, 0, stream>>>(wqkv, wqkvT, 192, 576, 192, 0);
    pack_bt<<<(192 * 192 + 255) / 256, 256, 0, stream>>>(wproj, projT, 192, 192, 384, 0);
    pack_bt<<<(192 * 192 + 255) / 256, 256, 0, stream>>>(aproj, projT, 192, 192, 384, 192);
    pack_bt<<<(192 * 384 + 255) / 256, 256, 0, stream>>>(w1, w1T, 192, 384, 192, 0);
    hipMemsetAsync(w2T, 0, (size_t)CDIM * 448 * 2, stream);
    pack_bt<<<(432 * 192 + 255) / 256, 256, 0, stream>>>(w2, w2T, 432, 192, 448, 0);

    // LN1: f32 (qn path) + bf16 (MFMA)
    ln_kernel<1><<<NTOT / 4, 256, 0, stream>>>(x, n1g, n1b, xn, xnh);

    // qkv (bf16) = xnh @ wqkv
    gemm_bt<0,0,1,0,0><<<dim3(9, 576), 256, 0, stream>>>(
        xnh, wqkvT, qkv, nullptr, NTOT, C3, CDIM, CDIM, CDIM, C3);

    // qn = l2norm(xn @ awq)   (f32 discrete path)
    qn_kernel<<<NTOT / 256, 256, 0, stream>>>(xn, awq, qn);

    // td-side small gemms (f32)
    gemm_kernel<0,0><<<dim3(1, 4), 256, 0, stream>>>(td, awk, kn, 2 * NTD, RD, CDIM, CDIM, RD, RD);
    gemm_kernel<0,0><<<dim3(3, 4), 256, 0, stream>>>(td, awv, vtd, 2 * NTD, CDIM, CDIM, CDIM, CDIM, CDIM);
    gemm_kernel<0,0><<<dim3(1, 4), 256, 0, stream>>>(td, fcw, tdf, 2 * NTD, TDF, CDIM, CDIM, TDF, TDF);
    l2n_kernel<<<1, 256, 0, stream>>>(kn, 2 * NTD);
    for (int b = 0; b < 2; ++b) {
        pack_bt<<<(NTD * CDIM + 255) / 256, 256, 0, stream>>>(
            vtd + (size_t)b * NTD * CDIM, vtdT + (size_t)b * CDIM * NTD, NTD, CDIM, NTD, 0);
        pack_bt<<<(NTD * TDF + 255) / 256, 256, 0, stream>>>(
            tdf + (size_t)b * NTD * TDF, tdfT + (size_t)b * TDF * NTD, NTD, TDF, NTD, 0);
    }

    sim_kernel<<<NTOT, 128, 0, stream>>>(qn, kn, ascl, simb, tkid);

    // out = x + sim @ vtd (fused residual) ; xtd = sim @ tdf
    for (int b = 0; b < 2; ++b) {
        gemm_bt<0,0,0,0,1><<<dim3(3, 288), 256, 0, stream>>>(
            simb + (size_t)b * NTOK * NTD, vtdT + (size_t)b * CDIM * NTD,
            out + (size_t)b * NTOK * CDIM, x + (size_t)b * NTOK * CDIM,
            NTOK, CDIM, NTD, NTD, NTD, CDIM);
        gemm_bt<0,0,1,0,0><<<dim3(1, 288), 256, 0, stream>>>(
            simb + (size_t)b * NTOK * NTD, tdfT + (size_t)b * TDF * NTD,
            xtd + (size_t)b * NTOK * TDF, nullptr, NTOK, TDF, NTD, NTD, NTD, TDF);
    }

    hist_kernel<<<576, 128, 0, stream>>>(tkid, hist);
    scan_kernel<<<2, 128, 0, stream>>>(hist);
    scatter_kernel<<<576, 128, 0, stream>>>(tkid, hist, idxs);

    // attentions -> raw (stride 384: win | aca), then one fused projection
    win_mfma<<<288 * NH * 4, 64, 0, stream>>>(qkv, rpb, raw);
    aca_mfma<<<576 * NH * 2, 64, 0, stream>>>(qkv, idxs, raw);
    gemm_bt<1,0,0,0,0><<<dim3(3, 576), 256, 0, stream>>>(
        raw, projT, out, nullptr, NTOT, CDIM, 384, RAWLD, 384, CDIM);

    // LN2 (bf16 only); qkv dead -> y (planar)
    ln_kernel<0><<<NTOT / 4, 256, 0, stream>>>(out, n2g, n2b, nullptr, xnh);

    // y planes 0..47 = gelu(xnh @ w1) (planar out); planes 48..53 = x_td
    gemm_bt<0,1,1,0,0,1><<<dim3(6, 576), 256, 0, stream>>>(
        xnh, w1T, y, nullptr, NTOT, MLP, CDIM, CDIM, CDIM, 0);
    xtdcopy_kernel<<<NTOT / 256, 256, 0, stream>>>(xtd, y);

    // zc = y + gelu(dwconv5x5(y)) (planar in/out), then out += zc @ w2 (K=432)
    conv_kernel<<<2 * 36 * 54, 256, 0, stream>>>(y, dw, zc);
    gemm_bt<1,0,0,1,0><<<dim3(3, 576), 256, 0, stream>>>(
        zc, w2T, out, nullptr, NTOT, CDIM, CH, 0, 448, CDIM);
}